// Round 4
// baseline (1649.516 us; speedup 1.0000x reference)
//
#include <hip/hip_runtime.h>
#include <math.h>

#define DIM 64
#define M_FINAL (128*89)   // 11392 final rows

static inline int cdiv(int a, int b) { return (a + b - 1) / b; }

struct EdgeSets {
    const int* src[12];
    const int* dst[12];
    int ne[12];
};

struct LayerArgs {
    const float* h[4];        // per-view input rows
    float* out[4];            // per-view pooled output rows
    const int* rowptr[4];
    const int* colsrc[4];
    const float* musig_prev;  // + j*128 ; unused for L==0
    double* dstats;           // + j*128
    const float* W;
    const float* as;
    const float* ad;
    const float* bias;
};

// ---------------- misc ----------------

__global__ void zero_kernel(float* __restrict__ p, int n) {
    int i = blockIdx.x * blockDim.x + threadIdx.x;
    if (i < n) p[i] = 0.f;
}

// ---------------- fused CSR build: one block per edge set ------------------
// 768 threads; hist + Hillis-Steele scan + scatter, all in LDS.
__global__ __launch_bounds__(768)
void csr_build_kernel(EdgeSets ES, int* __restrict__ rowptr_all,
                      int* __restrict__ colsrc_all) {
    __shared__ int cnt[768];
    __shared__ int cur[768];
    const int s = blockIdx.x;
    const int lay = s % 3;
    const int n = (lay == 0) ? 706 : (lay == 1) ? 353 : 177;
    const int ne = ES.ne[s];
    const int* __restrict__ src = ES.src[s];
    const int* __restrict__ dst = ES.dst[s];
    int* __restrict__ rowptr = rowptr_all + s * 768;
    int* __restrict__ colsrc = colsrc_all + s * 8192;
    const int t = threadIdx.x;

    cnt[t] = 0;
    __syncthreads();
    for (int k = t; k < ne; k += 768) atomicAdd(&cnt[dst[k]], 1);
    __syncthreads();
    int v = cnt[t];
    for (int off = 1; off < 768; off <<= 1) {
        int add = (t >= off) ? cnt[t - off] : 0;
        __syncthreads();
        cnt[t] += add;
        __syncthreads();
    }
    int excl = cnt[t] - v;
    if (t < n) { rowptr[t] = excl; cur[t] = excl; }
    if (t == n - 1) rowptr[n] = cnt[t];
    __syncthreads();
    for (int k = t; k < ne; k += 768) {
        int pos = atomicAdd(&cur[dst[k]], 1);
        colsrc[pos] = src[k];
    }
}

// ---------------- fused per-layer mega kernel ------------------------------
// block = (view, graph); 256 threads = 4 waves. BN'd h staged in (dynamic)
// LDS. Does: [BN] -> s-dots -> GAT softmax -> aggregate -> @W + bias ->
// relu -> pairwise max-pool -> BN stats.
template<int L>
__global__ __launch_bounds__(256)
void layer_kernel(LayerArgs A) {
    constexpr int NPIN  = (L == 0) ? 706 : (L == 1) ? 353 : 177;
    constexpr int NPOUT = (NPIN + 1) / 2;   // 353, 177, 89

    extern __shared__ char smem_raw[];
    double* sred = (double*)smem_raw;                   // [2][4][64] = 4096 B
    float* fbase = (float*)(smem_raw + 4096);
    float* hL   = fbase;                                // L0: NPIN*3 ; else NPIN*64
    float* sSrc = hL + ((L == 0) ? NPIN * 3 : NPIN * 64);
    float* sDst = sSrc + NPIN;
    float* waL  = sDst + NPIN;                          // L0: 8 ; else 128
    float* msL  = waL + ((L == 0) ? 8 : 128);           // 128 (L>0 only)

    const int bid = blockIdx.x;
    const int j = bid >> 7;            // view
    const int g = bid & 127;           // graph
    const int tid = threadIdx.x;
    const int wave = tid >> 6;
    const int lane = tid & 63;

    const float* __restrict__ h = A.h[j];
    const int* __restrict__ rowptr = A.rowptr[j];
    const int* __restrict__ colsrc = A.colsrc[j];
    const float* __restrict__ W = A.W;

    if constexpr (L == 0) {
        if (tid < 6) {                    // wa_{src,dst}[f] = sum_d W[f][d]*a[d]
            int f = (tid < 3) ? tid : tid - 3;
            const float* av = (tid < 3) ? A.as : A.ad;
            float acc = 0.f;
            for (int d = 0; d < 64; ++d) acc += W[f * 64 + d] * av[d];
            waL[tid] = acc;
        }
        for (int k = tid; k < NPIN * 3; k += 256) hL[k] = h[(size_t)g * (NPIN * 3) + k];
        __syncthreads();
        for (int r = tid; r < NPIN; r += 256) {
            float h0 = hL[r * 3], h1 = hL[r * 3 + 1], h2 = hL[r * 3 + 2];
            sSrc[r] = h0 * waL[0] + h1 * waL[1] + h2 * waL[2];
            sDst[r] = h0 * waL[3] + h1 * waL[4] + h2 * waL[5];
        }
        __syncthreads();
    } else {
        if (tid < 128) msL[tid] = A.musig_prev[j * 128 + tid];
        for (int f = wave; f < 64; f += 4) {   // wa vectors, wave per f
            float w = W[f * 64 + lane];
            float a = w * A.as[lane];
            float b = w * A.ad[lane];
            for (int off = 32; off > 0; off >>= 1) {
                a += __shfl_down(a, off, 64);
                b += __shfl_down(b, off, 64);
            }
            if (lane == 0) { waL[f] = a; waL[64 + f] = b; }
        }
        __syncthreads();
        // stage BN'd h into LDS (float4, coalesced)
        {
            const float4* hg = (const float4*)(h + (size_t)g * NPIN * 64);
            float4* hL4 = (float4*)hL;
            for (int k = tid; k < NPIN * 16; k += 256) {
                float4 v = hg[k];
                int d = (k * 4) & 63;
                v.x = (v.x - msL[d])     * msL[64 + d];
                v.y = (v.y - msL[d + 1]) * msL[64 + d + 1];
                v.z = (v.z - msL[d + 2]) * msL[64 + d + 2];
                v.w = (v.w - msL[d + 3]) * msL[64 + d + 3];
                hL4[k] = v;
            }
        }
        __syncthreads();
        for (int r = wave; r < NPIN; r += 4) {   // s-dots from LDS
            float v = hL[r * 64 + lane];
            float a = v * waL[lane];
            float b = v * waL[64 + lane];
            for (int off = 32; off > 0; off >>= 1) {
                a += __shfl_down(a, off, 64);
                b += __shfl_down(b, off, 64);
            }
            if (lane == 0) { sSrc[r] = a; sDst[r] = b; }
        }
        __syncthreads();
    }

    float w0 = 0.f, w1 = 0.f, w2 = 0.f;
    if constexpr (L == 0) { w0 = W[lane]; w1 = W[64 + lane]; w2 = W[128 + lane]; }
    const float b_l = A.bias[lane];
    float* outj = A.out[j];
    double bs = 0.0, bs2 = 0.0;

    for (int c = wave; c < NPOUT; c += 4) {
        float vmax = 0.f;                      // children are relu'd -> >= 0
        #pragma unroll
        for (int ch = 0; ch < 2; ++ch) {
            int child = 2 * c + ch;
            if (child >= NPIN) break;
            int start = rowptr[child];
            int deg = rowptr[child + 1] - start;
            float sd = sDst[child];
            float m = -1e30f;
            for (int k = 0; k < deg; ++k) {
                int sl = colsrc[start + k];
                float v = sSrc[sl] + sd;
                v = (v >= 0.f) ? v : 0.2f * v;
                m = fmaxf(m, v);
            }
            float z = 0.f, acc = 0.f, a0 = 0.f, a1 = 0.f, a2 = 0.f;
            for (int k = 0; k < deg; ++k) {
                int sl = colsrc[start + k];
                float v = sSrc[sl] + sd;
                v = (v >= 0.f) ? v : 0.2f * v;
                float p = __expf(v - m);
                z += p;
                if constexpr (L == 0) {
                    a0 += p * hL[sl * 3];
                    a1 += p * hL[sl * 3 + 1];
                    a2 += p * hL[sl * 3 + 2];
                } else {
                    acc += p * hL[sl * 64 + lane];
                }
            }
            float inv = 1.f / z;
            float o;
            if constexpr (L == 0) {
                o = (a0 * w0 + a1 * w1 + a2 * w2) * inv + b_l;
            } else {
                float agg = acc * inv;
                o = b_l;
                #pragma unroll 8
                for (int f = 0; f < 64; ++f)
                    o += __shfl(agg, f, 64) * W[f * 64 + lane];
            }
            vmax = fmaxf(vmax, fmaxf(o, 0.f));
        }
        outj[((size_t)g * NPOUT + c) * 64 + lane] = vmax;
        bs += vmax;
        bs2 += (double)vmax * vmax;
    }
    sred[(0 * 4 + wave) * 64 + lane] = bs;
    sred[(1 * 4 + wave) * 64 + lane] = bs2;
    __syncthreads();
    if (wave == 0) {
        double t1 = sred[lane] + sred[64 + lane] + sred[128 + lane] + sred[192 + lane];
        double t2 = sred[256 + lane] + sred[320 + lane] + sred[384 + lane] + sred[448 + lane];
        atomicAdd(A.dstats + j * 128 + lane, t1);
        atomicAdd(A.dstats + j * 128 + 64 + lane, t2);
    }
}

__global__ void bn_finalize_kernel(const double* __restrict__ dstats,
                                   float* __restrict__ musig, int n_rows) {
    int jv = blockIdx.x;           // view
    int d = threadIdx.x;           // 64
    double mu = dstats[jv * 128 + d] / n_rows;
    double var = dstats[jv * 128 + 64 + d] / n_rows - mu * mu;
    musig[jv * 128 + d] = (float)mu;
    musig[jv * 128 + 64 + d] = rsqrtf((float)var + 1e-5f);
}

// ---------------- fused head reduce: Bm dots -> S (BmT Bm) + column means --
// wave per row m; BN applied on the fly.
__global__ __launch_bounds__(256)
void head_reduce_kernel(const float* __restrict__ ALL, const float* __restrict__ musig,
                        const float* __restrict__ w_attn,
                        float* __restrict__ S, float* __restrict__ cm) {
    __shared__ float S_loc[16];
    __shared__ float cm_loc[256];
    const int t = threadIdx.x, wave = t >> 6, lane = t & 63;
    if (t < 16) S_loc[t] = 0.f;
    cm_loc[t] = 0.f;
    __syncthreads();
    const float wa = w_attn[lane];
    float cacc[4] = {0.f, 0.f, 0.f, 0.f};
    for (int m = blockIdx.x * 4 + wave; m < M_FINAL; m += gridDim.x * 4) {
        float b4[4];
        float csum = 0.f;
        #pragma unroll
        for (int v = 0; v < 4; ++v) {
            float val = (ALL[((size_t)v * M_FINAL + m) * 64 + lane] - musig[v * 128 + lane])
                        * musig[v * 128 + 64 + lane];
            csum += val;
            float p = val * wa;
            for (int off = 32; off > 0; off >>= 1) p += __shfl_down(p, off, 64);
            b4[v] = __shfl(p, 0, 64);
        }
        cacc[m & 3] += csum;
        if (lane < 16) atomicAdd(&S_loc[lane], b4[lane >> 2] * b4[lane & 3]);
    }
    #pragma unroll
    for (int q = 0; q < 4; ++q) atomicAdd(&cm_loc[q * 64 + lane], cacc[q]);
    __syncthreads();
    if (t < 16) atomicAdd(&S[t], S_loc[t]);
    atomicAdd(&cm[t], cm_loc[t]);
}

__global__ void fuse_small_kernel(const float* __restrict__ S, const float* __restrict__ cm,
                                  const float* __restrict__ w_lin0, const float* __restrict__ b_lin0,
                                  float* __restrict__ cvec) {
    if (threadIdx.x != 0 || blockIdx.x != 0) return;
    float cn[4];
    for (int v = 0; v < 4; ++v) cn[v] = sqrtf(S[v * 4 + v]);
    float A[16];
    for (int u = 0; u < 4; ++u) {
        float row[4]; float mx = -1e30f;
        for (int v = 0; v < 4; ++v) {
            float g = S[u * 4 + v] / (cn[u] * cn[v]);
            g = (g >= 0.f) ? g : 0.1f * g;       // leaky_relu 0.1
            row[v] = g; mx = fmaxf(mx, g);
        }
        float sum = 0.f;
        for (int v = 0; v < 4; ++v) { row[v] = expf(row[v] - mx); sum += row[v]; }
        for (int v = 0; v < 4; ++v) A[u * 4 + v] = row[v] / sum;
    }
    float e4[4];
    for (int v = 0; v < 4; ++v) {
        float a = b_lin0[v];
        for (int c = 0; c < 256; ++c) a += (cm[c] / (float)M_FINAL) * w_lin0[c * 4 + v];
        e4[v] = a;
    }
    float mx = fmaxf(fmaxf(e4[0], e4[1]), fmaxf(e4[2], e4[3]));
    float sum = 0.f, w[4];
    for (int v = 0; v < 4; ++v) { w[v] = expf(e4[v] - mx); sum += w[v]; }
    for (int v = 0; v < 4; ++v) w[v] /= sum;
    for (int k = 0; k < 4; ++k) {
        float c = 0.f;
        for (int v = 0; v < 4; ++v) c += A[k * 4 + v] * w[v];
        cvec[k] = c;
    }
}

// ---------------- fused head output: combine + 3 matvecs (selu,selu,none) --
__global__ __launch_bounds__(256)
void head_out_kernel(const float* __restrict__ ALL, const float* __restrict__ musig,
                     const float* __restrict__ cvec,
                     const float* __restrict__ W0, const float* __restrict__ W1,
                     const float* __restrict__ W2, float* __restrict__ outp) {
    __shared__ float Wl[3][64 * 64];   // 48 KB
    const int t = threadIdx.x, wave = t >> 6, lane = t & 63;
    for (int k = t; k < 4096; k += 256) {
        Wl[0][k] = W0[k]; Wl[1][k] = W1[k]; Wl[2][k] = W2[k];
    }
    __syncthreads();
    const float c0 = cvec[0], c1 = cvec[1], c2 = cvec[2], c3 = cvec[3];
    const float scale = 1.0507009873554805f;
    const float alpha = 1.6732632423543772f;
    for (int m = blockIdx.x * 4 + wave; m < M_FINAL; m += gridDim.x * 4) {
        float r =
            c0 * ((ALL[((size_t)0 * M_FINAL + m) * 64 + lane] - musig[0 * 128 + lane]) * musig[0 * 128 + 64 + lane]) +
            c1 * ((ALL[((size_t)1 * M_FINAL + m) * 64 + lane] - musig[1 * 128 + lane]) * musig[1 * 128 + 64 + lane]) +
            c2 * ((ALL[((size_t)2 * M_FINAL + m) * 64 + lane] - musig[2 * 128 + lane]) * musig[2 * 128 + 64 + lane]) +
            c3 * ((ALL[((size_t)3 * M_FINAL + m) * 64 + lane] - musig[3 * 128 + lane]) * musig[3 * 128 + 64 + lane]);
        #pragma unroll
        for (int s = 0; s < 3; ++s) {
            float o = 0.f;
            #pragma unroll 8
            for (int f = 0; f < 64; ++f) o += __shfl(r, f, 64) * Wl[s][f * 64 + lane];
            if (s < 2) o = (o > 0.f) ? scale * o : scale * alpha * expm1f(o);
            r = o;
        }
        outp[(size_t)m * 64 + lane] = r;
    }
}

extern "C" void kernel_launch(void* const* d_in, const int* in_sizes, int n_in,
                              void* d_out, int out_size, void* d_ws, size_t ws_size,
                              hipStream_t stream) {
    const float* x = (const float*)d_in[15];

    float* ws = (float*)d_ws;
    double* dstats_all = (double*)ws;                 // 1536 doubles -> [0, 3072)
    float*  cm         = ws + 3072;                   // 256
    float*  S          = ws + 3328;                   // 16
    float*  cvec       = ws + 3344;                   // 4
    float*  musig_all  = ws + 3584;                   // 3*512 -> [3584, 5120)
    int*    rowptr_all = (int*)(ws + 5120);           // 12*768 -> [5120, 14336)
    int*    colsrc_all = (int*)(ws + 14336);          // 12*8192 -> [14336, 112640)
    float*  A_buf      = ws + 112640;                 // 4*128*353*64 = 11,567,104
    float*  B_buf      = A_buf + (size_t)4 * 128 * 353 * 64;  // 4*128*177*64
    float*  ALLb       = A_buf;                       // aliases A (dead by layer 2)
    const size_t as0 = (size_t)128 * 353 * 64;
    const size_t as1 = (size_t)128 * 177 * 64;

    // dynamic LDS sizes per layer
    const int SM0 = 4096 + (706 * 3 + 706 + 706 + 8) * 4;            // 18,248
    const int SM1 = 4096 + (353 * 64 + 353 + 353 + 128 + 128) * 4;   // 98,312
    const int SM2 = 4096 + (177 * 64 + 177 + 177 + 128 + 128) * 4;   // 51,848
    (void)hipFuncSetAttribute(reinterpret_cast<const void*>(&layer_kernel<0>),
                              hipFuncAttributeMaxDynamicSharedMemorySize, SM0);
    (void)hipFuncSetAttribute(reinterpret_cast<const void*>(&layer_kernel<1>),
                              hipFuncAttributeMaxDynamicSharedMemorySize, SM1);
    (void)hipFuncSetAttribute(reinterpret_cast<const void*>(&layer_kernel<2>),
                              hipFuncAttributeMaxDynamicSharedMemorySize, SM2);

    // edge set table (graph-0 structure shared by all 128 graphs)
    EdgeSets ES;
    for (int s = 0; s < 12; ++s) {
        const int* e = (const int*)d_in[s];
        int E = in_sizes[s] / 2;
        ES.src[s] = e;
        ES.dst[s] = e + E;
        ES.ne[s] = E / 128;
    }

    zero_kernel<<<cdiv(3584, 256), 256, 0, stream>>>(ws, 3584);
    csr_build_kernel<<<12, 768, 0, stream>>>(ES, rowptr_all, colsrc_all);

    for (int L = 0; L < 3; ++L) {
        LayerArgs LA;
        for (int j = 0; j < 4; ++j) {
            int s = j * 3 + L;
            LA.rowptr[j] = rowptr_all + s * 768;
            LA.colsrc[j] = colsrc_all + s * 8192;
            if (L == 0) { LA.h[j] = x;               LA.out[j] = A_buf + j * as0; }
            if (L == 1) { LA.h[j] = A_buf + j * as0; LA.out[j] = B_buf + j * as1; }
            if (L == 2) { LA.h[j] = B_buf + j * as1; LA.out[j] = ALLb + (size_t)j * M_FINAL * 64; }
        }
        LA.musig_prev = (L == 0) ? nullptr : (musig_all + (L - 1) * 512);
        LA.dstats = dstats_all + L * 512;
        LA.W    = (const float*)d_in[16 + 4 * L];
        LA.as   = (const float*)d_in[17 + 4 * L];
        LA.ad   = (const float*)d_in[18 + 4 * L];
        LA.bias = (const float*)d_in[19 + 4 * L];
        if (L == 0) layer_kernel<0><<<512, 256, SM0, stream>>>(LA);
        if (L == 1) layer_kernel<1><<<512, 256, SM1, stream>>>(LA);
        if (L == 2) layer_kernel<2><<<512, 256, SM2, stream>>>(LA);
        static const int NPOUT[3] = {353, 177, 89};
        bn_finalize_kernel<<<4, 64, 0, stream>>>(dstats_all + L * 512, musig_all + L * 512,
                                                 128 * NPOUT[L]);
    }

    // ---- fusion head ----
    const float* w_attn = (const float*)d_in[28];
    const float* w_lin0 = (const float*)d_in[29];
    const float* b_lin0 = (const float*)d_in[30];
    const float* w_link0 = (const float*)d_in[31];
    const float* w_linkl = (const float*)d_in[32];
    const float* w_link_ = (const float*)d_in[33];
    const float* musig2 = musig_all + 2 * 512;

    head_reduce_kernel<<<64, 256, 0, stream>>>(ALLb, musig2, w_attn, S, cm);
    fuse_small_kernel<<<1, 64, 0, stream>>>(S, cm, w_lin0, b_lin0, cvec);
    head_out_kernel<<<128, 256, 0, stream>>>(ALLb, musig2, cvec, w_link0, w_linkl, w_link_,
                                             (float*)d_out);
}

// Round 5
// 869.711 us; speedup vs baseline: 1.8966x; 1.8966x over previous
//
#include <hip/hip_runtime.h>
#include <math.h>

#define DIM 64
#define M_FINAL (128*89)   // 11392 final rows

static inline int cdiv(int a, int b) { return (a + b - 1) / b; }

struct EdgeSets {
    const int* src[12];
    const int* dst[12];
    int ne[12];
};

struct LayerArgs {
    const float* h[4];        // per-view input rows
    float* out[4];            // per-view pooled output rows
    const int* rowptr[4];
    const int* colsrc[4];
    int ne[4];                // graph-0 edge count per view
    const float* musig_prev;  // + j*128 ; unused for L==0
    double* dstats;           // + j*128
    const float* W;
    const float* as;
    const float* ad;
    const float* bias;
};

// ---------------- misc ----------------

__global__ void zero_kernel(float* __restrict__ p, int n) {
    int i = blockIdx.x * blockDim.x + threadIdx.x;
    if (i < n) p[i] = 0.f;
}

// ---------------- fused CSR build: one block per edge set ------------------
__global__ __launch_bounds__(768)
void csr_build_kernel(EdgeSets ES, int* __restrict__ rowptr_all,
                      int* __restrict__ colsrc_all) {
    __shared__ int cnt[768];
    __shared__ int cur[768];
    const int s = blockIdx.x;
    const int lay = s % 3;
    const int n = (lay == 0) ? 706 : (lay == 1) ? 353 : 177;
    const int ne = ES.ne[s];
    const int* __restrict__ src = ES.src[s];
    const int* __restrict__ dst = ES.dst[s];
    int* __restrict__ rowptr = rowptr_all + s * 768;
    int* __restrict__ colsrc = colsrc_all + s * 8192;
    const int t = threadIdx.x;

    cnt[t] = 0;
    __syncthreads();
    for (int k = t; k < ne; k += 768) atomicAdd(&cnt[dst[k]], 1);
    __syncthreads();
    int v = cnt[t];
    for (int off = 1; off < 768; off <<= 1) {
        int add = (t >= off) ? cnt[t - off] : 0;
        __syncthreads();
        cnt[t] += add;
        __syncthreads();
    }
    int excl = cnt[t] - v;
    if (t < n) { rowptr[t] = excl; cur[t] = excl; }
    if (t == n - 1) rowptr[n] = cnt[t];
    __syncthreads();
    for (int k = t; k < ne; k += 768) {
        int pos = atomicAdd(&cur[dst[k]], 1);
        colsrc[pos] = src[k];
    }
}

// ---------------- fused per-layer mega kernel ------------------------------
// block = (view, graph); 512 threads = 8 waves. LDS holds only per-node
// scalars + uint16 CSR + W (L>0). h gathered from global (L2-hot slices).
// Phases: stage -> s-dots -> per-node softmax stats -> aggregate+matvec+
// pool+BN-stats.
template<int L>
__global__ __launch_bounds__(512)
void layer_kernel(LayerArgs A) {
    constexpr int NPIN  = (L == 0) ? 706 : (L == 1) ? 353 : 177;
    constexpr int NPOUT = (NPIN + 1) / 2;   // 353, 177, 89

    extern __shared__ char smem[];
    double* sred = (double*)smem;                       // [2][8][64] = 8192 B
    float* fp = (float*)(smem + 8192);
    float* sSrc = fp; fp += NPIN;
    float* sDst = fp; fp += NPIN;
    float* mArr = fp; fp += NPIN;
    float* zArr = fp; fp += NPIN;
    float* msL  = fp; fp += 128;
    float* waL  = fp; fp += (L == 0) ? 8 : 128;
    float* WL   = fp; if constexpr (L > 0) fp += 4096;
    float* hL   = fp; if constexpr (L == 0) fp += 706 * 3;
    unsigned short* rp16 = (unsigned short*)fp;
    unsigned short* cs16 = rp16 + (NPIN + 1);

    const int bid = blockIdx.x;
    const int j = bid >> 7;            // view
    const int g = bid & 127;           // graph
    const int tid = threadIdx.x;
    const int wave = tid >> 6;
    const int lane = tid & 63;
    const int bd = 512;

    const float* __restrict__ h = A.h[j];
    const int* __restrict__ rowptr = A.rowptr[j];
    const int* __restrict__ colsrc = A.colsrc[j];
    const float* __restrict__ W = A.W;
    const int ne = A.ne[j];
    const size_t gbase = (size_t)g * NPIN;

    // ---- phase 1: stage CSR (+ msL, WL, waL / hL) ----
    for (int k = tid; k < ne; k += bd) cs16[k] = (unsigned short)colsrc[k];
    for (int k = tid; k <= NPIN; k += bd) rp16[k] = (unsigned short)rowptr[k];
    if constexpr (L > 0) {
        if (tid < 128) msL[tid] = A.musig_prev[j * 128 + tid];
        for (int k = tid; k < 4096; k += bd) WL[k] = W[k];
        for (int f = wave; f < 64; f += 8) {   // wa vectors, wave per f
            float w = W[f * 64 + lane];
            float a = w * A.as[lane];
            float b = w * A.ad[lane];
            for (int off = 32; off > 0; off >>= 1) {
                a += __shfl_down(a, off, 64);
                b += __shfl_down(b, off, 64);
            }
            if (lane == 0) { waL[f] = a; waL[64 + f] = b; }
        }
    } else {
        if (tid < 6) {                    // wa_{src,dst}[f] = sum_d W[f][d]*a[d]
            int f = (tid < 3) ? tid : tid - 3;
            const float* av = (tid < 3) ? A.as : A.ad;
            float acc = 0.f;
            for (int d = 0; d < 64; ++d) acc += W[f * 64 + d] * av[d];
            waL[tid] = acc;
        }
        for (int k = tid; k < 706 * 3; k += bd) hL[k] = h[(size_t)g * 2118 + k];
    }
    __syncthreads();

    // ---- phase 2: s-dots ----
    float mu = 0.f, rs = 1.f;
    if constexpr (L == 0) {
        for (int r = tid; r < NPIN; r += bd) {
            float h0 = hL[r * 3], h1 = hL[r * 3 + 1], h2 = hL[r * 3 + 2];
            sSrc[r] = h0 * waL[0] + h1 * waL[1] + h2 * waL[2];
            sDst[r] = h0 * waL[3] + h1 * waL[4] + h2 * waL[5];
        }
    } else {
        mu = msL[lane];
        rs = msL[64 + lane];
        for (int r = wave; r < NPIN; r += 8) {
            float v = (h[(gbase + r) * 64 + lane] - mu) * rs;
            float a = v * waL[lane];
            float b = v * waL[64 + lane];
            for (int off = 32; off > 0; off >>= 1) {
                a += __shfl_down(a, off, 64);
                b += __shfl_down(b, off, 64);
            }
            if (lane == 0) { sSrc[r] = a; sDst[r] = b; }
        }
    }
    __syncthreads();

    // ---- phase 3: per-node softmax stats (thread-parallel, no atomics) ----
    for (int r = tid; r < NPIN; r += bd) {
        int s0 = rp16[r], e0 = rp16[r + 1];
        float sd = sDst[r];
        float m = -1e30f;
        for (int k = s0; k < e0; ++k) {
            float v = sSrc[cs16[k]] + sd;
            v = (v >= 0.f) ? v : 0.2f * v;
            m = fmaxf(m, v);
        }
        float z = 0.f;
        for (int k = s0; k < e0; ++k) {
            float v = sSrc[cs16[k]] + sd;
            v = (v >= 0.f) ? v : 0.2f * v;
            z += __expf(v - m);
        }
        mArr[r] = m;
        zArr[r] = z;
    }
    __syncthreads();

    // ---- phase 4: aggregate + matvec + relu + pool + BN stats ----
    float w0 = 0.f, w1 = 0.f, w2 = 0.f;
    if constexpr (L == 0) { w0 = W[lane]; w1 = W[64 + lane]; w2 = W[128 + lane]; }
    const float b_l = A.bias[lane];
    float* outj = A.out[j];
    double bs = 0.0, bs2 = 0.0;

    for (int c = wave; c < NPOUT; c += 8) {
        float vmax = 0.f;                      // children are relu'd -> >= 0
        #pragma unroll
        for (int ch = 0; ch < 2; ++ch) {
            int child = 2 * c + ch;
            if (child >= NPIN) break;
            int s0 = rp16[child], e0 = rp16[child + 1];
            float sd = sDst[child];
            float m = mArr[child];
            float invz = 1.f / zArr[child];
            float o;
            if constexpr (L == 0) {
                float a0 = 0.f, a1 = 0.f, a2 = 0.f;
                for (int k = s0; k < e0; ++k) {
                    int sl = cs16[k];
                    float v = sSrc[sl] + sd;
                    v = (v >= 0.f) ? v : 0.2f * v;
                    float p = __expf(v - m);
                    a0 += p * hL[sl * 3];
                    a1 += p * hL[sl * 3 + 1];
                    a2 += p * hL[sl * 3 + 2];
                }
                o = (a0 * w0 + a1 * w1 + a2 * w2) * invz + b_l;
            } else {
                float acc = 0.f;
                int k = s0;
                for (; k + 2 <= e0; k += 2) {
                    int sl0 = cs16[k], sl1 = cs16[k + 1];
                    float hv0 = h[(gbase + sl0) * 64 + lane];
                    float hv1 = h[(gbase + sl1) * 64 + lane];
                    float v0 = sSrc[sl0] + sd; v0 = (v0 >= 0.f) ? v0 : 0.2f * v0;
                    float v1 = sSrc[sl1] + sd; v1 = (v1 >= 0.f) ? v1 : 0.2f * v1;
                    acc += __expf(v0 - m) * ((hv0 - mu) * rs)
                         + __expf(v1 - m) * ((hv1 - mu) * rs);
                }
                if (k < e0) {
                    int sl = cs16[k];
                    float hv = h[(gbase + sl) * 64 + lane];
                    float v = sSrc[sl] + sd; v = (v >= 0.f) ? v : 0.2f * v;
                    acc += __expf(v - m) * ((hv - mu) * rs);
                }
                float agg = acc * invz;
                o = b_l;
                #pragma unroll
                for (int f = 0; f < 64; ++f)
                    o += __shfl(agg, f, 64) * WL[f * 64 + lane];
            }
            vmax = fmaxf(vmax, fmaxf(o, 0.f));
        }
        outj[((size_t)g * NPOUT + c) * 64 + lane] = vmax;
        bs += vmax;
        bs2 += (double)vmax * vmax;
    }
    sred[wave * 64 + lane] = bs;
    sred[512 + wave * 64 + lane] = bs2;
    __syncthreads();
    if (wave == 0) {
        double t1 = 0.0, t2 = 0.0;
        #pragma unroll
        for (int w = 0; w < 8; ++w) {
            t1 += sred[w * 64 + lane];
            t2 += sred[512 + w * 64 + lane];
        }
        atomicAdd(A.dstats + j * 128 + lane, t1);
        atomicAdd(A.dstats + j * 128 + 64 + lane, t2);
    }
}

__global__ void bn_finalize_kernel(const double* __restrict__ dstats,
                                   float* __restrict__ musig, int n_rows) {
    int jv = blockIdx.x;           // view
    int d = threadIdx.x;           // 64
    double mu = dstats[jv * 128 + d] / n_rows;
    double var = dstats[jv * 128 + 64 + d] / n_rows - mu * mu;
    musig[jv * 128 + d] = (float)mu;
    musig[jv * 128 + 64 + d] = rsqrtf((float)var + 1e-5f);
}

// ---------------- fused head reduce: Bm dots -> S (BmT Bm) + column means --
__global__ __launch_bounds__(256)
void head_reduce_kernel(const float* __restrict__ ALL, const float* __restrict__ musig,
                        const float* __restrict__ w_attn,
                        float* __restrict__ S, float* __restrict__ cm) {
    __shared__ float S_loc[16];
    __shared__ float cm_loc[256];
    const int t = threadIdx.x, wave = t >> 6, lane = t & 63;
    if (t < 16) S_loc[t] = 0.f;
    cm_loc[t] = 0.f;
    __syncthreads();
    const float wa = w_attn[lane];
    float cacc[4] = {0.f, 0.f, 0.f, 0.f};
    for (int m = blockIdx.x * 4 + wave; m < M_FINAL; m += gridDim.x * 4) {
        float b4[4];
        float csum = 0.f;
        #pragma unroll
        for (int v = 0; v < 4; ++v) {
            float val = (ALL[((size_t)v * M_FINAL + m) * 64 + lane] - musig[v * 128 + lane])
                        * musig[v * 128 + 64 + lane];
            csum += val;
            float p = val * wa;
            for (int off = 32; off > 0; off >>= 1) p += __shfl_down(p, off, 64);
            b4[v] = __shfl(p, 0, 64);
        }
        cacc[m & 3] += csum;
        if (lane < 16) atomicAdd(&S_loc[lane], b4[lane >> 2] * b4[lane & 3]);
    }
    #pragma unroll
    for (int q = 0; q < 4; ++q) atomicAdd(&cm_loc[q * 64 + lane], cacc[q]);
    __syncthreads();
    if (t < 16) atomicAdd(&S[t], S_loc[t]);
    atomicAdd(&cm[t], cm_loc[t]);
}

__global__ void fuse_small_kernel(const float* __restrict__ S, const float* __restrict__ cm,
                                  const float* __restrict__ w_lin0, const float* __restrict__ b_lin0,
                                  float* __restrict__ cvec) {
    if (threadIdx.x != 0 || blockIdx.x != 0) return;
    float cn[4];
    for (int v = 0; v < 4; ++v) cn[v] = sqrtf(S[v * 4 + v]);
    float A[16];
    for (int u = 0; u < 4; ++u) {
        float row[4]; float mx = -1e30f;
        for (int v = 0; v < 4; ++v) {
            float g = S[u * 4 + v] / (cn[u] * cn[v]);
            g = (g >= 0.f) ? g : 0.1f * g;       // leaky_relu 0.1
            row[v] = g; mx = fmaxf(mx, g);
        }
        float sum = 0.f;
        for (int v = 0; v < 4; ++v) { row[v] = expf(row[v] - mx); sum += row[v]; }
        for (int v = 0; v < 4; ++v) A[u * 4 + v] = row[v] / sum;
    }
    float e4[4];
    for (int v = 0; v < 4; ++v) {
        float a = b_lin0[v];
        for (int c = 0; c < 256; ++c) a += (cm[c] / (float)M_FINAL) * w_lin0[c * 4 + v];
        e4[v] = a;
    }
    float mx = fmaxf(fmaxf(e4[0], e4[1]), fmaxf(e4[2], e4[3]));
    float sum = 0.f, w[4];
    for (int v = 0; v < 4; ++v) { w[v] = expf(e4[v] - mx); sum += w[v]; }
    for (int v = 0; v < 4; ++v) w[v] /= sum;
    for (int k = 0; k < 4; ++k) {
        float c = 0.f;
        for (int v = 0; v < 4; ++v) c += A[k * 4 + v] * w[v];
        cvec[k] = c;
    }
}

// ---------------- fused head output: combine + 3 matvecs (selu,selu,none) --
__global__ __launch_bounds__(256)
void head_out_kernel(const float* __restrict__ ALL, const float* __restrict__ musig,
                     const float* __restrict__ cvec,
                     const float* __restrict__ W0, const float* __restrict__ W1,
                     const float* __restrict__ W2, float* __restrict__ outp) {
    __shared__ float Wl[3][64 * 64];   // 48 KB
    const int t = threadIdx.x, wave = t >> 6, lane = t & 63;
    for (int k = t; k < 4096; k += 256) {
        Wl[0][k] = W0[k]; Wl[1][k] = W1[k]; Wl[2][k] = W2[k];
    }
    __syncthreads();
    const float c0 = cvec[0], c1 = cvec[1], c2 = cvec[2], c3 = cvec[3];
    const float scale = 1.0507009873554805f;
    const float alpha = 1.6732632423543772f;
    for (int m = blockIdx.x * 4 + wave; m < M_FINAL; m += gridDim.x * 4) {
        float r =
            c0 * ((ALL[((size_t)0 * M_FINAL + m) * 64 + lane] - musig[0 * 128 + lane]) * musig[0 * 128 + 64 + lane]) +
            c1 * ((ALL[((size_t)1 * M_FINAL + m) * 64 + lane] - musig[1 * 128 + lane]) * musig[1 * 128 + 64 + lane]) +
            c2 * ((ALL[((size_t)2 * M_FINAL + m) * 64 + lane] - musig[2 * 128 + lane]) * musig[2 * 128 + 64 + lane]) +
            c3 * ((ALL[((size_t)3 * M_FINAL + m) * 64 + lane] - musig[3 * 128 + lane]) * musig[3 * 128 + 64 + lane]);
        #pragma unroll
        for (int s = 0; s < 3; ++s) {
            float o = 0.f;
            #pragma unroll
            for (int f = 0; f < 64; ++f) o += __shfl(r, f, 64) * Wl[s][f * 64 + lane];
            if (s < 2) o = (o > 0.f) ? scale * o : scale * alpha * expm1f(o);
            r = o;
        }
        outp[(size_t)m * 64 + lane] = r;
    }
}

extern "C" void kernel_launch(void* const* d_in, const int* in_sizes, int n_in,
                              void* d_out, int out_size, void* d_ws, size_t ws_size,
                              hipStream_t stream) {
    const float* x = (const float*)d_in[15];

    float* ws = (float*)d_ws;
    double* dstats_all = (double*)ws;                 // 1536 doubles -> [0, 3072)
    float*  cm         = ws + 3072;                   // 256
    float*  S          = ws + 3328;                   // 16
    float*  cvec       = ws + 3344;                   // 4
    float*  musig_all  = ws + 3584;                   // 3*512 -> [3584, 5120)
    int*    rowptr_all = (int*)(ws + 5120);           // 12*768 -> [5120, 14336)
    int*    colsrc_all = (int*)(ws + 14336);          // 12*8192 -> [14336, 112640)
    float*  A_buf      = ws + 112640;                 // 4*128*353*64 = 11,567,104
    float*  B_buf      = A_buf + (size_t)4 * 128 * 353 * 64;  // 4*128*177*64
    float*  ALLb       = A_buf;                       // aliases A (dead by layer 2)
    const size_t as0 = (size_t)128 * 353 * 64;
    const size_t as1 = (size_t)128 * 177 * 64;

    // edge set table (graph-0 structure shared by all 128 graphs)
    EdgeSets ES;
    int nemax[3] = {0, 0, 0};
    for (int s = 0; s < 12; ++s) {
        const int* e = (const int*)d_in[s];
        int E = in_sizes[s] / 2;
        ES.src[s] = e;
        ES.dst[s] = e + E;
        ES.ne[s] = E / 128;
        int lay = s % 3;
        if (ES.ne[s] > nemax[lay]) nemax[lay] = ES.ne[s];
    }

    // dynamic LDS sizes per layer (mirror in-kernel pointer chain)
    static const int NPIN_L[3] = {706, 353, 177};
    int SM[3];
    for (int L = 0; L < 3; ++L) {
        int np = NPIN_L[L];
        int floats = 4 * np + 128 + ((L == 0) ? 8 : 128) + ((L > 0) ? 4096 : 0)
                   + ((L == 0) ? 706 * 3 : 0);
        SM[L] = 8192 + floats * 4 + 2 * (np + 1) + 2 * nemax[L] + 8;
    }
    (void)hipFuncSetAttribute(reinterpret_cast<const void*>(&layer_kernel<0>),
                              hipFuncAttributeMaxDynamicSharedMemorySize, SM[0]);
    (void)hipFuncSetAttribute(reinterpret_cast<const void*>(&layer_kernel<1>),
                              hipFuncAttributeMaxDynamicSharedMemorySize, SM[1]);
    (void)hipFuncSetAttribute(reinterpret_cast<const void*>(&layer_kernel<2>),
                              hipFuncAttributeMaxDynamicSharedMemorySize, SM[2]);

    zero_kernel<<<cdiv(3584, 256), 256, 0, stream>>>(ws, 3584);
    csr_build_kernel<<<12, 768, 0, stream>>>(ES, rowptr_all, colsrc_all);

    for (int L = 0; L < 3; ++L) {
        LayerArgs LA;
        for (int j = 0; j < 4; ++j) {
            int s = j * 3 + L;
            LA.rowptr[j] = rowptr_all + s * 768;
            LA.colsrc[j] = colsrc_all + s * 8192;
            LA.ne[j] = ES.ne[s];
            if (L == 0) { LA.h[j] = x;               LA.out[j] = A_buf + j * as0; }
            if (L == 1) { LA.h[j] = A_buf + j * as0; LA.out[j] = B_buf + j * as1; }
            if (L == 2) { LA.h[j] = B_buf + j * as1; LA.out[j] = ALLb + (size_t)j * M_FINAL * 64; }
        }
        LA.musig_prev = (L == 0) ? nullptr : (musig_all + (L - 1) * 512);
        LA.dstats = dstats_all + L * 512;
        LA.W    = (const float*)d_in[16 + 4 * L];
        LA.as   = (const float*)d_in[17 + 4 * L];
        LA.ad   = (const float*)d_in[18 + 4 * L];
        LA.bias = (const float*)d_in[19 + 4 * L];
        if (L == 0) layer_kernel<0><<<512, 512, SM[0], stream>>>(LA);
        if (L == 1) layer_kernel<1><<<512, 512, SM[1], stream>>>(LA);
        if (L == 2) layer_kernel<2><<<512, 512, SM[2], stream>>>(LA);
        static const int NPOUT[3] = {353, 177, 89};
        bn_finalize_kernel<<<4, 64, 0, stream>>>(dstats_all + L * 512, musig_all + L * 512,
                                                 128 * NPOUT[L]);
    }

    // ---- fusion head ----
    const float* w_attn = (const float*)d_in[28];
    const float* w_lin0 = (const float*)d_in[29];
    const float* b_lin0 = (const float*)d_in[30];
    const float* w_link0 = (const float*)d_in[31];
    const float* w_linkl = (const float*)d_in[32];
    const float* w_link_ = (const float*)d_in[33];
    const float* musig2 = musig_all + 2 * 512;

    head_reduce_kernel<<<64, 256, 0, stream>>>(ALLb, musig2, w_attn, S, cm);
    fuse_small_kernel<<<1, 64, 0, stream>>>(S, cm, w_lin0, b_lin0, cvec);
    head_out_kernel<<<128, 256, 0, stream>>>(ALLb, musig2, cvec, w_link0, w_linkl, w_link_,
                                             (float*)d_out);
}

// Round 6
// 814.485 us; speedup vs baseline: 2.0252x; 1.0678x over previous
//
#include <hip/hip_runtime.h>
#include <math.h>

#define DIM 64
#define M_FINAL (128*89)   // 11392 final rows

static inline int cdiv(int a, int b) { return (a + b - 1) / b; }

__device__ inline float rdlane(float v, int l) {
    return __int_as_float(__builtin_amdgcn_readlane(__float_as_int(v), l));
}

struct EdgeSets {
    const int* src[12];
    const int* dst[12];
    int ne[12];
};

struct LayerArgs {
    const float* h[4];        // per-view input rows
    float* out[4];            // per-view pooled output rows
    const int* rowptr[4];
    const int* colsrc[4];
    int ne[4];                // graph-0 edge count per view
    int nemax;                // max over views (LDS layout)
    const float* musig_prev;  // + j*128 ; unused for L==0
    const float* eff;         // + j*132 : waSe[64], waDe[64], cS, cD ; L>0
    double* dstats;           // + j*128
    const float* W;
    const float* as;
    const float* ad;
    const float* bias;
};

// ---------------- misc ----------------

__global__ void zero_kernel(float* __restrict__ p, int n) {
    int i = blockIdx.x * blockDim.x + threadIdx.x;
    if (i < n) p[i] = 0.f;
}

// ---------------- fused CSR build: one block per edge set ------------------
__global__ __launch_bounds__(768)
void csr_build_kernel(EdgeSets ES, int* __restrict__ rowptr_all,
                      int* __restrict__ colsrc_all) {
    __shared__ int cnt[768];
    __shared__ int cur[768];
    const int s = blockIdx.x;
    const int lay = s % 3;
    const int n = (lay == 0) ? 706 : (lay == 1) ? 353 : 177;
    const int ne = ES.ne[s];
    const int* __restrict__ src = ES.src[s];
    const int* __restrict__ dst = ES.dst[s];
    int* __restrict__ rowptr = rowptr_all + s * 768;
    int* __restrict__ colsrc = colsrc_all + s * 8192;
    const int t = threadIdx.x;

    cnt[t] = 0;
    __syncthreads();
    for (int k = t; k < ne; k += 768) atomicAdd(&cnt[dst[k]], 1);
    __syncthreads();
    int v = cnt[t];
    for (int off = 1; off < 768; off <<= 1) {
        int add = (t >= off) ? cnt[t - off] : 0;
        __syncthreads();
        cnt[t] += add;
        __syncthreads();
    }
    int excl = cnt[t] - v;
    if (t < n) { rowptr[t] = excl; cur[t] = excl; }
    if (t == n - 1) rowptr[n] = cnt[t];
    __syncthreads();
    for (int k = t; k < ne; k += 768) {
        int pos = atomicAdd(&cur[dst[k]], 1);
        colsrc[pos] = src[k];
    }
}

// ---------------- fused per-layer mega kernel ------------------------------
// block = (view, graph); 512 threads = 8 waves.
// P1 stage (CSR->LDS, Wreg VGPRs, L0: h->LDS float4-padded)
// P2 s-dots (L>0: global rows + shfl reduce; L0: fused into stage)
// P3 per-node online softmax -> per-edge normalized weight stored in LDS
// P4 per-cluster: weighted gather + readlane-matvec + relu + pool + BN stats
template<int L>
__global__ __launch_bounds__(512, 4)
void layer_kernel(LayerArgs A) {
    constexpr int NPIN  = (L == 0) ? 706 : (L == 1) ? 353 : 177;
    constexpr int NPOUT = (NPIN + 1) / 2;   // 353, 177, 89

    extern __shared__ char smem[];
    double* sred = (double*)smem;                              // 8192 B
    uint2* epk = (uint2*)(smem + 8192);                        // nemax * 8 B
    float* fp = (float*)(smem + 8192 + (size_t)A.nemax * 8);
    float* sSrc = fp; fp += NPIN;
    float* sDst = fp; fp += NPIN;
    float* hL4  = fp; if constexpr (L == 0) fp += 706 * 4;
    float* waL0 = fp; if constexpr (L == 0) fp += 8;
    unsigned short* rp16 = (unsigned short*)fp;                // NPIN+2

    const int bid = blockIdx.x;
    const int j = bid >> 7;            // view
    const int g = bid & 127;           // graph
    const int tid = threadIdx.x;
    const int wave = tid >> 6;
    const int lane = tid & 63;

    const float* __restrict__ h = A.h[j];
    const int* __restrict__ rowptr = A.rowptr[j];
    const int* __restrict__ colsrc = A.colsrc[j];
    const float* __restrict__ W = A.W;
    const int ne = A.ne[j];
    const size_t gbase = (size_t)g * NPIN;

    // ---- phase 1: stage ----
    for (int k = tid; k <= NPIN; k += 512) rp16[k] = (unsigned short)rowptr[k];
    for (int k = tid; k < ne; k += 512) epk[k] = make_uint2(0u, (unsigned)colsrc[k]);

    float Wreg[64];
    float rsv = 1.f, rmv = 0.f, waSe = 0.f, waDe = 0.f, cS = 0.f, cD = 0.f;
    if constexpr (L > 0) {
        #pragma unroll
        for (int f = 0; f < 64; ++f) Wreg[f] = W[f * 64 + lane];
        waSe = A.eff[j * 132 + lane];
        waDe = A.eff[j * 132 + 64 + lane];
        cS = A.eff[j * 132 + 128];
        cD = A.eff[j * 132 + 129];
        rsv = A.musig_prev[j * 128 + 64 + lane];
        rmv = A.musig_prev[j * 128 + lane] * rsv;
    } else {
        if (tid < 6) {                    // wa_{src,dst}[f] = sum_d W[f][d]*a[d]
            int f = (tid < 3) ? tid : tid - 3;
            const float* av = (tid < 3) ? A.as : A.ad;
            float acc = 0.f;
            for (int d = 0; d < 64; ++d) acc += W[f * 64 + d] * av[d];
            waL0[tid] = acc;
        }
    }
    __syncthreads();

    // ---- phase 2: s-dots (+ L0: h staging) ----
    if constexpr (L == 0) {
        const float* hb = h + (size_t)g * (706 * 3);
        for (int r = tid; r < 706; r += 512) {
            float h0 = hb[r * 3], h1 = hb[r * 3 + 1], h2 = hb[r * 3 + 2];
            hL4[r * 4] = h0; hL4[r * 4 + 1] = h1; hL4[r * 4 + 2] = h2; hL4[r * 4 + 3] = 0.f;
            sSrc[r] = h0 * waL0[0] + h1 * waL0[1] + h2 * waL0[2];
            sDst[r] = h0 * waL0[3] + h1 * waL0[4] + h2 * waL0[5];
        }
    } else {
        for (int r = wave; r < NPIN; r += 8) {
            float hv = h[(gbase + r) * 64 + lane];
            float a = hv * waSe;
            float b = hv * waDe;
            for (int off = 32; off > 0; off >>= 1) {
                a += __shfl_down(a, off, 64);
                b += __shfl_down(b, off, 64);
            }
            if (lane == 0) { sSrc[r] = a - cS; sDst[r] = b - cD; }
        }
    }
    __syncthreads();

    // ---- phase 3: per-node online softmax -> normalized edge weights ----
    for (int r = tid; r < NPIN; r += 512) {
        int s0 = rp16[r], e0 = rp16[r + 1];
        float sd = sDst[r];
        float m = -1e30f, z = 0.f;
        for (int k = s0; k < e0; ++k) {
            float v = sSrc[epk[k].y] + sd;
            v = (v >= 0.f) ? v : 0.2f * v;
            if (v > m) { z = z * __expf(m - v) + 1.f; m = v; }
            else z += __expf(v - m);
        }
        float invz = 1.f / z;
        for (int k = s0; k < e0; ++k) {
            float v = sSrc[epk[k].y] + sd;
            v = (v >= 0.f) ? v : 0.2f * v;
            ((float*)epk)[2 * k] = __expf(v - m) * invz;
        }
    }
    __syncthreads();

    // ---- phase 4: aggregate + matvec + relu + pool + BN stats ----
    float w0 = 0.f, w1 = 0.f, w2 = 0.f;
    if constexpr (L == 0) { w0 = W[lane]; w1 = W[64 + lane]; w2 = W[128 + lane]; }
    const float b_l = A.bias[lane];
    float* outj = A.out[j];
    const float4* hL4v = (const float4*)hL4;
    double bs = 0.0, bs2 = 0.0;

    for (int c = wave; c < NPOUT; c += 8) {
        float vmax = 0.f;                      // children are relu'd -> >= 0
        #pragma unroll
        for (int ch = 0; ch < 2; ++ch) {
            int child = 2 * c + ch;
            if (child >= NPIN) break;
            int s0 = rp16[child], e0 = rp16[child + 1];
            float o;
            if constexpr (L == 0) {
                float a0 = 0.f, a1 = 0.f, a2 = 0.f;
                for (int k = s0; k < e0; ++k) {
                    uint2 ev = epk[k];
                    float p = __uint_as_float(ev.x);
                    float4 hv = hL4v[ev.y];
                    a0 += p * hv.x; a1 += p * hv.y; a2 += p * hv.z;
                }
                o = a0 * w0 + a1 * w1 + a2 * w2 + b_l;
            } else {
                float acc = 0.f;
                int k = s0;
                for (; k + 2 <= e0; k += 2) {
                    uint2 ev0 = epk[k], ev1 = epk[k + 1];
                    float hv0 = h[(gbase + ev0.y) * 64 + lane];
                    float hv1 = h[(gbase + ev1.y) * 64 + lane];
                    acc += __uint_as_float(ev0.x) * hv0 + __uint_as_float(ev1.x) * hv1;
                }
                if (k < e0) {
                    uint2 ev = epk[k];
                    acc += __uint_as_float(ev.x) * h[(gbase + ev.y) * 64 + lane];
                }
                float aggbn = acc * rsv - rmv;     // sum(p)=1 -> fold BN
                o = b_l;
                #pragma unroll
                for (int f = 0; f < 64; ++f) o += rdlane(aggbn, f) * Wreg[f];
            }
            vmax = fmaxf(vmax, fmaxf(o, 0.f));
        }
        outj[((size_t)g * NPOUT + c) * 64 + lane] = vmax;
        bs += vmax;
        bs2 += (double)vmax * vmax;
    }
    sred[wave * 64 + lane] = bs;
    sred[512 + wave * 64 + lane] = bs2;
    __syncthreads();
    if (wave == 0) {
        double t1 = 0.0, t2 = 0.0;
        #pragma unroll
        for (int w = 0; w < 8; ++w) {
            t1 += sred[w * 64 + lane];
            t2 += sred[512 + w * 64 + lane];
        }
        atomicAdd(A.dstats + j * 128 + lane, t1);
        atomicAdd(A.dstats + j * 128 + 64 + lane, t2);
    }
}

// BN finalize + precompute next layer's effective s-dot vectors:
// eff[j][f] = rs[j][f] * (W_next @ a)[f] ; c = sum_f mu[j][f]*eff[j][f]
__global__ void bn_finalize_kernel(const double* __restrict__ dstats,
                                   float* __restrict__ musig, int n_rows,
                                   const float* __restrict__ Wn,
                                   const float* __restrict__ asn,
                                   const float* __restrict__ adn,
                                   float* __restrict__ eff) {
    int jv = blockIdx.x;           // view
    int f = threadIdx.x;           // 64
    double mu = dstats[jv * 128 + f] / n_rows;
    double var = dstats[jv * 128 + 64 + f] / n_rows - mu * mu;
    float rs = rsqrtf((float)var + 1e-5f);
    musig[jv * 128 + f] = (float)mu;
    musig[jv * 128 + 64 + f] = rs;
    if (Wn != nullptr) {
        float wvS = 0.f, wvD = 0.f;
        for (int d = 0; d < 64; ++d) {
            float w = Wn[f * 64 + d];
            wvS += w * asn[d];
            wvD += w * adn[d];
        }
        float eS = rs * wvS, eD = rs * wvD;
        eff[jv * 132 + f] = eS;
        eff[jv * 132 + 64 + f] = eD;
        float cS = (float)mu * eS, cD = (float)mu * eD;
        for (int off = 32; off > 0; off >>= 1) {
            cS += __shfl_down(cS, off, 64);
            cD += __shfl_down(cD, off, 64);
        }
        if (f == 0) { eff[jv * 132 + 128] = cS; eff[jv * 132 + 129] = cD; }
    }
}

// ---------------- fused head reduce: Bm dots -> S (BmT Bm) + column means --
__global__ __launch_bounds__(256)
void head_reduce_kernel(const float* __restrict__ ALL, const float* __restrict__ musig,
                        const float* __restrict__ w_attn,
                        float* __restrict__ S, float* __restrict__ cm) {
    __shared__ float S_loc[16];
    __shared__ float cm_loc[256];
    const int t = threadIdx.x, wave = t >> 6, lane = t & 63;
    if (t < 16) S_loc[t] = 0.f;
    cm_loc[t] = 0.f;
    __syncthreads();
    const float wa = w_attn[lane];
    float cacc[4] = {0.f, 0.f, 0.f, 0.f};
    for (int m = blockIdx.x * 4 + wave; m < M_FINAL; m += gridDim.x * 4) {
        float b4[4];
        float csum = 0.f;
        #pragma unroll
        for (int v = 0; v < 4; ++v) {
            float val = (ALL[((size_t)v * M_FINAL + m) * 64 + lane] - musig[v * 128 + lane])
                        * musig[v * 128 + 64 + lane];
            csum += val;
            float p = val * wa;
            for (int off = 32; off > 0; off >>= 1) p += __shfl_down(p, off, 64);
            b4[v] = __shfl(p, 0, 64);
        }
        cacc[m & 3] += csum;
        if (lane < 16) atomicAdd(&S_loc[lane], b4[lane >> 2] * b4[lane & 3]);
    }
    #pragma unroll
    for (int q = 0; q < 4; ++q) atomicAdd(&cm_loc[q * 64 + lane], cacc[q]);
    __syncthreads();
    if (t < 16) atomicAdd(&S[t], S_loc[t]);
    atomicAdd(&cm[t], cm_loc[t]);
}

__global__ void fuse_small_kernel(const float* __restrict__ S, const float* __restrict__ cm,
                                  const float* __restrict__ w_lin0, const float* __restrict__ b_lin0,
                                  float* __restrict__ cvec) {
    if (threadIdx.x != 0 || blockIdx.x != 0) return;
    float cn[4];
    for (int v = 0; v < 4; ++v) cn[v] = sqrtf(S[v * 4 + v]);
    float A[16];
    for (int u = 0; u < 4; ++u) {
        float row[4]; float mx = -1e30f;
        for (int v = 0; v < 4; ++v) {
            float g = S[u * 4 + v] / (cn[u] * cn[v]);
            g = (g >= 0.f) ? g : 0.1f * g;       // leaky_relu 0.1
            row[v] = g; mx = fmaxf(mx, g);
        }
        float sum = 0.f;
        for (int v = 0; v < 4; ++v) { row[v] = expf(row[v] - mx); sum += row[v]; }
        for (int v = 0; v < 4; ++v) A[u * 4 + v] = row[v] / sum;
    }
    float e4[4];
    for (int v = 0; v < 4; ++v) {
        float a = b_lin0[v];
        for (int c = 0; c < 256; ++c) a += (cm[c] / (float)M_FINAL) * w_lin0[c * 4 + v];
        e4[v] = a;
    }
    float mx = fmaxf(fmaxf(e4[0], e4[1]), fmaxf(e4[2], e4[3]));
    float sum = 0.f, w[4];
    for (int v = 0; v < 4; ++v) { w[v] = expf(e4[v] - mx); sum += w[v]; }
    for (int v = 0; v < 4; ++v) w[v] /= sum;
    for (int k = 0; k < 4; ++k) {
        float c = 0.f;
        for (int v = 0; v < 4; ++v) c += A[k * 4 + v] * w[v];
        cvec[k] = c;
    }
}

// ---------------- fused head output: combine + 3 matvecs (selu,selu,none) --
__global__ __launch_bounds__(256)
void head_out_kernel(const float* __restrict__ ALL, const float* __restrict__ musig,
                     const float* __restrict__ cvec,
                     const float* __restrict__ W0, const float* __restrict__ W1,
                     const float* __restrict__ W2, float* __restrict__ outp) {
    __shared__ float Wl[3][64 * 64];   // 48 KB
    const int t = threadIdx.x, wave = t >> 6, lane = t & 63;
    for (int k = t; k < 4096; k += 256) {
        Wl[0][k] = W0[k]; Wl[1][k] = W1[k]; Wl[2][k] = W2[k];
    }
    __syncthreads();
    const float c0 = cvec[0], c1 = cvec[1], c2 = cvec[2], c3 = cvec[3];
    const float scale = 1.0507009873554805f;
    const float alpha = 1.6732632423543772f;
    for (int m = blockIdx.x * 4 + wave; m < M_FINAL; m += gridDim.x * 4) {
        float r =
            c0 * ((ALL[((size_t)0 * M_FINAL + m) * 64 + lane] - musig[0 * 128 + lane]) * musig[0 * 128 + 64 + lane]) +
            c1 * ((ALL[((size_t)1 * M_FINAL + m) * 64 + lane] - musig[1 * 128 + lane]) * musig[1 * 128 + 64 + lane]) +
            c2 * ((ALL[((size_t)2 * M_FINAL + m) * 64 + lane] - musig[2 * 128 + lane]) * musig[2 * 128 + 64 + lane]) +
            c3 * ((ALL[((size_t)3 * M_FINAL + m) * 64 + lane] - musig[3 * 128 + lane]) * musig[3 * 128 + 64 + lane]);
        #pragma unroll
        for (int s = 0; s < 3; ++s) {
            float o = 0.f;
            #pragma unroll
            for (int f = 0; f < 64; ++f) o += __shfl(r, f, 64) * Wl[s][f * 64 + lane];
            if (s < 2) o = (o > 0.f) ? scale * o : scale * alpha * expm1f(o);
            r = o;
        }
        outp[(size_t)m * 64 + lane] = r;
    }
}

extern "C" void kernel_launch(void* const* d_in, const int* in_sizes, int n_in,
                              void* d_out, int out_size, void* d_ws, size_t ws_size,
                              hipStream_t stream) {
    const float* x = (const float*)d_in[15];

    float* ws = (float*)d_ws;
    double* dstats_all = (double*)ws;                 // 1536 doubles -> [0, 3072)
    float*  cm         = ws + 3072;                   // 256
    float*  S          = ws + 3328;                   // 16
    float*  cvec       = ws + 3344;                   // 4
    float*  musig_all  = ws + 3584;                   // 3*512 -> [3584, 5120)
    float*  eff_all    = ws + 5120;                   // 2*528 -> [5120, 6176)
    int*    rowptr_all = (int*)(ws + 6176);           // 12*768 -> [6176, 15392)
    int*    colsrc_all = (int*)(ws + 15392);          // 12*8192 -> [15392, 113696)
    float*  A_buf      = ws + 114176;                 // 4*128*353*64 = 11,567,104
    float*  B_buf      = A_buf + (size_t)4 * 128 * 353 * 64;  // 4*128*177*64
    float*  ALLb       = A_buf;                       // aliases A (dead by layer 2)
    const size_t as0 = (size_t)128 * 353 * 64;
    const size_t as1 = (size_t)128 * 177 * 64;

    // edge set table (graph-0 structure shared by all 128 graphs)
    EdgeSets ES;
    int nemax[3] = {0, 0, 0};
    for (int s = 0; s < 12; ++s) {
        const int* e = (const int*)d_in[s];
        int E = in_sizes[s] / 2;
        ES.src[s] = e;
        ES.dst[s] = e + E;
        ES.ne[s] = E / 128;
        int lay = s % 3;
        if (ES.ne[s] > nemax[lay]) nemax[lay] = ES.ne[s];
    }

    // dynamic LDS sizes per layer (mirror in-kernel layout)
    static const int NPIN_L[3] = {706, 353, 177};
    int SM[3];
    for (int L = 0; L < 3; ++L) {
        int np = NPIN_L[L];
        int bytes = 8192 + nemax[L] * 8
                  + (2 * np + ((L == 0) ? (706 * 4 + 8) : 0)) * 4
                  + (np + 2) * 2;
        SM[L] = (bytes + 7) & ~7;
    }
    (void)hipFuncSetAttribute(reinterpret_cast<const void*>(&layer_kernel<0>),
                              hipFuncAttributeMaxDynamicSharedMemorySize, SM[0]);
    (void)hipFuncSetAttribute(reinterpret_cast<const void*>(&layer_kernel<1>),
                              hipFuncAttributeMaxDynamicSharedMemorySize, SM[1]);
    (void)hipFuncSetAttribute(reinterpret_cast<const void*>(&layer_kernel<2>),
                              hipFuncAttributeMaxDynamicSharedMemorySize, SM[2]);

    zero_kernel<<<cdiv(3584, 256), 256, 0, stream>>>(ws, 3584);
    csr_build_kernel<<<12, 768, 0, stream>>>(ES, rowptr_all, colsrc_all);

    static const int NPOUT[3] = {353, 177, 89};
    for (int L = 0; L < 3; ++L) {
        LayerArgs LA;
        for (int j = 0; j < 4; ++j) {
            int s = j * 3 + L;
            LA.rowptr[j] = rowptr_all + s * 768;
            LA.colsrc[j] = colsrc_all + s * 8192;
            LA.ne[j] = ES.ne[s];
            if (L == 0) { LA.h[j] = x;               LA.out[j] = A_buf + j * as0; }
            if (L == 1) { LA.h[j] = A_buf + j * as0; LA.out[j] = B_buf + j * as1; }
            if (L == 2) { LA.h[j] = B_buf + j * as1; LA.out[j] = ALLb + (size_t)j * M_FINAL * 64; }
        }
        LA.nemax = nemax[L];
        LA.musig_prev = (L == 0) ? nullptr : (musig_all + (L - 1) * 512);
        LA.eff = (L == 0) ? nullptr : (eff_all + (L - 1) * 528);
        LA.dstats = dstats_all + L * 512;
        LA.W    = (const float*)d_in[16 + 4 * L];
        LA.as   = (const float*)d_in[17 + 4 * L];
        LA.ad   = (const float*)d_in[18 + 4 * L];
        LA.bias = (const float*)d_in[19 + 4 * L];
        if (L == 0) layer_kernel<0><<<512, 512, SM[0], stream>>>(LA);
        if (L == 1) layer_kernel<1><<<512, 512, SM[1], stream>>>(LA);
        if (L == 2) layer_kernel<2><<<512, 512, SM[2], stream>>>(LA);

        const float* Wn = (L < 2) ? (const float*)d_in[16 + 4 * (L + 1)] : nullptr;
        const float* an = (L < 2) ? (const float*)d_in[17 + 4 * (L + 1)] : nullptr;
        const float* dn = (L < 2) ? (const float*)d_in[18 + 4 * (L + 1)] : nullptr;
        float* effn = (L < 2) ? (eff_all + L * 528) : nullptr;
        bn_finalize_kernel<<<4, 64, 0, stream>>>(dstats_all + L * 512, musig_all + L * 512,
                                                 128 * NPOUT[L], Wn, an, dn, effn);
    }

    // ---- fusion head ----
    const float* w_attn = (const float*)d_in[28];
    const float* w_lin0 = (const float*)d_in[29];
    const float* b_lin0 = (const float*)d_in[30];
    const float* w_link0 = (const float*)d_in[31];
    const float* w_linkl = (const float*)d_in[32];
    const float* w_link_ = (const float*)d_in[33];
    const float* musig2 = musig_all + 2 * 512;

    head_reduce_kernel<<<64, 256, 0, stream>>>(ALLb, musig2, w_attn, S, cm);
    fuse_small_kernel<<<1, 64, 0, stream>>>(S, cm, w_lin0, b_lin0, cvec);
    head_out_kernel<<<128, 256, 0, stream>>>(ALLb, musig2, cvec, w_link0, w_linkl, w_link_,
                                             (float*)d_out);
}

// Round 7
// 737.621 us; speedup vs baseline: 2.2363x; 1.1042x over previous
//
#include <hip/hip_runtime.h>
#include <math.h>

#define DIM 64
#define M_FINAL (128*89)   // 11392 final rows

static inline int cdiv(int a, int b) { return (a + b - 1) / b; }

__device__ inline float rdlane(float v, int l) {
    return __int_as_float(__builtin_amdgcn_readlane(__float_as_int(v), l));
}

struct EdgeSets {
    const int* src[12];
    const int* dst[12];
    int ne[12];
};

struct L0Args {
    const float* x;
    float* out[4];
    const int* rowptr[4];
    const int* colsrc[4];
    int ne[4];
    int nemax;
    double* dstats;
    const float* W;
    const float* as;
    const float* ad;
    const float* bias;
};

struct AggArgs {
    const float* hp[4];       // projected rows (out-space)
    float* out[4];
    const int* rowptr[4];
    const int* colsrc[4];
    int ne[4];
    int nemax;
    const float* sS;          // [j][g][NPIN]
    const float* sD;
    const float* bias;
    double* dstats;
};

// ---------------- misc ----------------

__global__ void zero_kernel(float* __restrict__ p, int n) {
    int i = blockIdx.x * blockDim.x + threadIdx.x;
    if (i < n) p[i] = 0.f;
}

// ---------------- fused CSR build: one block per edge set ------------------
__global__ __launch_bounds__(768)
void csr_build_kernel(EdgeSets ES, int* __restrict__ rowptr_all,
                      int* __restrict__ colsrc_all) {
    __shared__ int cnt[768];
    __shared__ int cur[768];
    const int s = blockIdx.x;
    const int lay = s % 3;
    const int n = (lay == 0) ? 706 : (lay == 1) ? 353 : 177;
    const int ne = ES.ne[s];
    const int* __restrict__ src = ES.src[s];
    const int* __restrict__ dst = ES.dst[s];
    int* __restrict__ rowptr = rowptr_all + s * 768;
    int* __restrict__ colsrc = colsrc_all + s * 8192;
    const int t = threadIdx.x;

    cnt[t] = 0;
    __syncthreads();
    for (int k = t; k < ne; k += 768) atomicAdd(&cnt[dst[k]], 1);
    __syncthreads();
    int v = cnt[t];
    for (int off = 1; off < 768; off <<= 1) {
        int add = (t >= off) ? cnt[t - off] : 0;
        __syncthreads();
        cnt[t] += add;
        __syncthreads();
    }
    int excl = cnt[t] - v;
    if (t < n) { rowptr[t] = excl; cur[t] = excl; }
    if (t == n - 1) rowptr[n] = cnt[t];
    __syncthreads();
    for (int k = t; k < ne; k += 768) {
        int pos = atomicAdd(&cur[dst[k]], 1);
        colsrc[pos] = src[k];
    }
}

// ---------------- layer 0 mega kernel (in_dim=3, fused) --------------------
// block = (view, graph); 512 threads = 8 waves.
__global__ __launch_bounds__(512, 6)
void layer0_kernel(L0Args A) {
    constexpr int NPIN = 706, NPOUT = 353;
    constexpr int RPCNT = 708;

    extern __shared__ char smem[];
    double* sred = (double*)smem;                      // 8192 B
    float* fp = (float*)(smem + 8192);
    float* sSrc = fp; fp += NPIN;
    float* sDst = fp; fp += NPIN;
    float* mArr = fp; fp += NPIN;
    float* zArr = fp; fp += NPIN;
    float* hL4  = fp; fp += NPIN * 4;
    float* waL0 = fp; fp += 8;
    unsigned short* rp16 = (unsigned short*)fp;
    unsigned short* cs16 = rp16 + RPCNT;

    const int bid = blockIdx.x;
    const int j = bid >> 7;
    const int g = bid & 127;
    const int tid = threadIdx.x;
    const int wave = tid >> 6;
    const int lane = tid & 63;

    const int* __restrict__ rowptr = A.rowptr[j];
    const int* __restrict__ colsrc = A.colsrc[j];
    const float* __restrict__ W = A.W;
    const int ne = A.ne[j];

    // stage CSR + wa
    for (int k = tid; k <= NPIN; k += 512) rp16[k] = (unsigned short)rowptr[k];
    for (int k = tid; k < ne; k += 512) cs16[k] = (unsigned short)colsrc[k];
    if (tid < 6) {                    // wa_{src,dst}[f] = sum_d W[f][d]*a[d]
        int f = (tid < 3) ? tid : tid - 3;
        const float* av = (tid < 3) ? A.as : A.ad;
        float acc = 0.f;
        for (int d = 0; d < 64; ++d) acc += W[f * 64 + d] * av[d];
        waL0[tid] = acc;
    }
    __syncthreads();

    // h staging + s-dots
    {
        const float* hb = A.x + (size_t)g * (NPIN * 3);
        for (int r = tid; r < NPIN; r += 512) {
            float h0 = hb[r * 3], h1 = hb[r * 3 + 1], h2 = hb[r * 3 + 2];
            hL4[r * 4] = h0; hL4[r * 4 + 1] = h1; hL4[r * 4 + 2] = h2; hL4[r * 4 + 3] = 0.f;
            sSrc[r] = h0 * waL0[0] + h1 * waL0[1] + h2 * waL0[2];
            sDst[r] = h0 * waL0[3] + h1 * waL0[4] + h2 * waL0[5];
        }
    }
    __syncthreads();

    // per-node online softmax stats (m, 1/z)
    for (int r = tid; r < NPIN; r += 512) {
        int s0 = rp16[r], e0 = rp16[r + 1];
        float sd = sDst[r];
        float m = -1e30f, z = 0.f;
        for (int k = s0; k < e0; ++k) {
            float v = sSrc[cs16[k]] + sd;
            v = (v >= 0.f) ? v : 0.2f * v;
            if (v > m) { z = z * __expf(m - v) + 1.f; m = v; }
            else z += __expf(v - m);
        }
        mArr[r] = m;
        zArr[r] = 1.f / z;
    }
    __syncthreads();

    // aggregate (3-dim) + tiny matvec + relu + pool + BN stats
    const float w0 = W[lane], w1 = W[64 + lane], w2 = W[128 + lane];
    const float b_l = A.bias[lane];
    float* outj = A.out[j];
    const float4* hL4v = (const float4*)hL4;
    double bs = 0.0, bs2 = 0.0;

    for (int c = wave; c < NPOUT; c += 8) {
        float vmax = 0.f;
        #pragma unroll
        for (int ch = 0; ch < 2; ++ch) {
            int child = 2 * c + ch;
            int s0 = rp16[child], e0 = rp16[child + 1];
            float sd = sDst[child];
            float m = mArr[child], iz = zArr[child];
            float a0 = 0.f, a1 = 0.f, a2 = 0.f;
            for (int k = s0; k < e0; ++k) {
                int sl = cs16[k];
                float v = sSrc[sl] + sd;
                v = (v >= 0.f) ? v : 0.2f * v;
                float p = __expf(v - m);
                float4 hv = hL4v[sl];
                a0 += p * hv.x; a1 += p * hv.y; a2 += p * hv.z;
            }
            float o = (a0 * w0 + a1 * w1 + a2 * w2) * iz + b_l;
            vmax = fmaxf(vmax, fmaxf(o, 0.f));
        }
        outj[((size_t)g * NPOUT + c) * 64 + lane] = vmax;
        bs += vmax;
        bs2 += (double)vmax * vmax;
    }
    sred[wave * 64 + lane] = bs;
    sred[512 + wave * 64 + lane] = bs2;
    __syncthreads();
    if (wave == 0) {
        double t1 = 0.0, t2 = 0.0;
        #pragma unroll
        for (int w = 0; w < 8; ++w) {
            t1 += sred[w * 64 + lane];
            t2 += sred[512 + w * 64 + lane];
        }
        atomicAdd(A.dstats + j * 128 + lane, t1);
        atomicAdd(A.dstats + j * 128 + 64 + lane, t2);
    }
}

// BN finalize; optionally fold stats into next layer's weight:
// Wp[f][d] = rs[f]*Wn[f][d]; csh[d] = sum_f mu[f]*rs[f]*Wn[f][d]
__global__ void bn_finalize_kernel(const double* __restrict__ dstats,
                                   float* __restrict__ musig, int n_rows,
                                   const float* __restrict__ Wn,
                                   float* __restrict__ Wp, float* __restrict__ csh) {
    __shared__ float mur[128];
    int jv = blockIdx.x;           // view
    int d = threadIdx.x;           // 64
    double mu = dstats[jv * 128 + d] / n_rows;
    double var = dstats[jv * 128 + 64 + d] / n_rows - mu * mu;
    float rs = rsqrtf((float)var + 1e-5f);
    musig[jv * 128 + d] = (float)mu;
    musig[jv * 128 + 64 + d] = rs;
    if (Wn != nullptr) {
        mur[d] = (float)mu; mur[64 + d] = rs;
        __syncthreads();
        float c = 0.f;
        for (int f = 0; f < 64; ++f) {
            float wp = mur[64 + f] * Wn[f * 64 + d];
            Wp[jv * 4096 + f * 64 + d] = wp;
            c += mur[f] * wp;
        }
        csh[jv * 64 + d] = c;
    }
}

// ---------------- projection: HP = h @ W' - c (in-place) + s-dots ----------
// grid (chunks, view); block 256 = 4 waves; wave per row; lane = out dim.
__global__ __launch_bounds__(256, 4)
void proj_kernel(float* __restrict__ buf, const float* __restrict__ Wp_all,
                 const float* __restrict__ csh_all,
                 const float* __restrict__ a_s, const float* __restrict__ a_d,
                 float* __restrict__ sS, float* __restrict__ sD, int npin) {
    const int j = blockIdx.y;
    const int lane = threadIdx.x & 63, wave = threadIdx.x >> 6;
    const int R = 128 * npin;
    float* h = buf + (size_t)j * R * 64;
    const float* Wp = Wp_all + j * 4096;
    float Wreg[64];
    #pragma unroll
    for (int f = 0; f < 64; ++f) Wreg[f] = Wp[f * 64 + lane];
    const float cst = csh_all[j * 64 + lane];
    const float asv = a_s[lane], adv = a_d[lane];
    const int nw = gridDim.x * 4;
    for (int r = blockIdx.x * 4 + wave; r < R; r += nw) {
        float v = h[(size_t)r * 64 + lane];
        float o0 = 0.f, o1 = 0.f, o2 = 0.f, o3 = 0.f;
        #pragma unroll
        for (int f = 0; f < 64; f += 4) {
            o0 += rdlane(v, f)     * Wreg[f];
            o1 += rdlane(v, f + 1) * Wreg[f + 1];
            o2 += rdlane(v, f + 2) * Wreg[f + 2];
            o3 += rdlane(v, f + 3) * Wreg[f + 3];
        }
        float o = ((o0 + o1) + (o2 + o3)) - cst;
        h[(size_t)r * 64 + lane] = o;
        float a = o * asv, b = o * adv;
        for (int off = 32; off > 0; off >>= 1) {
            a += __shfl_down(a, off, 64);
            b += __shfl_down(b, off, 64);
        }
        if (lane == 0) { sS[j * R + r] = a; sD[j * R + r] = b; }
    }
}

// ---------------- aggregation (L>0): softmax + gather + pool + BN stats ----
template<int NPIN>
__global__ __launch_bounds__(512, 8)
void agg_kernel(AggArgs A) {
    constexpr int NPOUT = (NPIN + 1) / 2;
    constexpr int RPCNT = (NPIN + 3) & ~1;

    extern __shared__ char smem[];
    double* sred = (double*)smem;                      // 8192 B
    float* fp = (float*)(smem + 8192);
    float* sSrc = fp; fp += NPIN;
    float* sDst = fp; fp += NPIN;
    float* mArr = fp; fp += NPIN;
    float* zArr = fp; fp += NPIN;
    unsigned short* rp16 = (unsigned short*)fp;
    unsigned short* cs16 = rp16 + RPCNT;

    const int bid = blockIdx.x;
    const int j = bid >> 7;
    const int g = bid & 127;
    const int tid = threadIdx.x;
    const int wave = tid >> 6;
    const int lane = tid & 63;

    const float* __restrict__ hp = A.hp[j];
    const int* __restrict__ rowptr = A.rowptr[j];
    const int* __restrict__ colsrc = A.colsrc[j];
    const int ne = A.ne[j];
    const size_t gbase = (size_t)g * NPIN;
    const int sbase = (j * 128 + g) * NPIN;

    for (int k = tid; k <= NPIN; k += 512) rp16[k] = (unsigned short)rowptr[k];
    for (int k = tid; k < ne; k += 512) cs16[k] = (unsigned short)colsrc[k];
    for (int r = tid; r < NPIN; r += 512) {
        sSrc[r] = A.sS[sbase + r];
        sDst[r] = A.sD[sbase + r];
    }
    __syncthreads();

    for (int r = tid; r < NPIN; r += 512) {
        int s0 = rp16[r], e0 = rp16[r + 1];
        float sd = sDst[r];
        float m = -1e30f, z = 0.f;
        for (int k = s0; k < e0; ++k) {
            float v = sSrc[cs16[k]] + sd;
            v = (v >= 0.f) ? v : 0.2f * v;
            if (v > m) { z = z * __expf(m - v) + 1.f; m = v; }
            else z += __expf(v - m);
        }
        mArr[r] = m;
        zArr[r] = 1.f / z;
    }
    __syncthreads();

    const float b_l = A.bias[lane];
    float* outj = A.out[j];
    double bs = 0.0, bs2 = 0.0;

    for (int c = wave; c < NPOUT; c += 8) {
        float vmax = 0.f;
        #pragma unroll
        for (int ch = 0; ch < 2; ++ch) {
            int child = 2 * c + ch;
            if (child >= NPIN) break;
            int s0 = rp16[child], e0 = rp16[child + 1];
            float sd = sDst[child];
            float m = mArr[child], iz = zArr[child];
            float acc = 0.f;
            int k = s0;
            for (; k + 2 <= e0; k += 2) {
                int sl0 = cs16[k], sl1 = cs16[k + 1];
                float hv0 = hp[(gbase + sl0) * 64 + lane];
                float hv1 = hp[(gbase + sl1) * 64 + lane];
                float v0 = sSrc[sl0] + sd; v0 = (v0 >= 0.f) ? v0 : 0.2f * v0;
                float v1 = sSrc[sl1] + sd; v1 = (v1 >= 0.f) ? v1 : 0.2f * v1;
                acc += __expf(v0 - m) * hv0 + __expf(v1 - m) * hv1;
            }
            if (k < e0) {
                int sl = cs16[k];
                float hv = hp[(gbase + sl) * 64 + lane];
                float v = sSrc[sl] + sd; v = (v >= 0.f) ? v : 0.2f * v;
                acc += __expf(v - m) * hv;
            }
            float o = acc * iz + b_l;
            vmax = fmaxf(vmax, fmaxf(o, 0.f));
        }
        outj[((size_t)g * NPOUT + c) * 64 + lane] = vmax;
        bs += vmax;
        bs2 += (double)vmax * vmax;
    }
    sred[wave * 64 + lane] = bs;
    sred[512 + wave * 64 + lane] = bs2;
    __syncthreads();
    if (wave == 0) {
        double t1 = 0.0, t2 = 0.0;
        #pragma unroll
        for (int w = 0; w < 8; ++w) {
            t1 += sred[w * 64 + lane];
            t2 += sred[512 + w * 64 + lane];
        }
        atomicAdd(A.dstats + j * 128 + lane, t1);
        atomicAdd(A.dstats + j * 128 + 64 + lane, t2);
    }
}

// ---------------- fused head reduce: Bm dots -> S (BmT Bm) + column means --
__global__ __launch_bounds__(256)
void head_reduce_kernel(const float* __restrict__ ALL, const float* __restrict__ musig,
                        const float* __restrict__ w_attn,
                        float* __restrict__ S, float* __restrict__ cm) {
    __shared__ float S_loc[16];
    __shared__ float cm_loc[256];
    const int t = threadIdx.x, wave = t >> 6, lane = t & 63;
    if (t < 16) S_loc[t] = 0.f;
    cm_loc[t] = 0.f;
    __syncthreads();
    const float wa = w_attn[lane];
    float cacc[4] = {0.f, 0.f, 0.f, 0.f};
    for (int m = blockIdx.x * 4 + wave; m < M_FINAL; m += gridDim.x * 4) {
        float b4[4];
        float csum = 0.f;
        #pragma unroll
        for (int v = 0; v < 4; ++v) {
            float val = (ALL[((size_t)v * M_FINAL + m) * 64 + lane] - musig[v * 128 + lane])
                        * musig[v * 128 + 64 + lane];
            csum += val;
            float p = val * wa;
            for (int off = 32; off > 0; off >>= 1) p += __shfl_down(p, off, 64);
            b4[v] = __shfl(p, 0, 64);
        }
        cacc[m & 3] += csum;
        if (lane < 16) atomicAdd(&S_loc[lane], b4[lane >> 2] * b4[lane & 3]);
    }
    #pragma unroll
    for (int q = 0; q < 4; ++q) atomicAdd(&cm_loc[q * 64 + lane], cacc[q]);
    __syncthreads();
    if (t < 16) atomicAdd(&S[t], S_loc[t]);
    atomicAdd(&cm[t], cm_loc[t]);
}

__global__ void fuse_small_kernel(const float* __restrict__ S, const float* __restrict__ cm,
                                  const float* __restrict__ w_lin0, const float* __restrict__ b_lin0,
                                  float* __restrict__ cvec) {
    if (threadIdx.x != 0 || blockIdx.x != 0) return;
    float cn[4];
    for (int v = 0; v < 4; ++v) cn[v] = sqrtf(S[v * 4 + v]);
    float A[16];
    for (int u = 0; u < 4; ++u) {
        float row[4]; float mx = -1e30f;
        for (int v = 0; v < 4; ++v) {
            float g = S[u * 4 + v] / (cn[u] * cn[v]);
            g = (g >= 0.f) ? g : 0.1f * g;       // leaky_relu 0.1
            row[v] = g; mx = fmaxf(mx, g);
        }
        float sum = 0.f;
        for (int v = 0; v < 4; ++v) { row[v] = expf(row[v] - mx); sum += row[v]; }
        for (int v = 0; v < 4; ++v) A[u * 4 + v] = row[v] / sum;
    }
    float e4[4];
    for (int v = 0; v < 4; ++v) {
        float a = b_lin0[v];
        for (int c = 0; c < 256; ++c) a += (cm[c] / (float)M_FINAL) * w_lin0[c * 4 + v];
        e4[v] = a;
    }
    float mx = fmaxf(fmaxf(e4[0], e4[1]), fmaxf(e4[2], e4[3]));
    float sum = 0.f, w[4];
    for (int v = 0; v < 4; ++v) { w[v] = expf(e4[v] - mx); sum += w[v]; }
    for (int v = 0; v < 4; ++v) w[v] /= sum;
    for (int k = 0; k < 4; ++k) {
        float c = 0.f;
        for (int v = 0; v < 4; ++v) c += A[k * 4 + v] * w[v];
        cvec[k] = c;
    }
}

// ---------------- fused head output: combine + 3 matvecs (selu,selu,none) --
__global__ __launch_bounds__(256)
void head_out_kernel(const float* __restrict__ ALL, const float* __restrict__ musig,
                     const float* __restrict__ cvec,
                     const float* __restrict__ W0, const float* __restrict__ W1,
                     const float* __restrict__ W2, float* __restrict__ outp) {
    __shared__ float Wl[3][64 * 64];   // 48 KB
    const int t = threadIdx.x, wave = t >> 6, lane = t & 63;
    for (int k = t; k < 4096; k += 256) {
        Wl[0][k] = W0[k]; Wl[1][k] = W1[k]; Wl[2][k] = W2[k];
    }
    __syncthreads();
    const float c0 = cvec[0], c1 = cvec[1], c2 = cvec[2], c3 = cvec[3];
    const float scale = 1.0507009873554805f;
    const float alpha = 1.6732632423543772f;
    for (int m = blockIdx.x * 4 + wave; m < M_FINAL; m += gridDim.x * 4) {
        float r =
            c0 * ((ALL[((size_t)0 * M_FINAL + m) * 64 + lane] - musig[0 * 128 + lane]) * musig[0 * 128 + 64 + lane]) +
            c1 * ((ALL[((size_t)1 * M_FINAL + m) * 64 + lane] - musig[1 * 128 + lane]) * musig[1 * 128 + 64 + lane]) +
            c2 * ((ALL[((size_t)2 * M_FINAL + m) * 64 + lane] - musig[2 * 128 + lane]) * musig[2 * 128 + 64 + lane]) +
            c3 * ((ALL[((size_t)3 * M_FINAL + m) * 64 + lane] - musig[3 * 128 + lane]) * musig[3 * 128 + 64 + lane]);
        #pragma unroll
        for (int s = 0; s < 3; ++s) {
            float o0 = 0.f, o1 = 0.f, o2 = 0.f, o3 = 0.f;
            #pragma unroll
            for (int f = 0; f < 64; f += 4) {
                o0 += rdlane(r, f)     * Wl[s][f * 64 + lane];
                o1 += rdlane(r, f + 1) * Wl[s][(f + 1) * 64 + lane];
                o2 += rdlane(r, f + 2) * Wl[s][(f + 2) * 64 + lane];
                o3 += rdlane(r, f + 3) * Wl[s][(f + 3) * 64 + lane];
            }
            float o = (o0 + o1) + (o2 + o3);
            if (s < 2) o = (o > 0.f) ? scale * o : scale * alpha * expm1f(o);
            r = o;
        }
        outp[(size_t)m * 64 + lane] = r;
    }
}

extern "C" void kernel_launch(void* const* d_in, const int* in_sizes, int n_in,
                              void* d_out, int out_size, void* d_ws, size_t ws_size,
                              hipStream_t stream) {
    const float* x = (const float*)d_in[15];

    float* ws = (float*)d_ws;
    double* dstats_all = (double*)ws;                 // 1536 doubles -> [0, 3072)
    float*  cm         = ws + 3072;                   // 256
    float*  S          = ws + 3328;                   // 16
    float*  cvec       = ws + 3344;                   // 4
    float*  musig_all  = ws + 3584;                   // 3*512 -> [3584, 5120)
    float*  Wp_all     = ws + 5120;                   // 2*4*4096 -> [5120, 37888)
    float*  csh_all    = ws + 37888;                  // 2*4*64 -> [37888, 38400)
    int*    rowptr_all = (int*)(ws + 38400);          // 12*768 -> [38400, 47616)
    int*    colsrc_all = (int*)(ws + 47616);          // 12*8192 -> [47616, 145920)
    float*  sS1        = ws + 145920;                 // 180736
    float*  sD1        = sS1 + 180736;
    float*  sS2        = sD1 + 180736;                // 90624
    float*  sD2        = sS2 + 90624;
    float*  A_buf      = sD2 + 90624;                 // 4*128*353*64 = 11,567,104
    float*  B_buf      = A_buf + (size_t)4 * 128 * 353 * 64;  // 4*128*177*64
    float*  ALLb       = A_buf;                       // alias (A dead after agg<177> input swap)
    const size_t as0 = (size_t)128 * 353 * 64;
    const size_t as1 = (size_t)128 * 177 * 64;

    // edge sets (graph-0 structure shared by all 128 graphs)
    EdgeSets ES;
    int nemax[3] = {0, 0, 0};
    for (int s = 0; s < 12; ++s) {
        const int* e = (const int*)d_in[s];
        int E = in_sizes[s] / 2;
        ES.src[s] = e;
        ES.dst[s] = e + E;
        ES.ne[s] = E / 128;
        int lay = s % 3;
        if (ES.ne[s] > nemax[lay]) nemax[lay] = ES.ne[s];
    }

    // dynamic LDS sizes
    int SM0 = 8192 + (4 * 706 + 706 * 4 + 8) * 4 + (708 + nemax[0]) * 2;
    SM0 = (SM0 + 15) & ~15;
    int SMa1 = 8192 + (4 * 353) * 4 + (356 + nemax[1]) * 2;
    SMa1 = (SMa1 + 15) & ~15;
    int SMa2 = 8192 + (4 * 177) * 4 + (180 + nemax[2]) * 2;
    SMa2 = (SMa2 + 15) & ~15;
    (void)hipFuncSetAttribute(reinterpret_cast<const void*>(&layer0_kernel),
                              hipFuncAttributeMaxDynamicSharedMemorySize, SM0);
    (void)hipFuncSetAttribute(reinterpret_cast<const void*>(&agg_kernel<353>),
                              hipFuncAttributeMaxDynamicSharedMemorySize, SMa1);
    (void)hipFuncSetAttribute(reinterpret_cast<const void*>(&agg_kernel<177>),
                              hipFuncAttributeMaxDynamicSharedMemorySize, SMa2);

    zero_kernel<<<cdiv(3584, 256), 256, 0, stream>>>(ws, 3584);
    csr_build_kernel<<<12, 768, 0, stream>>>(ES, rowptr_all, colsrc_all);

    // ---- layer 0 ----
    {
        L0Args A;
        A.x = x;
        for (int j = 0; j < 4; ++j) {
            int s = j * 3;
            A.rowptr[j] = rowptr_all + s * 768;
            A.colsrc[j] = colsrc_all + s * 8192;
            A.ne[j] = ES.ne[s];
            A.out[j] = A_buf + j * as0;
        }
        A.nemax = nemax[0];
        A.dstats = dstats_all;
        A.W = (const float*)d_in[16];
        A.as = (const float*)d_in[17];
        A.ad = (const float*)d_in[18];
        A.bias = (const float*)d_in[19];
        layer0_kernel<<<512, 512, SM0, stream>>>(A);
    }
    bn_finalize_kernel<<<4, 64, 0, stream>>>(dstats_all, musig_all, 128 * 353,
                                             (const float*)d_in[20], Wp_all, csh_all);

    // ---- layer 1: project (in-place on A_buf) then aggregate -> B_buf ----
    proj_kernel<<<dim3(128, 4), 256, 0, stream>>>(A_buf, Wp_all, csh_all,
                                                  (const float*)d_in[21], (const float*)d_in[22],
                                                  sS1, sD1, 353);
    {
        AggArgs A;
        for (int j = 0; j < 4; ++j) {
            int s = j * 3 + 1;
            A.rowptr[j] = rowptr_all + s * 768;
            A.colsrc[j] = colsrc_all + s * 8192;
            A.ne[j] = ES.ne[s];
            A.hp[j] = A_buf + j * as0;
            A.out[j] = B_buf + j * as1;
        }
        A.nemax = nemax[1];
        A.sS = sS1; A.sD = sD1;
        A.bias = (const float*)d_in[23];
        A.dstats = dstats_all + 512;
        agg_kernel<353><<<512, 512, SMa1, stream>>>(A);
    }
    bn_finalize_kernel<<<4, 64, 0, stream>>>(dstats_all + 512, musig_all + 512, 128 * 177,
                                             (const float*)d_in[24], Wp_all + 16384, csh_all + 256);

    // ---- layer 2: project (in-place on B_buf) then aggregate -> ALLb ----
    proj_kernel<<<dim3(128, 4), 256, 0, stream>>>(B_buf, Wp_all + 16384, csh_all + 256,
                                                  (const float*)d_in[25], (const float*)d_in[26],
                                                  sS2, sD2, 177);
    {
        AggArgs A;
        for (int j = 0; j < 4; ++j) {
            int s = j * 3 + 2;
            A.rowptr[j] = rowptr_all + s * 768;
            A.colsrc[j] = colsrc_all + s * 8192;
            A.ne[j] = ES.ne[s];
            A.hp[j] = B_buf + j * as1;
            A.out[j] = ALLb + (size_t)j * M_FINAL * 64;
        }
        A.nemax = nemax[2];
        A.sS = sS2; A.sD = sD2;
        A.bias = (const float*)d_in[27];
        A.dstats = dstats_all + 1024;
        agg_kernel<177><<<512, 512, SMa2, stream>>>(A);
    }
    bn_finalize_kernel<<<4, 64, 0, stream>>>(dstats_all + 1024, musig_all + 1024, 128 * 89,
                                             nullptr, nullptr, nullptr);

    // ---- fusion head ----
    const float* musig2 = musig_all + 1024;
    head_reduce_kernel<<<64, 256, 0, stream>>>(ALLb, musig2, (const float*)d_in[28], S, cm);
    fuse_small_kernel<<<1, 64, 0, stream>>>(S, cm, (const float*)d_in[29], (const float*)d_in[30], cvec);
    head_out_kernel<<<128, 256, 0, stream>>>(ALLb, musig2, cvec,
                                             (const float*)d_in[31], (const float*)d_in[32],
                                             (const float*)d_in[33], (float*)d_out);
}

// Round 8
// 561.409 us; speedup vs baseline: 2.9382x; 1.3139x over previous
//
#include <hip/hip_runtime.h>
#include <hip/hip_fp16.h>
#include <math.h>

#define DIM 64
#define M_FINAL (128*89)   // 11392 final rows

static inline int cdiv(int a, int b) { return (a + b - 1) / b; }

__device__ inline float rdlane(float v, int l) {
    return __int_as_float(__builtin_amdgcn_readlane(__float_as_int(v), l));
}
__device__ inline unsigned packpw(float p, unsigned src) {
    return ((unsigned)__half_as_ushort(__float2half(p)) << 16) | src;
}
__device__ inline float unpackpw(unsigned ep) {
    return __half2float(__ushort_as_half((unsigned short)(ep >> 16)));
}

struct EdgeSets {
    const int* src[12];
    const int* dst[12];
    int ne[12];
};

struct L0Args {
    const float* x;
    float* out[4];
    const int* rowptr[4];
    const int* colsrc[4];
    int ne[4];
    int nemax;
    double* dstats;
    const float* W;
    const float* as;
    const float* ad;
    const float* bias;
};

struct AggArgs {
    const float* hp[4];       // projected rows (out-space)
    float* out[4];
    const int* rowptr[4];
    const int* colsrc[4];
    int ne[4];
    int nemax;
    const float* sS;          // [j][g][NPIN]
    const float* sD;
    const float* bias;
    double* dstats;
};

// ---------------- misc ----------------

__global__ void zero_kernel(float* __restrict__ p, int n) {
    int i = blockIdx.x * blockDim.x + threadIdx.x;
    if (i < n) p[i] = 0.f;
}

// ---------------- fused CSR build: one block per edge set ------------------
__global__ __launch_bounds__(768)
void csr_build_kernel(EdgeSets ES, int* __restrict__ rowptr_all,
                      int* __restrict__ colsrc_all) {
    __shared__ int cnt[768];
    __shared__ int cur[768];
    const int s = blockIdx.x;
    const int lay = s % 3;
    const int n = (lay == 0) ? 706 : (lay == 1) ? 353 : 177;
    const int ne = ES.ne[s];
    const int* __restrict__ src = ES.src[s];
    const int* __restrict__ dst = ES.dst[s];
    int* __restrict__ rowptr = rowptr_all + s * 768;
    int* __restrict__ colsrc = colsrc_all + s * 8192;
    const int t = threadIdx.x;

    cnt[t] = 0;
    __syncthreads();
    for (int k = t; k < ne; k += 768) atomicAdd(&cnt[dst[k]], 1);
    __syncthreads();
    int v = cnt[t];
    for (int off = 1; off < 768; off <<= 1) {
        int add = (t >= off) ? cnt[t - off] : 0;
        __syncthreads();
        cnt[t] += add;
        __syncthreads();
    }
    int excl = cnt[t] - v;
    if (t < n) { rowptr[t] = excl; cur[t] = excl; }
    if (t == n - 1) rowptr[n] = cnt[t];
    __syncthreads();
    for (int k = t; k < ne; k += 768) {
        int pos = atomicAdd(&cur[dst[k]], 1);
        colsrc[pos] = src[k];
    }
}

// ---------------- layer 0 mega kernel (in_dim=3, fused) --------------------
// grid = split(2) x view(4) x graph(128) = 1024 blocks of 512 threads.
// Precomputed fp16 edge weights packed with src idx in one LDS word.
__global__ __launch_bounds__(512, 6)
void layer0_kernel(L0Args A) {
    constexpr int NPIN = 706, NPOUT = 353, HALF = 177;

    extern __shared__ char smem[];
    float* sredF = (float*)smem;                       // [2][8][64] = 4096 B
    float* fp = (float*)(smem + 4096);
    float* sSrc = fp; fp += NPIN;
    float* sDst = fp; fp += NPIN;
    float* hL4  = fp; fp += NPIN * 4;
    float* waL0 = fp; fp += 8;
    unsigned* ep32 = (unsigned*)fp;
    unsigned short* rp16 = (unsigned short*)(ep32 + A.nemax);

    const int split = blockIdx.x >> 9;
    const int jg = blockIdx.x & 511;
    const int j = jg >> 7;
    const int g = jg & 127;
    const int tid = threadIdx.x;
    const int wave = tid >> 6;
    const int lane = tid & 63;

    const int n0c = split * HALF;
    const int n1c = min(NPOUT, n0c + HALF);
    const int ch0 = 2 * n0c;
    const int ch1 = min(NPIN, 2 * n1c);

    const int* __restrict__ rowptr = A.rowptr[j];
    const int* __restrict__ colsrc = A.colsrc[j];
    const float* __restrict__ W = A.W;
    const int ne = A.ne[j];

    // stage CSR + wa
    for (int k = tid; k <= NPIN; k += 512) rp16[k] = (unsigned short)rowptr[k];
    for (int k = tid; k < ne; k += 512) ep32[k] = (unsigned)colsrc[k];
    if (tid < 6) {                    // wa_{src,dst}[f] = sum_d W[f][d]*a[d]
        int f = (tid < 3) ? tid : tid - 3;
        const float* av = (tid < 3) ? A.as : A.ad;
        float acc = 0.f;
        for (int d = 0; d < 64; ++d) acc += W[f * 64 + d] * av[d];
        waL0[tid] = acc;
    }
    __syncthreads();

    // h staging + s-dots (all nodes; duplicated across splits, cheap)
    {
        const float* hb = A.x + (size_t)g * (NPIN * 3);
        for (int r = tid; r < NPIN; r += 512) {
            float h0 = hb[r * 3], h1 = hb[r * 3 + 1], h2 = hb[r * 3 + 2];
            hL4[r * 4] = h0; hL4[r * 4 + 1] = h1; hL4[r * 4 + 2] = h2; hL4[r * 4 + 3] = 0.f;
            sSrc[r] = h0 * waL0[0] + h1 * waL0[1] + h2 * waL0[2];
            sDst[r] = h0 * waL0[3] + h1 * waL0[4] + h2 * waL0[5];
        }
    }
    __syncthreads();

    // per-node online softmax -> packed normalized fp16 weights (own range)
    for (int r = ch0 + tid; r < ch1; r += 512) {
        int s0 = rp16[r], e0 = rp16[r + 1];
        float sd = sDst[r];
        float m = -1e30f, z = 0.f;
        for (int k = s0; k < e0; ++k) {
            float v = sSrc[ep32[k] & 0xFFFFu] + sd;
            v = (v >= 0.f) ? v : 0.2f * v;
            if (v > m) { z = z * __expf(m - v) + 1.f; m = v; }
            else z += __expf(v - m);
        }
        float invz = 1.f / z;
        for (int k = s0; k < e0; ++k) {
            unsigned sl = ep32[k] & 0xFFFFu;
            float v = sSrc[sl] + sd;
            v = (v >= 0.f) ? v : 0.2f * v;
            ep32[k] = packpw(__expf(v - m) * invz, sl);
        }
    }
    __syncthreads();

    // aggregate (3-dim) + tiny matvec + relu + pool + BN stats
    const float w0 = W[lane], w1 = W[64 + lane], w2 = W[128 + lane];
    const float b_l = A.bias[lane];
    float* outj = A.out[j];
    const float4* hL4v = (const float4*)hL4;
    float bs = 0.f, bs2 = 0.f;

    for (int c = n0c + wave; c < n1c; c += 8) {
        float vmax = 0.f;
        #pragma unroll
        for (int ch = 0; ch < 2; ++ch) {
            int child = 2 * c + ch;
            if (child >= NPIN) break;
            int s0 = rp16[child], e0 = rp16[child + 1];
            float a0 = 0.f, a1 = 0.f, a2 = 0.f;
            for (int k = s0; k < e0; ++k) {
                unsigned ep = ep32[k];
                float p = unpackpw(ep);
                float4 hv = hL4v[ep & 0xFFFFu];
                a0 += p * hv.x; a1 += p * hv.y; a2 += p * hv.z;
            }
            float o = a0 * w0 + a1 * w1 + a2 * w2 + b_l;
            vmax = fmaxf(vmax, fmaxf(o, 0.f));
        }
        outj[((size_t)g * NPOUT + c) * 64 + lane] = vmax;
        bs += vmax;
        bs2 += vmax * vmax;
    }
    sredF[wave * 64 + lane] = bs;
    sredF[512 + wave * 64 + lane] = bs2;
    __syncthreads();
    if (wave == 0) {
        float t1 = 0.f, t2 = 0.f;
        #pragma unroll
        for (int w = 0; w < 8; ++w) {
            t1 += sredF[w * 64 + lane];
            t2 += sredF[512 + w * 64 + lane];
        }
        atomicAdd(A.dstats + j * 128 + lane, (double)t1);
        atomicAdd(A.dstats + j * 128 + 64 + lane, (double)t2);
    }
}

// BN finalize; optionally fold stats into next layer's weight:
// Wp[f][d] = rs[f]*Wn[f][d]; csh[d] = sum_f mu[f]*rs[f]*Wn[f][d]
__global__ void bn_finalize_kernel(const double* __restrict__ dstats,
                                   float* __restrict__ musig, int n_rows,
                                   const float* __restrict__ Wn,
                                   float* __restrict__ Wp, float* __restrict__ csh) {
    __shared__ float mur[128];
    int jv = blockIdx.x;           // view
    int d = threadIdx.x;           // 64
    double mu = dstats[jv * 128 + d] / n_rows;
    double var = dstats[jv * 128 + 64 + d] / n_rows - mu * mu;
    float rs = rsqrtf((float)var + 1e-5f);
    musig[jv * 128 + d] = (float)mu;
    musig[jv * 128 + 64 + d] = rs;
    if (Wn != nullptr) {
        mur[d] = (float)mu; mur[64 + d] = rs;
        __syncthreads();
        float c = 0.f;
        for (int f = 0; f < 64; ++f) {
            float wp = mur[64 + f] * Wn[f * 64 + d];
            Wp[jv * 4096 + f * 64 + d] = wp;
            c += mur[f] * wp;
        }
        csh[jv * 64 + d] = c;
    }
}

// ---------------- projection: HP = h @ W' - c (in-place) + s-dots ----------
// grid (320, view); block 256 = 4 waves; wave per ROW PAIR (2-row ILP).
__global__ __launch_bounds__(256, 5)
void proj_kernel(float* __restrict__ buf, const float* __restrict__ Wp_all,
                 const float* __restrict__ csh_all,
                 const float* __restrict__ a_s, const float* __restrict__ a_d,
                 float* __restrict__ sS, float* __restrict__ sD, int npin) {
    const int j = blockIdx.y;
    const int lane = threadIdx.x & 63, wave = threadIdx.x >> 6;
    const int R = 128 * npin;
    const int P = R >> 1;              // R is even
    float* h = buf + (size_t)j * R * 64;
    const float* Wp = Wp_all + j * 4096;
    float Wreg[64];
    #pragma unroll
    for (int f = 0; f < 64; ++f) Wreg[f] = Wp[f * 64 + lane];
    const float cst = csh_all[j * 64 + lane];
    const float asv = a_s[lane], adv = a_d[lane];
    const int nw = gridDim.x * 4;
    for (int pr = blockIdx.x * 4 + wave; pr < P; pr += nw) {
        int r0 = pr * 2;
        float va = h[(size_t)r0 * 64 + lane];
        float vb = h[(size_t)r0 * 64 + 64 + lane];
        float o0 = 0.f, o1 = 0.f, q0 = 0.f, q1 = 0.f;
        #pragma unroll
        for (int f = 0; f < 64; f += 2) {
            o0 += rdlane(va, f)     * Wreg[f];
            q0 += rdlane(vb, f)     * Wreg[f];
            o1 += rdlane(va, f + 1) * Wreg[f + 1];
            q1 += rdlane(vb, f + 1) * Wreg[f + 1];
        }
        float oa = (o0 + o1) - cst, ob = (q0 + q1) - cst;
        h[(size_t)r0 * 64 + lane] = oa;
        h[(size_t)r0 * 64 + 64 + lane] = ob;
        float aa = oa * asv, da = oa * adv, ab = ob * asv, db = ob * adv;
        for (int off = 32; off > 0; off >>= 1) {
            aa += __shfl_down(aa, off, 64);
            da += __shfl_down(da, off, 64);
            ab += __shfl_down(ab, off, 64);
            db += __shfl_down(db, off, 64);
        }
        if (lane == 0) {
            sS[j * R + r0] = aa;     sD[j * R + r0] = da;
            sS[j * R + r0 + 1] = ab; sD[j * R + r0 + 1] = db;
        }
    }
}

// ---------------- aggregation (L>0): softmax + gather + pool + BN stats ----
// grid = split(2) x view(4) x graph(128) = 1024 blocks of 512 threads.
template<int NPIN>
__global__ __launch_bounds__(512, 8)
void agg_kernel(AggArgs A) {
    constexpr int NPOUT = (NPIN + 1) / 2;
    constexpr int HALF = (NPOUT + 1) / 2;

    extern __shared__ char smem[];
    float* sredF = (float*)smem;                       // 4096 B
    float* fp = (float*)(smem + 4096);
    float* sSrc = fp; fp += NPIN;
    float* sDst = fp; fp += NPIN;
    unsigned* ep32 = (unsigned*)fp;
    unsigned short* rp16 = (unsigned short*)(ep32 + A.nemax);

    const int split = blockIdx.x >> 9;
    const int jg = blockIdx.x & 511;
    const int j = jg >> 7;
    const int g = jg & 127;
    const int tid = threadIdx.x;
    const int wave = tid >> 6;
    const int lane = tid & 63;

    const int n0c = split * HALF;
    const int n1c = min(NPOUT, n0c + HALF);
    const int ch0 = 2 * n0c;
    const int ch1 = min(NPIN, 2 * n1c);

    const float* __restrict__ hp = A.hp[j];
    const int* __restrict__ rowptr = A.rowptr[j];
    const int* __restrict__ colsrc = A.colsrc[j];
    const int ne = A.ne[j];
    const size_t gbase = (size_t)g * NPIN;
    const int sbase = (j * 128 + g) * NPIN;

    for (int k = tid; k <= NPIN; k += 512) rp16[k] = (unsigned short)rowptr[k];
    for (int k = tid; k < ne; k += 512) ep32[k] = (unsigned)colsrc[k];
    for (int r = tid; r < NPIN; r += 512) {
        sSrc[r] = A.sS[sbase + r];
        sDst[r] = A.sD[sbase + r];
    }
    __syncthreads();

    // per-node online softmax -> packed normalized fp16 weights (own range)
    for (int r = ch0 + tid; r < ch1; r += 512) {
        int s0 = rp16[r], e0 = rp16[r + 1];
        float sd = sDst[r];
        float m = -1e30f, z = 0.f;
        for (int k = s0; k < e0; ++k) {
            float v = sSrc[ep32[k] & 0xFFFFu] + sd;
            v = (v >= 0.f) ? v : 0.2f * v;
            if (v > m) { z = z * __expf(m - v) + 1.f; m = v; }
            else z += __expf(v - m);
        }
        float invz = 1.f / z;
        for (int k = s0; k < e0; ++k) {
            unsigned sl = ep32[k] & 0xFFFFu;
            float v = sSrc[sl] + sd;
            v = (v >= 0.f) ? v : 0.2f * v;
            ep32[k] = packpw(__expf(v - m) * invz, sl);
        }
    }
    __syncthreads();

    const float b_l = A.bias[lane];
    float* outj = A.out[j];
    float bs = 0.f, bs2 = 0.f;

    for (int c = n0c + wave; c < n1c; c += 8) {
        float vmax = 0.f;
        #pragma unroll
        for (int ch = 0; ch < 2; ++ch) {
            int child = 2 * c + ch;
            if (child >= NPIN) break;
            int s0 = rp16[child], e0 = rp16[child + 1];
            float acc = 0.f;
            int k = s0;
            for (; k + 2 <= e0; k += 2) {
                unsigned ea = ep32[k], eb = ep32[k + 1];
                float ha = hp[(gbase + (ea & 0xFFFFu)) * 64 + lane];
                float hb = hp[(gbase + (eb & 0xFFFFu)) * 64 + lane];
                acc += unpackpw(ea) * ha + unpackpw(eb) * hb;
            }
            if (k < e0) {
                unsigned ea = ep32[k];
                acc += unpackpw(ea) * hp[(gbase + (ea & 0xFFFFu)) * 64 + lane];
            }
            float o = acc + b_l;
            vmax = fmaxf(vmax, fmaxf(o, 0.f));
        }
        outj[((size_t)g * NPOUT + c) * 64 + lane] = vmax;
        bs += vmax;
        bs2 += vmax * vmax;
    }
    sredF[wave * 64 + lane] = bs;
    sredF[512 + wave * 64 + lane] = bs2;
    __syncthreads();
    if (wave == 0) {
        float t1 = 0.f, t2 = 0.f;
        #pragma unroll
        for (int w = 0; w < 8; ++w) {
            t1 += sredF[w * 64 + lane];
            t2 += sredF[512 + w * 64 + lane];
        }
        atomicAdd(A.dstats + j * 128 + lane, (double)t1);
        atomicAdd(A.dstats + j * 128 + 64 + lane, (double)t2);
    }
}

// ---------------- fused head reduce: Bm dots -> S (BmT Bm) + column means --
__global__ __launch_bounds__(256)
void head_reduce_kernel(const float* __restrict__ ALL, const float* __restrict__ musig,
                        const float* __restrict__ w_attn,
                        float* __restrict__ S, float* __restrict__ cm) {
    __shared__ float S_loc[16];
    __shared__ float cm_loc[256];
    const int t = threadIdx.x, wave = t >> 6, lane = t & 63;
    if (t < 16) S_loc[t] = 0.f;
    cm_loc[t] = 0.f;
    __syncthreads();
    const float wa = w_attn[lane];
    float cacc[4] = {0.f, 0.f, 0.f, 0.f};
    for (int m = blockIdx.x * 4 + wave; m < M_FINAL; m += gridDim.x * 4) {
        float b4[4];
        float csum = 0.f;
        #pragma unroll
        for (int v = 0; v < 4; ++v) {
            float val = (ALL[((size_t)v * M_FINAL + m) * 64 + lane] - musig[v * 128 + lane])
                        * musig[v * 128 + 64 + lane];
            csum += val;
            float p = val * wa;
            for (int off = 32; off > 0; off >>= 1) p += __shfl_down(p, off, 64);
            b4[v] = __shfl(p, 0, 64);
        }
        cacc[m & 3] += csum;
        if (lane < 16) atomicAdd(&S_loc[lane], b4[lane >> 2] * b4[lane & 3]);
    }
    #pragma unroll
    for (int q = 0; q < 4; ++q) atomicAdd(&cm_loc[q * 64 + lane], cacc[q]);
    __syncthreads();
    if (t < 16) atomicAdd(&S[t], S_loc[t]);
    atomicAdd(&cm[t], cm_loc[t]);
}

__global__ void fuse_small_kernel(const float* __restrict__ S, const float* __restrict__ cm,
                                  const float* __restrict__ w_lin0, const float* __restrict__ b_lin0,
                                  float* __restrict__ cvec) {
    if (threadIdx.x != 0 || blockIdx.x != 0) return;
    float cn[4];
    for (int v = 0; v < 4; ++v) cn[v] = sqrtf(S[v * 4 + v]);
    float A[16];
    for (int u = 0; u < 4; ++u) {
        float row[4]; float mx = -1e30f;
        for (int v = 0; v < 4; ++v) {
            float g = S[u * 4 + v] / (cn[u] * cn[v]);
            g = (g >= 0.f) ? g : 0.1f * g;       // leaky_relu 0.1
            row[v] = g; mx = fmaxf(mx, g);
        }
        float sum = 0.f;
        for (int v = 0; v < 4; ++v) { row[v] = expf(row[v] - mx); sum += row[v]; }
        for (int v = 0; v < 4; ++v) A[u * 4 + v] = row[v] / sum;
    }
    float e4[4];
    for (int v = 0; v < 4; ++v) {
        float a = b_lin0[v];
        for (int c = 0; c < 256; ++c) a += (cm[c] / (float)M_FINAL) * w_lin0[c * 4 + v];
        e4[v] = a;
    }
    float mx = fmaxf(fmaxf(e4[0], e4[1]), fmaxf(e4[2], e4[3]));
    float sum = 0.f, w[4];
    for (int v = 0; v < 4; ++v) { w[v] = expf(e4[v] - mx); sum += w[v]; }
    for (int v = 0; v < 4; ++v) w[v] /= sum;
    for (int k = 0; k < 4; ++k) {
        float c = 0.f;
        for (int v = 0; v < 4; ++v) c += A[k * 4 + v] * w[v];
        cvec[k] = c;
    }
}

// ---------------- fused head output: combine + 3 matvecs (selu,selu,none) --
__global__ __launch_bounds__(256)
void head_out_kernel(const float* __restrict__ ALL, const float* __restrict__ musig,
                     const float* __restrict__ cvec,
                     const float* __restrict__ W0, const float* __restrict__ W1,
                     const float* __restrict__ W2, float* __restrict__ outp) {
    __shared__ float Wl[3][64 * 64];   // 48 KB
    const int t = threadIdx.x, wave = t >> 6, lane = t & 63;
    for (int k = t; k < 4096; k += 256) {
        Wl[0][k] = W0[k]; Wl[1][k] = W1[k]; Wl[2][k] = W2[k];
    }
    __syncthreads();
    const float c0 = cvec[0], c1 = cvec[1], c2 = cvec[2], c3 = cvec[3];
    const float scale = 1.0507009873554805f;
    const float alpha = 1.6732632423543772f;
    for (int m = blockIdx.x * 4 + wave; m < M_FINAL; m += gridDim.x * 4) {
        float r =
            c0 * ((ALL[((size_t)0 * M_FINAL + m) * 64 + lane] - musig[0 * 128 + lane]) * musig[0 * 128 + 64 + lane]) +
            c1 * ((ALL[((size_t)1 * M_FINAL + m) * 64 + lane] - musig[1 * 128 + lane]) * musig[1 * 128 + 64 + lane]) +
            c2 * ((ALL[((size_t)2 * M_FINAL + m) * 64 + lane] - musig[2 * 128 + lane]) * musig[2 * 128 + 64 + lane]) +
            c3 * ((ALL[((size_t)3 * M_FINAL + m) * 64 + lane] - musig[3 * 128 + lane]) * musig[3 * 128 + 64 + lane]);
        #pragma unroll
        for (int s = 0; s < 3; ++s) {
            float o0 = 0.f, o1 = 0.f, o2 = 0.f, o3 = 0.f;
            #pragma unroll
            for (int f = 0; f < 64; f += 4) {
                o0 += rdlane(r, f)     * Wl[s][f * 64 + lane];
                o1 += rdlane(r, f + 1) * Wl[s][(f + 1) * 64 + lane];
                o2 += rdlane(r, f + 2) * Wl[s][(f + 2) * 64 + lane];
                o3 += rdlane(r, f + 3) * Wl[s][(f + 3) * 64 + lane];
            }
            float o = (o0 + o1) + (o2 + o3);
            if (s < 2) o = (o > 0.f) ? scale * o : scale * alpha * expm1f(o);
            r = o;
        }
        outp[(size_t)m * 64 + lane] = r;
    }
}

extern "C" void kernel_launch(void* const* d_in, const int* in_sizes, int n_in,
                              void* d_out, int out_size, void* d_ws, size_t ws_size,
                              hipStream_t stream) {
    const float* x = (const float*)d_in[15];

    float* ws = (float*)d_ws;
    double* dstats_all = (double*)ws;                 // 1536 doubles -> [0, 3072)
    float*  cm         = ws + 3072;                   // 256
    float*  S          = ws + 3328;                   // 16
    float*  cvec       = ws + 3344;                   // 4
    float*  musig_all  = ws + 3584;                   // 3*512 -> [3584, 5120)
    float*  Wp_all     = ws + 5120;                   // 2*4*4096 -> [5120, 37888)
    float*  csh_all    = ws + 37888;                  // 2*4*64 -> [37888, 38400)
    int*    rowptr_all = (int*)(ws + 38400);          // 12*768 -> [38400, 47616)
    int*    colsrc_all = (int*)(ws + 47616);          // 12*8192 -> [47616, 145920)
    float*  sS1        = ws + 145920;                 // 180736
    float*  sD1        = sS1 + 180736;
    float*  sS2        = sD1 + 180736;                // 90624
    float*  sD2        = sS2 + 90624;
    float*  A_buf      = sD2 + 90624;                 // 4*128*353*64 = 11,567,104
    float*  B_buf      = A_buf + (size_t)4 * 128 * 353 * 64;  // 4*128*177*64
    float*  ALLb       = A_buf;                       // alias (A dead after L2 proj input)
    const size_t as0 = (size_t)128 * 353 * 64;
    const size_t as1 = (size_t)128 * 177 * 64;

    // edge sets (graph-0 structure shared by all 128 graphs)
    EdgeSets ES;
    int nemax[3] = {0, 0, 0};
    for (int s = 0; s < 12; ++s) {
        const int* e = (const int*)d_in[s];
        int E = in_sizes[s] / 2;
        ES.src[s] = e;
        ES.dst[s] = e + E;
        ES.ne[s] = E / 128;
        int lay = s % 3;
        if (ES.ne[s] > nemax[lay]) nemax[lay] = ES.ne[s];
    }

    // dynamic LDS sizes (mirror in-kernel layouts)
    int SM0 = 4096 + (706 * 6 + 8) * 4 + nemax[0] * 4 + 708 * 2;
    SM0 = (SM0 + 15) & ~15;
    int SMa1 = 4096 + (2 * 353) * 4 + nemax[1] * 4 + 355 * 2;
    SMa1 = (SMa1 + 15) & ~15;
    int SMa2 = 4096 + (2 * 177) * 4 + nemax[2] * 4 + 179 * 2;
    SMa2 = (SMa2 + 15) & ~15;
    (void)hipFuncSetAttribute(reinterpret_cast<const void*>(&layer0_kernel),
                              hipFuncAttributeMaxDynamicSharedMemorySize, SM0);
    (void)hipFuncSetAttribute(reinterpret_cast<const void*>(&agg_kernel<353>),
                              hipFuncAttributeMaxDynamicSharedMemorySize, SMa1);
    (void)hipFuncSetAttribute(reinterpret_cast<const void*>(&agg_kernel<177>),
                              hipFuncAttributeMaxDynamicSharedMemorySize, SMa2);

    zero_kernel<<<cdiv(3584, 256), 256, 0, stream>>>(ws, 3584);
    csr_build_kernel<<<12, 768, 0, stream>>>(ES, rowptr_all, colsrc_all);

    // ---- layer 0 ----
    {
        L0Args A;
        A.x = x;
        for (int j = 0; j < 4; ++j) {
            int s = j * 3;
            A.rowptr[j] = rowptr_all + s * 768;
            A.colsrc[j] = colsrc_all + s * 8192;
            A.ne[j] = ES.ne[s];
            A.out[j] = A_buf + j * as0;
        }
        A.nemax = nemax[0];
        A.dstats = dstats_all;
        A.W = (const float*)d_in[16];
        A.as = (const float*)d_in[17];
        A.ad = (const float*)d_in[18];
        A.bias = (const float*)d_in[19];
        layer0_kernel<<<1024, 512, SM0, stream>>>(A);
    }
    bn_finalize_kernel<<<4, 64, 0, stream>>>(dstats_all, musig_all, 128 * 353,
                                             (const float*)d_in[20], Wp_all, csh_all);

    // ---- layer 1: project (in-place on A_buf) then aggregate -> B_buf ----
    proj_kernel<<<dim3(320, 4), 256, 0, stream>>>(A_buf, Wp_all, csh_all,
                                                  (const float*)d_in[21], (const float*)d_in[22],
                                                  sS1, sD1, 353);
    {
        AggArgs A;
        for (int j = 0; j < 4; ++j) {
            int s = j * 3 + 1;
            A.rowptr[j] = rowptr_all + s * 768;
            A.colsrc[j] = colsrc_all + s * 8192;
            A.ne[j] = ES.ne[s];
            A.hp[j] = A_buf + j * as0;
            A.out[j] = B_buf + j * as1;
        }
        A.nemax = nemax[1];
        A.sS = sS1; A.sD = sD1;
        A.bias = (const float*)d_in[23];
        A.dstats = dstats_all + 512;
        agg_kernel<353><<<1024, 512, SMa1, stream>>>(A);
    }
    bn_finalize_kernel<<<4, 64, 0, stream>>>(dstats_all + 512, musig_all + 512, 128 * 177,
                                             (const float*)d_in[24], Wp_all + 16384, csh_all + 256);

    // ---- layer 2: project (in-place on B_buf) then aggregate -> ALLb ----
    proj_kernel<<<dim3(320, 4), 256, 0, stream>>>(B_buf, Wp_all + 16384, csh_all + 256,
                                                  (const float*)d_in[25], (const float*)d_in[26],
                                                  sS2, sD2, 177);
    {
        AggArgs A;
        for (int j = 0; j < 4; ++j) {
            int s = j * 3 + 2;
            A.rowptr[j] = rowptr_all + s * 768;
            A.colsrc[j] = colsrc_all + s * 8192;
            A.ne[j] = ES.ne[s];
            A.hp[j] = B_buf + j * as1;
            A.out[j] = ALLb + (size_t)j * M_FINAL * 64;
        }
        A.nemax = nemax[2];
        A.sS = sS2; A.sD = sD2;
        A.bias = (const float*)d_in[27];
        A.dstats = dstats_all + 1024;
        agg_kernel<177><<<1024, 512, SMa2, stream>>>(A);
    }
    bn_finalize_kernel<<<4, 64, 0, stream>>>(dstats_all + 1024, musig_all + 1024, 128 * 89,
                                             nullptr, nullptr, nullptr);

    // ---- fusion head ----
    const float* musig2 = musig_all + 1024;
    head_reduce_kernel<<<256, 256, 0, stream>>>(ALLb, musig2, (const float*)d_in[28], S, cm);
    fuse_small_kernel<<<1, 64, 0, stream>>>(S, cm, (const float*)d_in[29], (const float*)d_in[30], cvec);
    head_out_kernel<<<256, 256, 0, stream>>>(ALLb, musig2, cvec,
                                             (const float*)d_in[31], (const float*)d_in[32],
                                             (const float*)d_in[33], (float*)d_out);
}

// Round 9
// 519.087 us; speedup vs baseline: 3.1777x; 1.0815x over previous
//
#include <hip/hip_runtime.h>
#include <hip/hip_fp16.h>
#include <math.h>

#define DIM 64
#define M_FINAL (128*89)   // 11392 final rows

static inline int cdiv(int a, int b) { return (a + b - 1) / b; }

__device__ inline float rdlane(float v, int l) {
    return __int_as_float(__builtin_amdgcn_readlane(__float_as_int(v), l));
}
__device__ inline unsigned packpw(float p, unsigned src) {
    return ((unsigned)__half_as_ushort(__float2half(p)) << 16) | src;
}
__device__ inline float unpackpw(unsigned ep) {
    return __half2float(__ushort_as_half((unsigned short)(ep >> 16)));
}
__device__ inline void storeval(float* p, float v) { *p = v; }
__device__ inline void storeval(__half* p, float v) { *p = __float2half(v); }

struct EdgeSets {
    const int* src[12];
    const int* dst[12];
    int ne[12];
};

struct L0Args {
    const float* x;
    __half* out[4];
    const int* rowptr[4];
    const int* colsrc[4];
    int ne[4];
    int nemax;
    double* dstats;
    const float* W;
    const float* as;
    const float* ad;
    const float* bias;
};

struct AggArgs {
    const __half* hp[4];      // projected rows (out-space, fp16)
    void* out[4];
    const int* rowptr[4];
    const int* colsrc[4];
    int ne[4];
    int nemax;
    const float* sS;          // [j][g][NPIN]
    const float* sD;
    const float* bias;
    double* dstats;
};

// ---------------- misc ----------------

__global__ void zero_kernel(float* __restrict__ p, int n) {
    int i = blockIdx.x * blockDim.x + threadIdx.x;
    if (i < n) p[i] = 0.f;
}

// ---------------- fused CSR build: one block per edge set ------------------
__global__ __launch_bounds__(768)
void csr_build_kernel(EdgeSets ES, int* __restrict__ rowptr_all,
                      int* __restrict__ colsrc_all) {
    __shared__ int cnt[768];
    __shared__ int cur[768];
    const int s = blockIdx.x;
    const int lay = s % 3;
    const int n = (lay == 0) ? 706 : (lay == 1) ? 353 : 177;
    const int ne = ES.ne[s];
    const int* __restrict__ src = ES.src[s];
    const int* __restrict__ dst = ES.dst[s];
    int* __restrict__ rowptr = rowptr_all + s * 768;
    int* __restrict__ colsrc = colsrc_all + s * 8192;
    const int t = threadIdx.x;

    cnt[t] = 0;
    __syncthreads();
    for (int k = t; k < ne; k += 768) atomicAdd(&cnt[dst[k]], 1);
    __syncthreads();
    int v = cnt[t];
    for (int off = 1; off < 768; off <<= 1) {
        int add = (t >= off) ? cnt[t - off] : 0;
        __syncthreads();
        cnt[t] += add;
        __syncthreads();
    }
    int excl = cnt[t] - v;
    if (t < n) { rowptr[t] = excl; cur[t] = excl; }
    if (t == n - 1) rowptr[n] = cnt[t];
    __syncthreads();
    for (int k = t; k < ne; k += 768) {
        int pos = atomicAdd(&cur[dst[k]], 1);
        colsrc[pos] = src[k];
    }
}

// ---------------- layer 0 mega kernel (in_dim=3, fused) --------------------
// grid = split(2) x view(4) x graph(128) = 1024 blocks of 512 threads.
__global__ __launch_bounds__(512, 6)
void layer0_kernel(L0Args A) {
    constexpr int NPIN = 706, NPOUT = 353, HALF = 177;

    extern __shared__ char smem[];
    float* sredF = (float*)smem;                       // [2][8][64] = 4096 B
    float* fp = (float*)(smem + 4096);
    float* sSrc = fp; fp += NPIN;
    float* sDst = fp; fp += NPIN;
    float* hL4  = fp; fp += NPIN * 4;
    float* waL0 = fp; fp += 8;
    unsigned* ep32 = (unsigned*)fp;
    unsigned short* rp16 = (unsigned short*)(ep32 + A.nemax);

    const int split = blockIdx.x >> 9;
    const int jg = blockIdx.x & 511;
    const int j = jg >> 7;
    const int g = jg & 127;
    const int tid = threadIdx.x;
    const int wave = tid >> 6;
    const int lane = tid & 63;

    const int n0c = split * HALF;
    const int n1c = min(NPOUT, n0c + HALF);
    const int ch0 = 2 * n0c;
    const int ch1 = min(NPIN, 2 * n1c);

    const int* __restrict__ rowptr = A.rowptr[j];
    const int* __restrict__ colsrc = A.colsrc[j];
    const float* __restrict__ W = A.W;
    const int ne = A.ne[j];

    for (int k = tid; k <= NPIN; k += 512) rp16[k] = (unsigned short)rowptr[k];
    for (int k = tid; k < ne; k += 512) ep32[k] = (unsigned)colsrc[k];
    if (tid < 6) {                    // wa_{src,dst}[f] = sum_d W[f][d]*a[d]
        int f = (tid < 3) ? tid : tid - 3;
        const float* av = (tid < 3) ? A.as : A.ad;
        float acc = 0.f;
        for (int d = 0; d < 64; ++d) acc += W[f * 64 + d] * av[d];
        waL0[tid] = acc;
    }
    __syncthreads();

    {
        const float* hb = A.x + (size_t)g * (NPIN * 3);
        for (int r = tid; r < NPIN; r += 512) {
            float h0 = hb[r * 3], h1 = hb[r * 3 + 1], h2 = hb[r * 3 + 2];
            hL4[r * 4] = h0; hL4[r * 4 + 1] = h1; hL4[r * 4 + 2] = h2; hL4[r * 4 + 3] = 0.f;
            sSrc[r] = h0 * waL0[0] + h1 * waL0[1] + h2 * waL0[2];
            sDst[r] = h0 * waL0[3] + h1 * waL0[4] + h2 * waL0[5];
        }
    }
    __syncthreads();

    for (int r = ch0 + tid; r < ch1; r += 512) {
        int s0 = rp16[r], e0 = rp16[r + 1];
        float sd = sDst[r];
        float m = -1e30f, z = 0.f;
        for (int k = s0; k < e0; ++k) {
            float v = sSrc[ep32[k] & 0xFFFFu] + sd;
            v = (v >= 0.f) ? v : 0.2f * v;
            if (v > m) { z = z * __expf(m - v) + 1.f; m = v; }
            else z += __expf(v - m);
        }
        float invz = 1.f / z;
        for (int k = s0; k < e0; ++k) {
            unsigned sl = ep32[k] & 0xFFFFu;
            float v = sSrc[sl] + sd;
            v = (v >= 0.f) ? v : 0.2f * v;
            ep32[k] = packpw(__expf(v - m) * invz, sl);
        }
    }
    __syncthreads();

    const float w0 = W[lane], w1 = W[64 + lane], w2 = W[128 + lane];
    const float b_l = A.bias[lane];
    __half* outj = A.out[j];
    const float4* hL4v = (const float4*)hL4;
    float bs = 0.f, bs2 = 0.f;

    for (int c = n0c + wave; c < n1c; c += 8) {
        float vmax = 0.f;
        #pragma unroll
        for (int ch = 0; ch < 2; ++ch) {
            int child = 2 * c + ch;
            if (child >= NPIN) break;
            int s0 = rp16[child], e0 = rp16[child + 1];
            float a0 = 0.f, a1 = 0.f, a2 = 0.f;
            for (int k = s0; k < e0; ++k) {
                unsigned ep = ep32[k];
                float p = unpackpw(ep);
                float4 hv = hL4v[ep & 0xFFFFu];
                a0 += p * hv.x; a1 += p * hv.y; a2 += p * hv.z;
            }
            float o = a0 * w0 + a1 * w1 + a2 * w2 + b_l;
            vmax = fmaxf(vmax, fmaxf(o, 0.f));
        }
        outj[((size_t)g * NPOUT + c) * 64 + lane] = __float2half(vmax);
        bs += vmax;
        bs2 += vmax * vmax;
    }
    sredF[wave * 64 + lane] = bs;
    sredF[512 + wave * 64 + lane] = bs2;
    __syncthreads();
    if (wave == 0) {
        float t1 = 0.f, t2 = 0.f;
        #pragma unroll
        for (int w = 0; w < 8; ++w) {
            t1 += sredF[w * 64 + lane];
            t2 += sredF[512 + w * 64 + lane];
        }
        atomicAdd(A.dstats + j * 128 + lane, (double)t1);
        atomicAdd(A.dstats + j * 128 + 64 + lane, (double)t2);
    }
}

// BN finalize; optionally fold stats into next layer's weight:
// Wp[f][d] = rs[f]*Wn[f][d]; csh[d] = sum_f mu[f]*rs[f]*Wn[f][d]
__global__ void bn_finalize_kernel(const double* __restrict__ dstats,
                                   float* __restrict__ musig, int n_rows,
                                   const float* __restrict__ Wn,
                                   float* __restrict__ Wp, float* __restrict__ csh) {
    __shared__ float mur[128];
    int jv = blockIdx.x;           // view
    int d = threadIdx.x;           // 64
    double mu = dstats[jv * 128 + d] / n_rows;
    double var = dstats[jv * 128 + 64 + d] / n_rows - mu * mu;
    float rs = rsqrtf((float)var + 1e-5f);
    musig[jv * 128 + d] = (float)mu;
    musig[jv * 128 + 64 + d] = rs;
    if (Wn != nullptr) {
        mur[d] = (float)mu; mur[64 + d] = rs;
        __syncthreads();
        float c = 0.f;
        for (int f = 0; f < 64; ++f) {
            float wp = mur[64 + f] * Wn[f * 64 + d];
            Wp[jv * 4096 + f * 64 + d] = wp;
            c += mur[f] * wp;
        }
        csh[jv * 64 + d] = c;
    }
}

// ---------------- projection: HP = h @ W' - c, fp16 in-place + s-dots ------
// grid (320, view); block 256 = 4 waves; wave per ROW PAIR (2-row ILP).
__global__ __launch_bounds__(256, 5)
void proj_kernel(__half* __restrict__ buf, const float* __restrict__ Wp_all,
                 const float* __restrict__ csh_all,
                 const float* __restrict__ a_s, const float* __restrict__ a_d,
                 float* __restrict__ sS, float* __restrict__ sD, int npin) {
    const int j = blockIdx.y;
    const int lane = threadIdx.x & 63, wave = threadIdx.x >> 6;
    const int R = 128 * npin;
    const int P = R >> 1;              // R is even
    __half* h = buf + (size_t)j * R * 64;
    const float* Wp = Wp_all + j * 4096;
    float Wreg[64];
    #pragma unroll
    for (int f = 0; f < 64; ++f) Wreg[f] = Wp[f * 64 + lane];
    const float cst = csh_all[j * 64 + lane];
    const float asv = a_s[lane], adv = a_d[lane];
    const int nw = gridDim.x * 4;
    for (int pr = blockIdx.x * 4 + wave; pr < P; pr += nw) {
        int r0 = pr * 2;
        float va = __half2float(h[(size_t)r0 * 64 + lane]);
        float vb = __half2float(h[(size_t)r0 * 64 + 64 + lane]);
        float o0 = 0.f, o1 = 0.f, q0 = 0.f, q1 = 0.f;
        #pragma unroll
        for (int f = 0; f < 64; f += 2) {
            o0 += rdlane(va, f)     * Wreg[f];
            q0 += rdlane(vb, f)     * Wreg[f];
            o1 += rdlane(va, f + 1) * Wreg[f + 1];
            q1 += rdlane(vb, f + 1) * Wreg[f + 1];
        }
        float oa = (o0 + o1) - cst, ob = (q0 + q1) - cst;
        h[(size_t)r0 * 64 + lane] = __float2half(oa);
        h[(size_t)r0 * 64 + 64 + lane] = __float2half(ob);
        float aa = oa * asv, da = oa * adv, ab = ob * asv, db = ob * adv;
        for (int off = 32; off > 0; off >>= 1) {
            aa += __shfl_down(aa, off, 64);
            da += __shfl_down(da, off, 64);
            ab += __shfl_down(ab, off, 64);
            db += __shfl_down(db, off, 64);
        }
        if (lane == 0) {
            sS[j * R + r0] = aa;     sD[j * R + r0] = da;
            sS[j * R + r0 + 1] = ab; sD[j * R + r0 + 1] = db;
        }
    }
}

// ---------------- aggregation (L>0): softmax + fp16 gather + pool + BN -----
// grid = split(2) x view(4) x graph(128) = 1024 blocks of 512 threads.
template<int NPIN, typename OutT>
__global__ __launch_bounds__(512, 8)
void agg_kernel(AggArgs A) {
    constexpr int NPOUT = (NPIN + 1) / 2;
    constexpr int HALF = (NPOUT + 1) / 2;

    extern __shared__ char smem[];
    float* sredF = (float*)smem;                       // 4096 B
    float* fp = (float*)(smem + 4096);
    float* sSrc = fp; fp += NPIN;
    float* sDst = fp; fp += NPIN;
    unsigned* ep32 = (unsigned*)fp;
    unsigned short* rp16 = (unsigned short*)(ep32 + A.nemax);

    const int split = blockIdx.x >> 9;
    const int jg = blockIdx.x & 511;
    const int j = jg >> 7;
    const int g = jg & 127;
    const int tid = threadIdx.x;
    const int wave = tid >> 6;
    const int lane = tid & 63;

    const int n0c = split * HALF;
    const int n1c = min(NPOUT, n0c + HALF);
    const int ch0 = 2 * n0c;
    const int ch1 = min(NPIN, 2 * n1c);

    const int* __restrict__ rowptr = A.rowptr[j];
    const int* __restrict__ colsrc = A.colsrc[j];
    const int ne = A.ne[j];
    const int sbase = (j * 128 + g) * NPIN;
    // per-lane gather base: hp row sl is at hpg + sl*64 (halves)
    const __half* __restrict__ hpg = A.hp[j] + (size_t)g * NPIN * 64 + lane;

    for (int k = tid; k <= NPIN; k += 512) rp16[k] = (unsigned short)rowptr[k];
    for (int k = tid; k < ne; k += 512) ep32[k] = (unsigned)colsrc[k];
    for (int r = tid; r < NPIN; r += 512) {
        sSrc[r] = A.sS[sbase + r];
        sDst[r] = A.sD[sbase + r];
    }
    __syncthreads();

    for (int r = ch0 + tid; r < ch1; r += 512) {
        int s0 = rp16[r], e0 = rp16[r + 1];
        float sd = sDst[r];
        float m = -1e30f, z = 0.f;
        for (int k = s0; k < e0; ++k) {
            float v = sSrc[ep32[k] & 0xFFFFu] + sd;
            v = (v >= 0.f) ? v : 0.2f * v;
            if (v > m) { z = z * __expf(m - v) + 1.f; m = v; }
            else z += __expf(v - m);
        }
        float invz = 1.f / z;
        for (int k = s0; k < e0; ++k) {
            unsigned sl = ep32[k] & 0xFFFFu;
            float v = sSrc[sl] + sd;
            v = (v >= 0.f) ? v : 0.2f * v;
            ep32[k] = packpw(__expf(v - m) * invz, sl);
        }
    }
    __syncthreads();

    const float b_l = A.bias[lane];
    OutT* outj = (OutT*)A.out[j];
    float bs = 0.f, bs2 = 0.f;

    for (int c = n0c + wave; c < n1c; c += 8) {
        float vmax = 0.f;
        #pragma unroll
        for (int ch = 0; ch < 2; ++ch) {
            int child = 2 * c + ch;
            if (child >= NPIN) break;
            int s0 = rp16[child], e0 = rp16[child + 1];
            float acc0 = 0.f, acc1 = 0.f;
            int k = s0;
            for (; k + 4 <= e0; k += 4) {
                unsigned ea = ep32[k], eb = ep32[k + 1], ec = ep32[k + 2], ed = ep32[k + 3];
                float ha = __half2float(hpg[(size_t)(ea & 0xFFFFu) << 6]);
                float hb = __half2float(hpg[(size_t)(eb & 0xFFFFu) << 6]);
                float hc = __half2float(hpg[(size_t)(ec & 0xFFFFu) << 6]);
                float hd = __half2float(hpg[(size_t)(ed & 0xFFFFu) << 6]);
                acc0 += unpackpw(ea) * ha + unpackpw(eb) * hb;
                acc1 += unpackpw(ec) * hc + unpackpw(ed) * hd;
            }
            for (; k < e0; ++k) {
                unsigned ea = ep32[k];
                acc0 += unpackpw(ea) * __half2float(hpg[(size_t)(ea & 0xFFFFu) << 6]);
            }
            float o = acc0 + acc1 + b_l;
            vmax = fmaxf(vmax, fmaxf(o, 0.f));
        }
        storeval(&outj[((size_t)g * NPOUT + c) * 64 + lane], vmax);
        bs += vmax;
        bs2 += vmax * vmax;
    }
    sredF[wave * 64 + lane] = bs;
    sredF[512 + wave * 64 + lane] = bs2;
    __syncthreads();
    if (wave == 0) {
        float t1 = 0.f, t2 = 0.f;
        #pragma unroll
        for (int w = 0; w < 8; ++w) {
            t1 += sredF[w * 64 + lane];
            t2 += sredF[512 + w * 64 + lane];
        }
        atomicAdd(A.dstats + j * 128 + lane, (double)t1);
        atomicAdd(A.dstats + j * 128 + 64 + lane, (double)t2);
    }
}

// ---------------- fused head reduce: Bm dots -> S (BmT Bm) + column means --
__global__ __launch_bounds__(256)
void head_reduce_kernel(const float* __restrict__ ALL, const float* __restrict__ musig,
                        const float* __restrict__ w_attn,
                        float* __restrict__ S, float* __restrict__ cm) {
    __shared__ float S_loc[16];
    __shared__ float cm_loc[256];
    const int t = threadIdx.x, wave = t >> 6, lane = t & 63;
    if (t < 16) S_loc[t] = 0.f;
    cm_loc[t] = 0.f;
    __syncthreads();
    const float wa = w_attn[lane];
    float cacc[4] = {0.f, 0.f, 0.f, 0.f};
    for (int m = blockIdx.x * 4 + wave; m < M_FINAL; m += gridDim.x * 4) {
        float b4[4];
        float csum = 0.f;
        #pragma unroll
        for (int v = 0; v < 4; ++v) {
            float val = (ALL[((size_t)v * M_FINAL + m) * 64 + lane] - musig[v * 128 + lane])
                        * musig[v * 128 + 64 + lane];
            csum += val;
            float p = val * wa;
            for (int off = 32; off > 0; off >>= 1) p += __shfl_down(p, off, 64);
            b4[v] = __shfl(p, 0, 64);
        }
        cacc[m & 3] += csum;
        if (lane < 16) atomicAdd(&S_loc[lane], b4[lane >> 2] * b4[lane & 3]);
    }
    #pragma unroll
    for (int q = 0; q < 4; ++q) atomicAdd(&cm_loc[q * 64 + lane], cacc[q]);
    __syncthreads();
    if (t < 16) atomicAdd(&S[t], S_loc[t]);
    atomicAdd(&cm[t], cm_loc[t]);
}

__global__ void fuse_small_kernel(const float* __restrict__ S, const float* __restrict__ cm,
                                  const float* __restrict__ w_lin0, const float* __restrict__ b_lin0,
                                  float* __restrict__ cvec) {
    if (threadIdx.x != 0 || blockIdx.x != 0) return;
    float cn[4];
    for (int v = 0; v < 4; ++v) cn[v] = sqrtf(S[v * 4 + v]);
    float A[16];
    for (int u = 0; u < 4; ++u) {
        float row[4]; float mx = -1e30f;
        for (int v = 0; v < 4; ++v) {
            float g = S[u * 4 + v] / (cn[u] * cn[v]);
            g = (g >= 0.f) ? g : 0.1f * g;       // leaky_relu 0.1
            row[v] = g; mx = fmaxf(mx, g);
        }
        float sum = 0.f;
        for (int v = 0; v < 4; ++v) { row[v] = expf(row[v] - mx); sum += row[v]; }
        for (int v = 0; v < 4; ++v) A[u * 4 + v] = row[v] / sum;
    }
    float e4[4];
    for (int v = 0; v < 4; ++v) {
        float a = b_lin0[v];
        for (int c = 0; c < 256; ++c) a += (cm[c] / (float)M_FINAL) * w_lin0[c * 4 + v];
        e4[v] = a;
    }
    float mx = fmaxf(fmaxf(e4[0], e4[1]), fmaxf(e4[2], e4[3]));
    float sum = 0.f, w[4];
    for (int v = 0; v < 4; ++v) { w[v] = expf(e4[v] - mx); sum += w[v]; }
    for (int v = 0; v < 4; ++v) w[v] /= sum;
    for (int k = 0; k < 4; ++k) {
        float c = 0.f;
        for (int v = 0; v < 4; ++v) c += A[k * 4 + v] * w[v];
        cvec[k] = c;
    }
}

// ---------------- fused head output: combine + 3 matvecs (selu,selu,none) --
__global__ __launch_bounds__(256)
void head_out_kernel(const float* __restrict__ ALL, const float* __restrict__ musig,
                     const float* __restrict__ cvec,
                     const float* __restrict__ W0, const float* __restrict__ W1,
                     const float* __restrict__ W2, float* __restrict__ outp) {
    __shared__ float Wl[3][64 * 64];   // 48 KB
    const int t = threadIdx.x, wave = t >> 6, lane = t & 63;
    for (int k = t; k < 4096; k += 256) {
        Wl[0][k] = W0[k]; Wl[1][k] = W1[k]; Wl[2][k] = W2[k];
    }
    __syncthreads();
    const float c0 = cvec[0], c1 = cvec[1], c2 = cvec[2], c3 = cvec[3];
    const float scale = 1.0507009873554805f;
    const float alpha = 1.6732632423543772f;
    for (int m = blockIdx.x * 4 + wave; m < M_FINAL; m += gridDim.x * 4) {
        float r =
            c0 * ((ALL[((size_t)0 * M_FINAL + m) * 64 + lane] - musig[0 * 128 + lane]) * musig[0 * 128 + 64 + lane]) +
            c1 * ((ALL[((size_t)1 * M_FINAL + m) * 64 + lane] - musig[1 * 128 + lane]) * musig[1 * 128 + 64 + lane]) +
            c2 * ((ALL[((size_t)2 * M_FINAL + m) * 64 + lane] - musig[2 * 128 + lane]) * musig[2 * 128 + 64 + lane]) +
            c3 * ((ALL[((size_t)3 * M_FINAL + m) * 64 + lane] - musig[3 * 128 + lane]) * musig[3 * 128 + 64 + lane]);
        #pragma unroll
        for (int s = 0; s < 3; ++s) {
            float o0 = 0.f, o1 = 0.f, o2 = 0.f, o3 = 0.f;
            #pragma unroll
            for (int f = 0; f < 64; f += 4) {
                o0 += rdlane(r, f)     * Wl[s][f * 64 + lane];
                o1 += rdlane(r, f + 1) * Wl[s][(f + 1) * 64 + lane];
                o2 += rdlane(r, f + 2) * Wl[s][(f + 2) * 64 + lane];
                o3 += rdlane(r, f + 3) * Wl[s][(f + 3) * 64 + lane];
            }
            float o = (o0 + o1) + (o2 + o3);
            if (s < 2) o = (o > 0.f) ? scale * o : scale * alpha * expm1f(o);
            r = o;
        }
        outp[(size_t)m * 64 + lane] = r;
    }
}

extern "C" void kernel_launch(void* const* d_in, const int* in_sizes, int n_in,
                              void* d_out, int out_size, void* d_ws, size_t ws_size,
                              hipStream_t stream) {
    const float* x = (const float*)d_in[15];

    float* ws = (float*)d_ws;
    double* dstats_all = (double*)ws;                 // 1536 doubles -> [0, 3072)
    float*  cm         = ws + 3072;                   // 256
    float*  S          = ws + 3328;                   // 16
    float*  cvec       = ws + 3344;                   // 4
    float*  musig_all  = ws + 3584;                   // 3*512 -> [3584, 5120)
    float*  Wp_all     = ws + 5120;                   // 2*4*4096 -> [5120, 37888)
    float*  csh_all    = ws + 37888;                  // 2*4*64 -> [37888, 38400)
    int*    rowptr_all = (int*)(ws + 38400);          // 12*768 -> [38400, 47616)
    int*    colsrc_all = (int*)(ws + 47616);          // 12*8192 -> [47616, 145920)
    float*  sS1        = ws + 145920;                 // 180736
    float*  sD1        = sS1 + 180736;
    float*  sS2        = sD1 + 180736;                // 90624
    float*  sD2        = sS2 + 90624;
    __half* A16        = (__half*)(sD2 + 90624);      // 11,567,104 halves (5,783,552 slots)
    __half* B16        = (__half*)((float*)A16 + 5783552);  // 5,799,936 halves (2,899,968 slots)
    float*  ALLb       = (float*)B16 + 2899968;       // 2,916,352 floats
    const size_t as0h = (size_t)128 * 353 * 64;       // halves per view (layer0/1)
    const size_t as1h = (size_t)128 * 177 * 64;

    // edge sets (graph-0 structure shared by all 128 graphs)
    EdgeSets ES;
    int nemax[3] = {0, 0, 0};
    for (int s = 0; s < 12; ++s) {
        const int* e = (const int*)d_in[s];
        int E = in_sizes[s] / 2;
        ES.src[s] = e;
        ES.dst[s] = e + E;
        ES.ne[s] = E / 128;
        int lay = s % 3;
        if (ES.ne[s] > nemax[lay]) nemax[lay] = ES.ne[s];
    }

    // dynamic LDS sizes (mirror in-kernel layouts)
    int SM0 = 4096 + (706 * 6 + 8) * 4 + nemax[0] * 4 + 708 * 2;
    SM0 = (SM0 + 15) & ~15;
    int SMa1 = 4096 + (2 * 353) * 4 + nemax[1] * 4 + 355 * 2;
    SMa1 = (SMa1 + 15) & ~15;
    int SMa2 = 4096 + (2 * 177) * 4 + nemax[2] * 4 + 179 * 2;
    SMa2 = (SMa2 + 15) & ~15;
    (void)hipFuncSetAttribute(reinterpret_cast<const void*>(&layer0_kernel),
                              hipFuncAttributeMaxDynamicSharedMemorySize, SM0);
    (void)hipFuncSetAttribute(reinterpret_cast<const void*>(&agg_kernel<353, __half>),
                              hipFuncAttributeMaxDynamicSharedMemorySize, SMa1);
    (void)hipFuncSetAttribute(reinterpret_cast<const void*>(&agg_kernel<177, float>),
                              hipFuncAttributeMaxDynamicSharedMemorySize, SMa2);

    zero_kernel<<<cdiv(3584, 256), 256, 0, stream>>>(ws, 3584);
    csr_build_kernel<<<12, 768, 0, stream>>>(ES, rowptr_all, colsrc_all);

    // ---- layer 0 -> fp16 raw0 in A16 ----
    {
        L0Args A;
        A.x = x;
        for (int j = 0; j < 4; ++j) {
            int s = j * 3;
            A.rowptr[j] = rowptr_all + s * 768;
            A.colsrc[j] = colsrc_all + s * 8192;
            A.ne[j] = ES.ne[s];
            A.out[j] = A16 + j * as0h;
        }
        A.nemax = nemax[0];
        A.dstats = dstats_all;
        A.W = (const float*)d_in[16];
        A.as = (const float*)d_in[17];
        A.ad = (const float*)d_in[18];
        A.bias = (const float*)d_in[19];
        layer0_kernel<<<1024, 512, SM0, stream>>>(A);
    }
    bn_finalize_kernel<<<4, 64, 0, stream>>>(dstats_all, musig_all, 128 * 353,
                                             (const float*)d_in[20], Wp_all, csh_all);

    // ---- layer 1: in-place fp16 proj on A16, then aggregate -> B16 ----
    proj_kernel<<<dim3(320, 4), 256, 0, stream>>>(A16, Wp_all, csh_all,
                                                  (const float*)d_in[21], (const float*)d_in[22],
                                                  sS1, sD1, 353);
    {
        AggArgs A;
        for (int j = 0; j < 4; ++j) {
            int s = j * 3 + 1;
            A.rowptr[j] = rowptr_all + s * 768;
            A.colsrc[j] = colsrc_all + s * 8192;
            A.ne[j] = ES.ne[s];
            A.hp[j] = A16 + j * as0h;
            A.out[j] = B16 + j * as1h;
        }
        A.nemax = nemax[1];
        A.sS = sS1; A.sD = sD1;
        A.bias = (const float*)d_in[23];
        A.dstats = dstats_all + 512;
        agg_kernel<353, __half><<<1024, 512, SMa1, stream>>>(A);
    }
    bn_finalize_kernel<<<4, 64, 0, stream>>>(dstats_all + 512, musig_all + 512, 128 * 177,
                                             (const float*)d_in[24], Wp_all + 16384, csh_all + 256);

    // ---- layer 2: in-place fp16 proj on B16, then aggregate -> ALLb fp32 --
    proj_kernel<<<dim3(320, 4), 256, 0, stream>>>(B16, Wp_all + 16384, csh_all + 256,
                                                  (const float*)d_in[25], (const float*)d_in[26],
                                                  sS2, sD2, 177);
    {
        AggArgs A;
        for (int j = 0; j < 4; ++j) {
            int s = j * 3 + 2;
            A.rowptr[j] = rowptr_all + s * 768;
            A.colsrc[j] = colsrc_all + s * 8192;
            A.ne[j] = ES.ne[s];
            A.hp[j] = B16 + j * as1h;
            A.out[j] = ALLb + (size_t)j * M_FINAL * 64;
        }
        A.nemax = nemax[2];
        A.sS = sS2; A.sD = sD2;
        A.bias = (const float*)d_in[27];
        A.dstats = dstats_all + 1024;
        agg_kernel<177, float><<<1024, 512, SMa2, stream>>>(A);
    }
    bn_finalize_kernel<<<4, 64, 0, stream>>>(dstats_all + 1024, musig_all + 1024, 128 * 89,
                                             nullptr, nullptr, nullptr);

    // ---- fusion head ----
    const float* musig2 = musig_all + 1024;
    head_reduce_kernel<<<256, 256, 0, stream>>>(ALLb, musig2, (const float*)d_in[28], S, cm);
    fuse_small_kernel<<<1, 64, 0, stream>>>(S, cm, (const float*)d_in[29], (const float*)d_in[30], cvec);
    head_out_kernel<<<256, 256, 0, stream>>>(ALLb, musig2, cvec,
                                             (const float*)d_in[31], (const float*)d_in[32],
                                             (const float*)d_in[33], (float*)d_out);
}

// Round 10
// 468.378 us; speedup vs baseline: 3.5218x; 1.1083x over previous
//
#include <hip/hip_runtime.h>
#include <hip/hip_fp16.h>
#include <math.h>

#define DIM 64
#define M_FINAL (128*89)   // 11392 final rows

static inline int cdiv(int a, int b) { return (a + b - 1) / b; }

__device__ inline float rdlane(float v, int l) {
    return __int_as_float(__builtin_amdgcn_readlane(__float_as_int(v), l));
}
__device__ inline unsigned packpw(float p, unsigned src) {
    return ((unsigned)__half_as_ushort(__float2half(p)) << 16) | src;
}
__device__ inline float unpackpw(unsigned ep) {
    return __half2float(__ushort_as_half((unsigned short)(ep >> 16)));
}
__device__ inline void storeval(float* p, float v) { *p = v; }
__device__ inline void storeval(__half* p, float v) { *p = __float2half(v); }

struct EdgeSets {
    const int* src[12];
    const int* dst[12];
    int ne[12];
};

struct L0Args {
    const float* x;
    __half* out[4];
    const int* rowptr[4];
    const int* colsrc[4];
    int ne[4];
    int nemax;
    double* dstats;
    const float* W;
    const float* as;
    const float* ad;
    const float* bias;
};

struct AggArgs {
    const __half* hp[4];      // projected rows (out-space, fp16)
    void* out[4];
    const int* rowptr[4];
    const int* colsrc[4];
    int ne[4];
    int nemax;
    const float* sS;          // [j][g][NPIN]
    const float* sD;
    const float* bias;
    double* dstats;
};

// ---------------- misc ----------------

__global__ void zero_kernel(float* __restrict__ p, int n) {
    int i = blockIdx.x * blockDim.x + threadIdx.x;
    if (i < n) p[i] = 0.f;
}

// ---------------- fused CSR build: one block per edge set ------------------
__global__ __launch_bounds__(768)
void csr_build_kernel(EdgeSets ES, int* __restrict__ rowptr_all,
                      int* __restrict__ colsrc_all) {
    __shared__ int cnt[768];
    __shared__ int cur[768];
    const int s = blockIdx.x;
    const int lay = s % 3;
    const int n = (lay == 0) ? 706 : (lay == 1) ? 353 : 177;
    const int ne = ES.ne[s];
    const int* __restrict__ src = ES.src[s];
    const int* __restrict__ dst = ES.dst[s];
    int* __restrict__ rowptr = rowptr_all + s * 768;
    int* __restrict__ colsrc = colsrc_all + s * 8192;
    const int t = threadIdx.x;

    cnt[t] = 0;
    __syncthreads();
    for (int k = t; k < ne; k += 768) atomicAdd(&cnt[dst[k]], 1);
    __syncthreads();
    int v = cnt[t];
    for (int off = 1; off < 768; off <<= 1) {
        int add = (t >= off) ? cnt[t - off] : 0;
        __syncthreads();
        cnt[t] += add;
        __syncthreads();
    }
    int excl = cnt[t] - v;
    if (t < n) { rowptr[t] = excl; cur[t] = excl; }
    if (t == n - 1) rowptr[n] = cnt[t];
    __syncthreads();
    for (int k = t; k < ne; k += 768) {
        int pos = atomicAdd(&cur[dst[k]], 1);
        colsrc[pos] = src[k];
    }
}

// ---------------- layer 0 mega kernel (in_dim=3, thread-par agg) -----------
// grid = split(2) x view(4) x graph(128) = 1024 blocks of 512 threads.
// Each block owns <=354 children -> ONE CHILD PER THREAD: pass1 max-logit,
// pass2 exp + 3-dim accumulate in registers -> agg4 LDS; then a cheap
// wave-par matvec+pool+store+BN phase.
__global__ __launch_bounds__(512, 8)
void layer0_kernel(L0Args A) {
    constexpr int NPIN = 706, NPOUT = 353, HALF = 177;

    extern __shared__ char smem[];
    float* sredF = (float*)smem;                       // [2][8][64] = 4096 B
    float* fp = (float*)(smem + 4096);
    float* sSrc = fp; fp += NPIN;
    float* sDst = fp; fp += NPIN;
    float* hL4  = fp; fp += NPIN * 4;
    float* agg4 = fp; fp += 356 * 4;
    float* waL0 = fp; fp += 8;
    unsigned short* rp16 = (unsigned short*)fp;        // 708

    const int split = blockIdx.x >> 9;
    const int jg = blockIdx.x & 511;
    const int j = jg >> 7;
    const int g = jg & 127;
    const int tid = threadIdx.x;
    const int wave = tid >> 6;
    const int lane = tid & 63;

    const int n0c = split * HALF;
    const int n1c = min(NPOUT, n0c + HALF);
    const int ch0 = 2 * n0c;
    const int ch1 = 2 * n1c;          // NPIN even -> always valid children

    const int* __restrict__ rowptr = A.rowptr[j];
    const int* __restrict__ colsrc = A.colsrc[j];
    const float* __restrict__ W = A.W;

    for (int k = tid; k <= NPIN; k += 512) rp16[k] = (unsigned short)rowptr[k];
    if (tid < 6) {                    // wa_{src,dst}[f] = sum_d W[f][d]*a[d]
        int f = (tid < 3) ? tid : tid - 3;
        const float* av = (tid < 3) ? A.as : A.ad;
        float acc = 0.f;
        for (int d = 0; d < 64; ++d) acc += W[f * 64 + d] * av[d];
        waL0[tid] = acc;
    }
    __syncthreads();

    // h staging + s-dots
    {
        const float* hb = A.x + (size_t)g * (NPIN * 3);
        for (int r = tid; r < NPIN; r += 512) {
            float h0 = hb[r * 3], h1 = hb[r * 3 + 1], h2 = hb[r * 3 + 2];
            hL4[r * 4] = h0; hL4[r * 4 + 1] = h1; hL4[r * 4 + 2] = h2; hL4[r * 4 + 3] = 0.f;
            sSrc[r] = h0 * waL0[0] + h1 * waL0[1] + h2 * waL0[2];
            sDst[r] = h0 * waL0[3] + h1 * waL0[4] + h2 * waL0[5];
        }
    }
    __syncthreads();

    // thread-par softmax + aggregation: one child per thread
    const int child = ch0 + tid;
    if (child < ch1) {
        int s0 = rp16[child], e0 = rp16[child + 1];
        float sd = sDst[child];
        float m = -1e30f;
        for (int k = s0; k < e0; ++k) {
            float v = sSrc[colsrc[k]] + sd;
            v = (v >= 0.f) ? v : 0.2f * v;
            m = fmaxf(m, v);
        }
        float z = 0.f, a0 = 0.f, a1 = 0.f, a2 = 0.f;
        for (int k = s0; k < e0; ++k) {
            int sl = colsrc[k];
            float v = sSrc[sl] + sd;
            v = (v >= 0.f) ? v : 0.2f * v;
            float p = __expf(v - m);
            z += p;
            a0 += p * hL4[sl * 4];
            a1 += p * hL4[sl * 4 + 1];
            a2 += p * hL4[sl * 4 + 2];
        }
        float iz = 1.f / z;
        agg4[tid * 4]     = a0 * iz;
        agg4[tid * 4 + 1] = a1 * iz;
        agg4[tid * 4 + 2] = a2 * iz;
        agg4[tid * 4 + 3] = 0.f;
    }
    __syncthreads();

    // wave-par matvec + relu + pool + store + BN stats
    const float w0 = W[lane], w1 = W[64 + lane], w2 = W[128 + lane];
    const float b_l = A.bias[lane];
    __half* outj = A.out[j];
    const float4* agg4v = (const float4*)agg4;
    float bs = 0.f, bs2 = 0.f;

    for (int c = n0c + wave; c < n1c; c += 8) {
        int lc = 2 * (c - n0c);
        float4 va = agg4v[lc];
        float4 vb = agg4v[lc + 1];
        float oa = va.x * w0 + va.y * w1 + va.z * w2 + b_l;
        float ob = vb.x * w0 + vb.y * w1 + vb.z * w2 + b_l;
        float vmax = fmaxf(fmaxf(oa, ob), 0.f);
        outj[((size_t)g * NPOUT + c) * 64 + lane] = __float2half(vmax);
        bs += vmax;
        bs2 += vmax * vmax;
    }
    sredF[wave * 64 + lane] = bs;
    sredF[512 + wave * 64 + lane] = bs2;
    __syncthreads();
    if (wave == 0) {
        float t1 = 0.f, t2 = 0.f;
        #pragma unroll
        for (int w = 0; w < 8; ++w) {
            t1 += sredF[w * 64 + lane];
            t2 += sredF[512 + w * 64 + lane];
        }
        atomicAdd(A.dstats + j * 128 + lane, (double)t1);
        atomicAdd(A.dstats + j * 128 + 64 + lane, (double)t2);
    }
}

// BN finalize; optionally fold stats into next layer's weight:
// Wp[f][d] = rs[f]*Wn[f][d]; csh[d] = sum_f mu[f]*rs[f]*Wn[f][d]
__global__ void bn_finalize_kernel(const double* __restrict__ dstats,
                                   float* __restrict__ musig, int n_rows,
                                   const float* __restrict__ Wn,
                                   float* __restrict__ Wp, float* __restrict__ csh) {
    __shared__ float mur[128];
    int jv = blockIdx.x;           // view
    int d = threadIdx.x;           // 64
    double mu = dstats[jv * 128 + d] / n_rows;
    double var = dstats[jv * 128 + 64 + d] / n_rows - mu * mu;
    float rs = rsqrtf((float)var + 1e-5f);
    musig[jv * 128 + d] = (float)mu;
    musig[jv * 128 + 64 + d] = rs;
    if (Wn != nullptr) {
        mur[d] = (float)mu; mur[64 + d] = rs;
        __syncthreads();
        float c = 0.f;
        for (int f = 0; f < 64; ++f) {
            float wp = mur[64 + f] * Wn[f * 64 + d];
            Wp[jv * 4096 + f * 64 + d] = wp;
            c += mur[f] * wp;
        }
        csh[jv * 64 + d] = c;
    }
}

// ---------------- projection: HP = h @ W' - c, fp16 in-place + s-dots ------
// grid (320, view); block 256 = 4 waves; wave per ROW PAIR (2-row ILP).
__global__ __launch_bounds__(256, 5)
void proj_kernel(__half* __restrict__ buf, const float* __restrict__ Wp_all,
                 const float* __restrict__ csh_all,
                 const float* __restrict__ a_s, const float* __restrict__ a_d,
                 float* __restrict__ sS, float* __restrict__ sD, int npin) {
    const int j = blockIdx.y;
    const int lane = threadIdx.x & 63, wave = threadIdx.x >> 6;
    const int R = 128 * npin;
    const int P = R >> 1;              // R is even
    __half* h = buf + (size_t)j * R * 64;
    const float* Wp = Wp_all + j * 4096;
    float Wreg[64];
    #pragma unroll
    for (int f = 0; f < 64; ++f) Wreg[f] = Wp[f * 64 + lane];
    const float cst = csh_all[j * 64 + lane];
    const float asv = a_s[lane], adv = a_d[lane];
    const int nw = gridDim.x * 4;
    for (int pr = blockIdx.x * 4 + wave; pr < P; pr += nw) {
        int r0 = pr * 2;
        float va = __half2float(h[(size_t)r0 * 64 + lane]);
        float vb = __half2float(h[(size_t)r0 * 64 + 64 + lane]);
        float o0 = 0.f, o1 = 0.f, q0 = 0.f, q1 = 0.f;
        #pragma unroll
        for (int f = 0; f < 64; f += 2) {
            o0 += rdlane(va, f)     * Wreg[f];
            q0 += rdlane(vb, f)     * Wreg[f];
            o1 += rdlane(va, f + 1) * Wreg[f + 1];
            q1 += rdlane(vb, f + 1) * Wreg[f + 1];
        }
        float oa = (o0 + o1) - cst, ob = (q0 + q1) - cst;
        h[(size_t)r0 * 64 + lane] = __float2half(oa);
        h[(size_t)r0 * 64 + 64 + lane] = __float2half(ob);
        float aa = oa * asv, da = oa * adv, ab = ob * asv, db = ob * adv;
        for (int off = 32; off > 0; off >>= 1) {
            aa += __shfl_down(aa, off, 64);
            da += __shfl_down(da, off, 64);
            ab += __shfl_down(ab, off, 64);
            db += __shfl_down(db, off, 64);
        }
        if (lane == 0) {
            sS[j * R + r0] = aa;     sD[j * R + r0] = da;
            sS[j * R + r0 + 1] = ab; sD[j * R + r0 + 1] = db;
        }
    }
}

// ---------------- aggregation (L>0): softmax + fp16 gather + pool + BN -----
// grid = split(2) x view(4) x graph(128) = 1024 blocks of 512 threads.
template<int NPIN, typename OutT>
__global__ __launch_bounds__(512, 8)
void agg_kernel(AggArgs A) {
    constexpr int NPOUT = (NPIN + 1) / 2;
    constexpr int HALF = (NPOUT + 1) / 2;

    extern __shared__ char smem[];
    float* sredF = (float*)smem;                       // 4096 B
    float* fp = (float*)(smem + 4096);
    float* sSrc = fp; fp += NPIN;
    float* sDst = fp; fp += NPIN;
    unsigned* ep32 = (unsigned*)fp;
    unsigned short* rp16 = (unsigned short*)(ep32 + A.nemax);

    const int split = blockIdx.x >> 9;
    const int jg = blockIdx.x & 511;
    const int j = jg >> 7;
    const int g = jg & 127;
    const int tid = threadIdx.x;
    const int wave = tid >> 6;
    const int lane = tid & 63;

    const int n0c = split * HALF;
    const int n1c = min(NPOUT, n0c + HALF);
    const int ch0 = 2 * n0c;
    const int ch1 = min(NPIN, 2 * n1c);

    const int* __restrict__ rowptr = A.rowptr[j];
    const int* __restrict__ colsrc = A.colsrc[j];
    const int ne = A.ne[j];
    const int sbase = (j * 128 + g) * NPIN;
    // per-lane gather base: hp row sl is at hpg + sl*64 (halves)
    const __half* __restrict__ hpg = A.hp[j] + (size_t)g * NPIN * 64 + lane;

    for (int k = tid; k <= NPIN; k += 512) rp16[k] = (unsigned short)rowptr[k];
    for (int k = tid; k < ne; k += 512) ep32[k] = (unsigned)colsrc[k];
    for (int r = tid; r < NPIN; r += 512) {
        sSrc[r] = A.sS[sbase + r];
        sDst[r] = A.sD[sbase + r];
    }
    __syncthreads();

    for (int r = ch0 + tid; r < ch1; r += 512) {
        int s0 = rp16[r], e0 = rp16[r + 1];
        float sd = sDst[r];
        float m = -1e30f, z = 0.f;
        for (int k = s0; k < e0; ++k) {
            float v = sSrc[ep32[k] & 0xFFFFu] + sd;
            v = (v >= 0.f) ? v : 0.2f * v;
            if (v > m) { z = z * __expf(m - v) + 1.f; m = v; }
            else z += __expf(v - m);
        }
        float invz = 1.f / z;
        for (int k = s0; k < e0; ++k) {
            unsigned sl = ep32[k] & 0xFFFFu;
            float v = sSrc[sl] + sd;
            v = (v >= 0.f) ? v : 0.2f * v;
            ep32[k] = packpw(__expf(v - m) * invz, sl);
        }
    }
    __syncthreads();

    const float b_l = A.bias[lane];
    OutT* outj = (OutT*)A.out[j];
    float bs = 0.f, bs2 = 0.f;

    for (int c = n0c + wave; c < n1c; c += 8) {
        float vmax = 0.f;
        #pragma unroll
        for (int ch = 0; ch < 2; ++ch) {
            int child = 2 * c + ch;
            if (child >= NPIN) break;
            int s0 = rp16[child], e0 = rp16[child + 1];
            float acc0 = 0.f, acc1 = 0.f;
            int k = s0;
            for (; k + 4 <= e0; k += 4) {
                unsigned ea = ep32[k], eb = ep32[k + 1], ec = ep32[k + 2], ed = ep32[k + 3];
                float ha = __half2float(hpg[(size_t)(ea & 0xFFFFu) << 6]);
                float hb = __half2float(hpg[(size_t)(eb & 0xFFFFu) << 6]);
                float hc = __half2float(hpg[(size_t)(ec & 0xFFFFu) << 6]);
                float hd = __half2float(hpg[(size_t)(ed & 0xFFFFu) << 6]);
                acc0 += unpackpw(ea) * ha + unpackpw(eb) * hb;
                acc1 += unpackpw(ec) * hc + unpackpw(ed) * hd;
            }
            for (; k < e0; ++k) {
                unsigned ea = ep32[k];
                acc0 += unpackpw(ea) * __half2float(hpg[(size_t)(ea & 0xFFFFu) << 6]);
            }
            float o = acc0 + acc1 + b_l;
            vmax = fmaxf(vmax, fmaxf(o, 0.f));
        }
        storeval(&outj[((size_t)g * NPOUT + c) * 64 + lane], vmax);
        bs += vmax;
        bs2 += vmax * vmax;
    }
    sredF[wave * 64 + lane] = bs;
    sredF[512 + wave * 64 + lane] = bs2;
    __syncthreads();
    if (wave == 0) {
        float t1 = 0.f, t2 = 0.f;
        #pragma unroll
        for (int w = 0; w < 8; ++w) {
            t1 += sredF[w * 64 + lane];
            t2 += sredF[512 + w * 64 + lane];
        }
        atomicAdd(A.dstats + j * 128 + lane, (double)t1);
        atomicAdd(A.dstats + j * 128 + 64 + lane, (double)t2);
    }
}

// ---------------- fused head reduce: Bm dots -> S (BmT Bm) + column means --
__global__ __launch_bounds__(256)
void head_reduce_kernel(const float* __restrict__ ALL, const float* __restrict__ musig,
                        const float* __restrict__ w_attn,
                        float* __restrict__ S, float* __restrict__ cm) {
    __shared__ float S_loc[16];
    __shared__ float cm_loc[256];
    const int t = threadIdx.x, wave = t >> 6, lane = t & 63;
    if (t < 16) S_loc[t] = 0.f;
    cm_loc[t] = 0.f;
    __syncthreads();
    const float wa = w_attn[lane];
    float cacc[4] = {0.f, 0.f, 0.f, 0.f};
    for (int m = blockIdx.x * 4 + wave; m < M_FINAL; m += gridDim.x * 4) {
        float b4[4];
        float csum = 0.f;
        #pragma unroll
        for (int v = 0; v < 4; ++v) {
            float val = (ALL[((size_t)v * M_FINAL + m) * 64 + lane] - musig[v * 128 + lane])
                        * musig[v * 128 + 64 + lane];
            csum += val;
            float p = val * wa;
            for (int off = 32; off > 0; off >>= 1) p += __shfl_down(p, off, 64);
            b4[v] = __shfl(p, 0, 64);
        }
        cacc[m & 3] += csum;
        if (lane < 16) atomicAdd(&S_loc[lane], b4[lane >> 2] * b4[lane & 3]);
    }
    #pragma unroll
    for (int q = 0; q < 4; ++q) atomicAdd(&cm_loc[q * 64 + lane], cacc[q]);
    __syncthreads();
    if (t < 16) atomicAdd(&S[t], S_loc[t]);
    atomicAdd(&cm[t], cm_loc[t]);
}

__global__ void fuse_small_kernel(const float* __restrict__ S, const float* __restrict__ cm,
                                  const float* __restrict__ w_lin0, const float* __restrict__ b_lin0,
                                  float* __restrict__ cvec) {
    if (threadIdx.x != 0 || blockIdx.x != 0) return;
    float cn[4];
    for (int v = 0; v < 4; ++v) cn[v] = sqrtf(S[v * 4 + v]);
    float A[16];
    for (int u = 0; u < 4; ++u) {
        float row[4]; float mx = -1e30f;
        for (int v = 0; v < 4; ++v) {
            float g = S[u * 4 + v] / (cn[u] * cn[v]);
            g = (g >= 0.f) ? g : 0.1f * g;       // leaky_relu 0.1
            row[v] = g; mx = fmaxf(mx, g);
        }
        float sum = 0.f;
        for (int v = 0; v < 4; ++v) { row[v] = expf(row[v] - mx); sum += row[v]; }
        for (int v = 0; v < 4; ++v) A[u * 4 + v] = row[v] / sum;
    }
    float e4[4];
    for (int v = 0; v < 4; ++v) {
        float a = b_lin0[v];
        for (int c = 0; c < 256; ++c) a += (cm[c] / (float)M_FINAL) * w_lin0[c * 4 + v];
        e4[v] = a;
    }
    float mx = fmaxf(fmaxf(e4[0], e4[1]), fmaxf(e4[2], e4[3]));
    float sum = 0.f, w[4];
    for (int v = 0; v < 4; ++v) { w[v] = expf(e4[v] - mx); sum += w[v]; }
    for (int v = 0; v < 4; ++v) w[v] /= sum;
    for (int k = 0; k < 4; ++k) {
        float c = 0.f;
        for (int v = 0; v < 4; ++v) c += A[k * 4 + v] * w[v];
        cvec[k] = c;
    }
}

// ---------------- fused head output: combine + 3 matvecs (selu,selu,none) --
__global__ __launch_bounds__(256)
void head_out_kernel(const float* __restrict__ ALL, const float* __restrict__ musig,
                     const float* __restrict__ cvec,
                     const float* __restrict__ W0, const float* __restrict__ W1,
                     const float* __restrict__ W2, float* __restrict__ outp) {
    __shared__ float Wl[3][64 * 64];   // 48 KB
    const int t = threadIdx.x, wave = t >> 6, lane = t & 63;
    for (int k = t; k < 4096; k += 256) {
        Wl[0][k] = W0[k]; Wl[1][k] = W1[k]; Wl[2][k] = W2[k];
    }
    __syncthreads();
    const float c0 = cvec[0], c1 = cvec[1], c2 = cvec[2], c3 = cvec[3];
    const float scale = 1.0507009873554805f;
    const float alpha = 1.6732632423543772f;
    for (int m = blockIdx.x * 4 + wave; m < M_FINAL; m += gridDim.x * 4) {
        float r =
            c0 * ((ALL[((size_t)0 * M_FINAL + m) * 64 + lane] - musig[0 * 128 + lane]) * musig[0 * 128 + 64 + lane]) +
            c1 * ((ALL[((size_t)1 * M_FINAL + m) * 64 + lane] - musig[1 * 128 + lane]) * musig[1 * 128 + 64 + lane]) +
            c2 * ((ALL[((size_t)2 * M_FINAL + m) * 64 + lane] - musig[2 * 128 + lane]) * musig[2 * 128 + 64 + lane]) +
            c3 * ((ALL[((size_t)3 * M_FINAL + m) * 64 + lane] - musig[3 * 128 + lane]) * musig[3 * 128 + 64 + lane]);
        #pragma unroll
        for (int s = 0; s < 3; ++s) {
            float o0 = 0.f, o1 = 0.f, o2 = 0.f, o3 = 0.f;
            #pragma unroll
            for (int f = 0; f < 64; f += 4) {
                o0 += rdlane(r, f)     * Wl[s][f * 64 + lane];
                o1 += rdlane(r, f + 1) * Wl[s][(f + 1) * 64 + lane];
                o2 += rdlane(r, f + 2) * Wl[s][(f + 2) * 64 + lane];
                o3 += rdlane(r, f + 3) * Wl[s][(f + 3) * 64 + lane];
            }
            float o = (o0 + o1) + (o2 + o3);
            if (s < 2) o = (o > 0.f) ? scale * o : scale * alpha * expm1f(o);
            r = o;
        }
        outp[(size_t)m * 64 + lane] = r;
    }
}

extern "C" void kernel_launch(void* const* d_in, const int* in_sizes, int n_in,
                              void* d_out, int out_size, void* d_ws, size_t ws_size,
                              hipStream_t stream) {
    const float* x = (const float*)d_in[15];

    float* ws = (float*)d_ws;
    double* dstats_all = (double*)ws;                 // 1536 doubles -> [0, 3072)
    float*  cm         = ws + 3072;                   // 256
    float*  S          = ws + 3328;                   // 16
    float*  cvec       = ws + 3344;                   // 4
    float*  musig_all  = ws + 3584;                   // 3*512 -> [3584, 5120)
    float*  Wp_all     = ws + 5120;                   // 2*4*4096 -> [5120, 37888)
    float*  csh_all    = ws + 37888;                  // 2*4*64 -> [37888, 38400)
    int*    rowptr_all = (int*)(ws + 38400);          // 12*768 -> [38400, 47616)
    int*    colsrc_all = (int*)(ws + 47616);          // 12*8192 -> [47616, 145920)
    float*  sS1        = ws + 145920;                 // 180736
    float*  sD1        = sS1 + 180736;
    float*  sS2        = sD1 + 180736;                // 90624
    float*  sD2        = sS2 + 90624;
    __half* A16        = (__half*)(sD2 + 90624);      // 11,567,104 halves (5,783,552 slots)
    __half* B16        = (__half*)((float*)A16 + 5783552);  // 5,799,936 halves (2,899,968 slots)
    float*  ALLb       = (float*)B16 + 2899968;       // 2,916,352 floats
    const size_t as0h = (size_t)128 * 353 * 64;       // halves per view (layer0/1)
    const size_t as1h = (size_t)128 * 177 * 64;

    // edge sets (graph-0 structure shared by all 128 graphs)
    EdgeSets ES;
    int nemax[3] = {0, 0, 0};
    for (int s = 0; s < 12; ++s) {
        const int* e = (const int*)d_in[s];
        int E = in_sizes[s] / 2;
        ES.src[s] = e;
        ES.dst[s] = e + E;
        ES.ne[s] = E / 128;
        int lay = s % 3;
        if (ES.ne[s] > nemax[lay]) nemax[lay] = ES.ne[s];
    }

    // dynamic LDS sizes (mirror in-kernel layouts)
    int SM0 = 4096 + (706 * 6 + 356 * 4 + 8) * 4 + 708 * 2;
    SM0 = (SM0 + 15) & ~15;
    int SMa1 = 4096 + (2 * 353) * 4 + nemax[1] * 4 + 355 * 2;
    SMa1 = (SMa1 + 15) & ~15;
    int SMa2 = 4096 + (2 * 177) * 4 + nemax[2] * 4 + 179 * 2;
    SMa2 = (SMa2 + 15) & ~15;
    (void)hipFuncSetAttribute(reinterpret_cast<const void*>(&layer0_kernel),
                              hipFuncAttributeMaxDynamicSharedMemorySize, SM0);
    (void)hipFuncSetAttribute(reinterpret_cast<const void*>(&agg_kernel<353, __half>),
                              hipFuncAttributeMaxDynamicSharedMemorySize, SMa1);
    (void)hipFuncSetAttribute(reinterpret_cast<const void*>(&agg_kernel<177, float>),
                              hipFuncAttributeMaxDynamicSharedMemorySize, SMa2);

    zero_kernel<<<cdiv(3584, 256), 256, 0, stream>>>(ws, 3584);
    csr_build_kernel<<<12, 768, 0, stream>>>(ES, rowptr_all, colsrc_all);

    // ---- layer 0 -> fp16 raw0 in A16 ----
    {
        L0Args A;
        A.x = x;
        for (int j = 0; j < 4; ++j) {
            int s = j * 3;
            A.rowptr[j] = rowptr_all + s * 768;
            A.colsrc[j] = colsrc_all + s * 8192;
            A.ne[j] = ES.ne[s];
            A.out[j] = A16 + j * as0h;
        }
        A.nemax = nemax[0];
        A.dstats = dstats_all;
        A.W = (const float*)d_in[16];
        A.as = (const float*)d_in[17];
        A.ad = (const float*)d_in[18];
        A.bias = (const float*)d_in[19];
        layer0_kernel<<<1024, 512, SM0, stream>>>(A);
    }
    bn_finalize_kernel<<<4, 64, 0, stream>>>(dstats_all, musig_all, 128 * 353,
                                             (const float*)d_in[20], Wp_all, csh_all);

    // ---- layer 1: in-place fp16 proj on A16, then aggregate -> B16 ----
    proj_kernel<<<dim3(320, 4), 256, 0, stream>>>(A16, Wp_all, csh_all,
                                                  (const float*)d_in[21], (const float*)d_in[22],
                                                  sS1, sD1, 353);
    {
        AggArgs A;
        for (int j = 0; j < 4; ++j) {
            int s = j * 3 + 1;
            A.rowptr[j] = rowptr_all + s * 768;
            A.colsrc[j] = colsrc_all + s * 8192;
            A.ne[j] = ES.ne[s];
            A.hp[j] = A16 + j * as0h;
            A.out[j] = B16 + j * as1h;
        }
        A.nemax = nemax[1];
        A.sS = sS1; A.sD = sD1;
        A.bias = (const float*)d_in[23];
        A.dstats = dstats_all + 512;
        agg_kernel<353, __half><<<1024, 512, SMa1, stream>>>(A);
    }
    bn_finalize_kernel<<<4, 64, 0, stream>>>(dstats_all + 512, musig_all + 512, 128 * 177,
                                             (const float*)d_in[24], Wp_all + 16384, csh_all + 256);

    // ---- layer 2: in-place fp16 proj on B16, then aggregate -> ALLb fp32 --
    proj_kernel<<<dim3(320, 4), 256, 0, stream>>>(B16, Wp_all + 16384, csh_all + 256,
                                                  (const float*)d_in[25], (const float*)d_in[26],
                                                  sS2, sD2, 177);
    {
        AggArgs A;
        for (int j = 0; j < 4; ++j) {
            int s = j * 3 + 2;
            A.rowptr[j] = rowptr_all + s * 768;
            A.colsrc[j] = colsrc_all + s * 8192;
            A.ne[j] = ES.ne[s];
            A.hp[j] = B16 + j * as1h;
            A.out[j] = ALLb + (size_t)j * M_FINAL * 64;
        }
        A.nemax = nemax[2];
        A.sS = sS2; A.sD = sD2;
        A.bias = (const float*)d_in[27];
        A.dstats = dstats_all + 1024;
        agg_kernel<177, float><<<1024, 512, SMa2, stream>>>(A);
    }
    bn_finalize_kernel<<<4, 64, 0, stream>>>(dstats_all + 1024, musig_all + 1024, 128 * 89,
                                             nullptr, nullptr, nullptr);

    // ---- fusion head ----
    const float* musig2 = musig_all + 1024;
    head_reduce_kernel<<<256, 256, 0, stream>>>(ALLb, musig2, (const float*)d_in[28], S, cm);
    fuse_small_kernel<<<1, 64, 0, stream>>>(S, cm, (const float*)d_in[29], (const float*)d_in[30], cvec);
    head_out_kernel<<<256, 256, 0, stream>>>(ALLb, musig2, cvec,
                                             (const float*)d_in[31], (const float*)d_in[32],
                                             (const float*)d_in[33], (float*)d_out);
}

// Round 11
// 416.394 us; speedup vs baseline: 3.9614x; 1.1248x over previous
//
#include <hip/hip_runtime.h>
#include <hip/hip_fp16.h>
#include <math.h>

#define DIM 64
#define M_FINAL (128*89)   // 11392 final rows

static inline int cdiv(int a, int b) { return (a + b - 1) / b; }

__device__ inline float rdlane(float v, int l) {
    return __int_as_float(__builtin_amdgcn_readlane(__float_as_int(v), l));
}
__device__ inline unsigned packpw(float p, unsigned src) {
    return ((unsigned)__half_as_ushort(__float2half(p)) << 16) | src;
}
__device__ inline float unpackpw(unsigned ep) {
    return __half2float(__ushort_as_half((unsigned short)(ep >> 16)));
}
__device__ inline void storeval(float* p, float v) { *p = v; }
__device__ inline void storeval(__half* p, float v) { *p = __float2half(v); }

struct EdgeSets {
    const int* src[12];
    const int* dst[12];
    int ne[12];
};

struct L0Args {
    const float* x;
    __half* out[4];
    const int* rowptr[4];
    const int* colsrc[4];
    int ne[4];
    int nemax;
    double* dstats;
    const float* W;
    const float* as;
    const float* ad;
    const float* bias;
};

struct AggArgs {
    const __half* hp[4];      // projected rows (out-space, fp16)
    void* out[4];
    const int* rowptr[4];
    const int* colsrc[4];
    int ne[4];
    int nemax;
    const float* sS;          // [j][g][NPIN]
    const float* sD;
    const float* bias;
    double* dstats;
};

// ---------------- misc ----------------

__global__ void zero_kernel(float* __restrict__ p, int n) {
    int i = blockIdx.x * blockDim.x + threadIdx.x;
    if (i < n) p[i] = 0.f;
}

// ---------------- fused CSR build: one block per edge set ------------------
__global__ __launch_bounds__(768)
void csr_build_kernel(EdgeSets ES, int* __restrict__ rowptr_all,
                      int* __restrict__ colsrc_all) {
    __shared__ int cnt[768];
    __shared__ int cur[768];
    const int s = blockIdx.x;
    const int lay = s % 3;
    const int n = (lay == 0) ? 706 : (lay == 1) ? 353 : 177;
    const int ne = ES.ne[s];
    const int* __restrict__ src = ES.src[s];
    const int* __restrict__ dst = ES.dst[s];
    int* __restrict__ rowptr = rowptr_all + s * 768;
    int* __restrict__ colsrc = colsrc_all + s * 8192;
    const int t = threadIdx.x;

    cnt[t] = 0;
    __syncthreads();
    for (int k = t; k < ne; k += 768) atomicAdd(&cnt[dst[k]], 1);
    __syncthreads();
    int v = cnt[t];
    for (int off = 1; off < 768; off <<= 1) {
        int add = (t >= off) ? cnt[t - off] : 0;
        __syncthreads();
        cnt[t] += add;
        __syncthreads();
    }
    int excl = cnt[t] - v;
    if (t < n) { rowptr[t] = excl; cur[t] = excl; }
    if (t == n - 1) rowptr[n] = cnt[t];
    __syncthreads();
    for (int k = t; k < ne; k += 768) {
        int pos = atomicAdd(&cur[dst[k]], 1);
        colsrc[pos] = src[k];
    }
}

// ---------------- layer 0 mega kernel (in_dim=3, thread-par agg) -----------
// grid = split(2) x view(4) x graph(128) = 1024 blocks of 512 threads.
__global__ __launch_bounds__(512, 8)
void layer0_kernel(L0Args A) {
    constexpr int NPIN = 706, NPOUT = 353, HALF = 177;

    extern __shared__ char smem[];
    float* sredF = (float*)smem;                       // [2][8][64] = 4096 B
    float* fp = (float*)(smem + 4096);
    float* sSrc = fp; fp += NPIN;
    float* sDst = fp; fp += NPIN;
    float* hL4  = fp; fp += NPIN * 4;
    float* agg4 = fp; fp += 356 * 4;
    float* waL0 = fp; fp += 8;
    unsigned short* rp16 = (unsigned short*)fp;        // 708

    const int split = blockIdx.x >> 9;
    const int jg = blockIdx.x & 511;
    const int j = jg >> 7;
    const int g = jg & 127;
    const int tid = threadIdx.x;
    const int wave = tid >> 6;
    const int lane = tid & 63;

    const int n0c = split * HALF;
    const int n1c = min(NPOUT, n0c + HALF);
    const int ch0 = 2 * n0c;
    const int ch1 = 2 * n1c;          // NPIN even -> always valid children

    const int* __restrict__ rowptr = A.rowptr[j];
    const int* __restrict__ colsrc = A.colsrc[j];
    const float* __restrict__ W = A.W;

    for (int k = tid; k <= NPIN; k += 512) rp16[k] = (unsigned short)rowptr[k];
    if (tid < 6) {                    // wa_{src,dst}[f] = sum_d W[f][d]*a[d]
        int f = (tid < 3) ? tid : tid - 3;
        const float* av = (tid < 3) ? A.as : A.ad;
        float acc = 0.f;
        for (int d = 0; d < 64; ++d) acc += W[f * 64 + d] * av[d];
        waL0[tid] = acc;
    }
    __syncthreads();

    // h staging + s-dots
    {
        const float* hb = A.x + (size_t)g * (NPIN * 3);
        for (int r = tid; r < NPIN; r += 512) {
            float h0 = hb[r * 3], h1 = hb[r * 3 + 1], h2 = hb[r * 3 + 2];
            hL4[r * 4] = h0; hL4[r * 4 + 1] = h1; hL4[r * 4 + 2] = h2; hL4[r * 4 + 3] = 0.f;
            sSrc[r] = h0 * waL0[0] + h1 * waL0[1] + h2 * waL0[2];
            sDst[r] = h0 * waL0[3] + h1 * waL0[4] + h2 * waL0[5];
        }
    }
    __syncthreads();

    // thread-par softmax + aggregation: one child per thread
    const int child = ch0 + tid;
    if (child < ch1) {
        int s0 = rp16[child], e0 = rp16[child + 1];
        float sd = sDst[child];
        float m = -1e30f;
        for (int k = s0; k < e0; ++k) {
            float v = sSrc[colsrc[k]] + sd;
            v = (v >= 0.f) ? v : 0.2f * v;
            m = fmaxf(m, v);
        }
        float z = 0.f, a0 = 0.f, a1 = 0.f, a2 = 0.f;
        for (int k = s0; k < e0; ++k) {
            int sl = colsrc[k];
            float v = sSrc[sl] + sd;
            v = (v >= 0.f) ? v : 0.2f * v;
            float p = __expf(v - m);
            z += p;
            a0 += p * hL4[sl * 4];
            a1 += p * hL4[sl * 4 + 1];
            a2 += p * hL4[sl * 4 + 2];
        }
        float iz = 1.f / z;
        agg4[tid * 4]     = a0 * iz;
        agg4[tid * 4 + 1] = a1 * iz;
        agg4[tid * 4 + 2] = a2 * iz;
        agg4[tid * 4 + 3] = 0.f;
    }
    __syncthreads();

    // wave-par matvec + relu + pool + store + BN stats
    const float w0 = W[lane], w1 = W[64 + lane], w2 = W[128 + lane];
    const float b_l = A.bias[lane];
    __half* outj = A.out[j];
    const float4* agg4v = (const float4*)agg4;
    float bs = 0.f, bs2 = 0.f;

    for (int c = n0c + wave; c < n1c; c += 8) {
        int lc = 2 * (c - n0c);
        float4 va = agg4v[lc];
        float4 vb = agg4v[lc + 1];
        float oa = va.x * w0 + va.y * w1 + va.z * w2 + b_l;
        float ob = vb.x * w0 + vb.y * w1 + vb.z * w2 + b_l;
        float vmax = fmaxf(fmaxf(oa, ob), 0.f);
        outj[((size_t)g * NPOUT + c) * 64 + lane] = __float2half(vmax);
        bs += vmax;
        bs2 += vmax * vmax;
    }
    sredF[wave * 64 + lane] = bs;
    sredF[512 + wave * 64 + lane] = bs2;
    __syncthreads();
    if (wave == 0) {
        float t1 = 0.f, t2 = 0.f;
        #pragma unroll
        for (int w = 0; w < 8; ++w) {
            t1 += sredF[w * 64 + lane];
            t2 += sredF[512 + w * 64 + lane];
        }
        atomicAdd(A.dstats + j * 128 + lane, (double)t1);
        atomicAdd(A.dstats + j * 128 + 64 + lane, (double)t2);
    }
}

// BN finalize; optionally fold stats into next layer's weight:
// Wp[f][d] = rs[f]*Wn[f][d]; csh[d] = sum_f mu[f]*rs[f]*Wn[f][d]
__global__ void bn_finalize_kernel(const double* __restrict__ dstats,
                                   float* __restrict__ musig, int n_rows,
                                   const float* __restrict__ Wn,
                                   float* __restrict__ Wp, float* __restrict__ csh) {
    __shared__ float mur[128];
    int jv = blockIdx.x;           // view
    int d = threadIdx.x;           // 64
    double mu = dstats[jv * 128 + d] / n_rows;
    double var = dstats[jv * 128 + 64 + d] / n_rows - mu * mu;
    float rs = rsqrtf((float)var + 1e-5f);
    musig[jv * 128 + d] = (float)mu;
    musig[jv * 128 + 64 + d] = rs;
    if (Wn != nullptr) {
        mur[d] = (float)mu; mur[64 + d] = rs;
        __syncthreads();
        float c = 0.f;
        for (int f = 0; f < 64; ++f) {
            float wp = mur[64 + f] * Wn[f * 64 + d];
            Wp[jv * 4096 + f * 64 + d] = wp;
            c += mur[f] * wp;
        }
        csh[jv * 64 + d] = c;
    }
}

// ---------------- projection: HP = h @ W' - c, fp16 in-place + s-dots ------
// grid (320, view); block 256 = 4 waves; wave per ROW PAIR (2-row ILP).
__global__ __launch_bounds__(256, 5)
void proj_kernel(__half* __restrict__ buf, const float* __restrict__ Wp_all,
                 const float* __restrict__ csh_all,
                 const float* __restrict__ a_s, const float* __restrict__ a_d,
                 float* __restrict__ sS, float* __restrict__ sD, int npin) {
    const int j = blockIdx.y;
    const int lane = threadIdx.x & 63, wave = threadIdx.x >> 6;
    const int R = 128 * npin;
    const int P = R >> 1;              // R is even
    __half* h = buf + (size_t)j * R * 64;
    const float* Wp = Wp_all + j * 4096;
    float Wreg[64];
    #pragma unroll
    for (int f = 0; f < 64; ++f) Wreg[f] = Wp[f * 64 + lane];
    const float cst = csh_all[j * 64 + lane];
    const float asv = a_s[lane], adv = a_d[lane];
    const int nw = gridDim.x * 4;
    for (int pr = blockIdx.x * 4 + wave; pr < P; pr += nw) {
        int r0 = pr * 2;
        float va = __half2float(h[(size_t)r0 * 64 + lane]);
        float vb = __half2float(h[(size_t)r0 * 64 + 64 + lane]);
        float o0 = 0.f, o1 = 0.f, q0 = 0.f, q1 = 0.f;
        #pragma unroll
        for (int f = 0; f < 64; f += 2) {
            o0 += rdlane(va, f)     * Wreg[f];
            q0 += rdlane(vb, f)     * Wreg[f];
            o1 += rdlane(va, f + 1) * Wreg[f + 1];
            q1 += rdlane(vb, f + 1) * Wreg[f + 1];
        }
        float oa = (o0 + o1) - cst, ob = (q0 + q1) - cst;
        h[(size_t)r0 * 64 + lane] = __float2half(oa);
        h[(size_t)r0 * 64 + 64 + lane] = __float2half(ob);
        float aa = oa * asv, da = oa * adv, ab = ob * asv, db = ob * adv;
        for (int off = 32; off > 0; off >>= 1) {
            aa += __shfl_down(aa, off, 64);
            da += __shfl_down(da, off, 64);
            ab += __shfl_down(ab, off, 64);
            db += __shfl_down(db, off, 64);
        }
        if (lane == 0) {
            sS[j * R + r0] = aa;     sD[j * R + r0] = da;
            sS[j * R + r0 + 1] = ab; sD[j * R + r0 + 1] = db;
        }
    }
}

// ---------------- aggregation (L>0): softmax + fp16 gather + pool + BN -----
// grid = split(2) x view(4) x graph(128) = 1024 blocks of 512 threads.
template<int NPIN, typename OutT>
__global__ __launch_bounds__(512, 8)
void agg_kernel(AggArgs A) {
    constexpr int NPOUT = (NPIN + 1) / 2;
    constexpr int HALF = (NPOUT + 1) / 2;

    extern __shared__ char smem[];
    float* sredF = (float*)smem;                       // 4096 B
    float* fp = (float*)(smem + 4096);
    float* sSrc = fp; fp += NPIN;
    float* sDst = fp; fp += NPIN;
    unsigned* ep32 = (unsigned*)fp;
    unsigned short* rp16 = (unsigned short*)(ep32 + A.nemax);

    const int split = blockIdx.x >> 9;
    const int jg = blockIdx.x & 511;
    const int j = jg >> 7;
    const int g = jg & 127;
    const int tid = threadIdx.x;
    const int wave = tid >> 6;
    const int lane = tid & 63;

    const int n0c = split * HALF;
    const int n1c = min(NPOUT, n0c + HALF);
    const int ch0 = 2 * n0c;
    const int ch1 = min(NPIN, 2 * n1c);

    const int* __restrict__ rowptr = A.rowptr[j];
    const int* __restrict__ colsrc = A.colsrc[j];
    const int ne = A.ne[j];
    const int sbase = (j * 128 + g) * NPIN;
    // per-lane gather base: hp row sl is at hpg + sl*64 (halves)
    const __half* __restrict__ hpg = A.hp[j] + (size_t)g * NPIN * 64 + lane;

    for (int k = tid; k <= NPIN; k += 512) rp16[k] = (unsigned short)rowptr[k];
    for (int k = tid; k < ne; k += 512) ep32[k] = (unsigned)colsrc[k];
    for (int r = tid; r < NPIN; r += 512) {
        sSrc[r] = A.sS[sbase + r];
        sDst[r] = A.sD[sbase + r];
    }
    __syncthreads();

    for (int r = ch0 + tid; r < ch1; r += 512) {
        int s0 = rp16[r], e0 = rp16[r + 1];
        float sd = sDst[r];
        float m = -1e30f, z = 0.f;
        for (int k = s0; k < e0; ++k) {
            float v = sSrc[ep32[k] & 0xFFFFu] + sd;
            v = (v >= 0.f) ? v : 0.2f * v;
            if (v > m) { z = z * __expf(m - v) + 1.f; m = v; }
            else z += __expf(v - m);
        }
        float invz = 1.f / z;
        for (int k = s0; k < e0; ++k) {
            unsigned sl = ep32[k] & 0xFFFFu;
            float v = sSrc[sl] + sd;
            v = (v >= 0.f) ? v : 0.2f * v;
            ep32[k] = packpw(__expf(v - m) * invz, sl);
        }
    }
    __syncthreads();

    const float b_l = A.bias[lane];
    OutT* outj = (OutT*)A.out[j];
    float bs = 0.f, bs2 = 0.f;

    for (int c = n0c + wave; c < n1c; c += 8) {
        float vmax = 0.f;
        #pragma unroll
        for (int ch = 0; ch < 2; ++ch) {
            int child = 2 * c + ch;
            if (child >= NPIN) break;
            int s0 = rp16[child], e0 = rp16[child + 1];
            float acc0 = 0.f, acc1 = 0.f;
            int k = s0;
            for (; k + 4 <= e0; k += 4) {
                unsigned ea = ep32[k], eb = ep32[k + 1], ec = ep32[k + 2], ed = ep32[k + 3];
                float ha = __half2float(hpg[(size_t)(ea & 0xFFFFu) << 6]);
                float hb = __half2float(hpg[(size_t)(eb & 0xFFFFu) << 6]);
                float hc = __half2float(hpg[(size_t)(ec & 0xFFFFu) << 6]);
                float hd = __half2float(hpg[(size_t)(ed & 0xFFFFu) << 6]);
                acc0 += unpackpw(ea) * ha + unpackpw(eb) * hb;
                acc1 += unpackpw(ec) * hc + unpackpw(ed) * hd;
            }
            for (; k < e0; ++k) {
                unsigned ea = ep32[k];
                acc0 += unpackpw(ea) * __half2float(hpg[(size_t)(ea & 0xFFFFu) << 6]);
            }
            float o = acc0 + acc1 + b_l;
            vmax = fmaxf(vmax, fmaxf(o, 0.f));
        }
        storeval(&outj[((size_t)g * NPOUT + c) * 64 + lane], vmax);
        bs += vmax;
        bs2 += vmax * vmax;
    }
    sredF[wave * 64 + lane] = bs;
    sredF[512 + wave * 64 + lane] = bs2;
    __syncthreads();
    if (wave == 0) {
        float t1 = 0.f, t2 = 0.f;
        #pragma unroll
        for (int w = 0; w < 8; ++w) {
            t1 += sredF[w * 64 + lane];
            t2 += sredF[512 + w * 64 + lane];
        }
        atomicAdd(A.dstats + j * 128 + lane, (double)t1);
        atomicAdd(A.dstats + j * 128 + 64 + lane, (double)t2);
    }
}

// ---------------- fused head reduce: Bm dots -> S (BmT Bm) + column means --
__global__ __launch_bounds__(256)
void head_reduce_kernel(const float* __restrict__ ALL, const float* __restrict__ musig,
                        const float* __restrict__ w_attn,
                        float* __restrict__ S, float* __restrict__ cm) {
    __shared__ float S_loc[16];
    __shared__ float cm_loc[256];
    const int t = threadIdx.x, wave = t >> 6, lane = t & 63;
    if (t < 16) S_loc[t] = 0.f;
    cm_loc[t] = 0.f;
    __syncthreads();
    const float wa = w_attn[lane];
    float cacc[4] = {0.f, 0.f, 0.f, 0.f};
    for (int m = blockIdx.x * 4 + wave; m < M_FINAL; m += gridDim.x * 4) {
        float b4[4];
        float csum = 0.f;
        #pragma unroll
        for (int v = 0; v < 4; ++v) {
            float val = (ALL[((size_t)v * M_FINAL + m) * 64 + lane] - musig[v * 128 + lane])
                        * musig[v * 128 + 64 + lane];
            csum += val;
            float p = val * wa;
            for (int off = 32; off > 0; off >>= 1) p += __shfl_down(p, off, 64);
            b4[v] = __shfl(p, 0, 64);
        }
        cacc[m & 3] += csum;
        if (lane < 16) atomicAdd(&S_loc[lane], b4[lane >> 2] * b4[lane & 3]);
    }
    #pragma unroll
    for (int q = 0; q < 4; ++q) atomicAdd(&cm_loc[q * 64 + lane], cacc[q]);
    __syncthreads();
    if (t < 16) atomicAdd(&S[t], S_loc[t]);
    atomicAdd(&cm[t], cm_loc[t]);
}

// wave-parallel: 64 lanes split the 256-column mean-dot; lane 0 does the
// tiny 4x4 softmax tail. (Was single-thread: 1024 serial loads = 66 us.)
__global__ void fuse_small_kernel(const float* __restrict__ S, const float* __restrict__ cm,
                                  const float* __restrict__ w_lin0, const float* __restrict__ b_lin0,
                                  float* __restrict__ cvec) {
    const int lane = threadIdx.x;      // 64
    float pa0 = 0.f, pa1 = 0.f, pa2 = 0.f, pa3 = 0.f;
    #pragma unroll
    for (int q = 0; q < 4; ++q) {
        int c = q * 64 + lane;
        float cmv = cm[c] / (float)M_FINAL;
        pa0 += cmv * w_lin0[c * 4 + 0];
        pa1 += cmv * w_lin0[c * 4 + 1];
        pa2 += cmv * w_lin0[c * 4 + 2];
        pa3 += cmv * w_lin0[c * 4 + 3];
    }
    for (int off = 32; off > 0; off >>= 1) {
        pa0 += __shfl_down(pa0, off, 64);
        pa1 += __shfl_down(pa1, off, 64);
        pa2 += __shfl_down(pa2, off, 64);
        pa3 += __shfl_down(pa3, off, 64);
    }
    if (lane != 0) return;
    float e4[4] = {pa0 + b_lin0[0], pa1 + b_lin0[1], pa2 + b_lin0[2], pa3 + b_lin0[3]};
    float cn[4];
    for (int v = 0; v < 4; ++v) cn[v] = sqrtf(S[v * 4 + v]);
    float A[16];
    for (int u = 0; u < 4; ++u) {
        float row[4]; float mx = -1e30f;
        for (int v = 0; v < 4; ++v) {
            float g = S[u * 4 + v] / (cn[u] * cn[v]);
            g = (g >= 0.f) ? g : 0.1f * g;       // leaky_relu 0.1
            row[v] = g; mx = fmaxf(mx, g);
        }
        float sum = 0.f;
        for (int v = 0; v < 4; ++v) { row[v] = expf(row[v] - mx); sum += row[v]; }
        for (int v = 0; v < 4; ++v) A[u * 4 + v] = row[v] / sum;
    }
    float mx = fmaxf(fmaxf(e4[0], e4[1]), fmaxf(e4[2], e4[3]));
    float sum = 0.f, w[4];
    for (int v = 0; v < 4; ++v) { w[v] = expf(e4[v] - mx); sum += w[v]; }
    for (int v = 0; v < 4; ++v) w[v] /= sum;
    for (int k = 0; k < 4; ++k) {
        float c = 0.f;
        for (int v = 0; v < 4; ++v) c += A[k * 4 + v] * w[v];
        cvec[k] = c;
    }
}

// ---------------- fused head output: combine + 3 matvecs (selu,selu,none) --
__global__ __launch_bounds__(256)
void head_out_kernel(const float* __restrict__ ALL, const float* __restrict__ musig,
                     const float* __restrict__ cvec,
                     const float* __restrict__ W0, const float* __restrict__ W1,
                     const float* __restrict__ W2, float* __restrict__ outp) {
    __shared__ float Wl[3][64 * 64];   // 48 KB
    const int t = threadIdx.x, wave = t >> 6, lane = t & 63;
    for (int k = t; k < 4096; k += 256) {
        Wl[0][k] = W0[k]; Wl[1][k] = W1[k]; Wl[2][k] = W2[k];
    }
    __syncthreads();
    const float c0 = cvec[0], c1 = cvec[1], c2 = cvec[2], c3 = cvec[3];
    const float scale = 1.0507009873554805f;
    const float alpha = 1.6732632423543772f;
    for (int m = blockIdx.x * 4 + wave; m < M_FINAL; m += gridDim.x * 4) {
        float r =
            c0 * ((ALL[((size_t)0 * M_FINAL + m) * 64 + lane] - musig[0 * 128 + lane]) * musig[0 * 128 + 64 + lane]) +
            c1 * ((ALL[((size_t)1 * M_FINAL + m) * 64 + lane] - musig[1 * 128 + lane]) * musig[1 * 128 + 64 + lane]) +
            c2 * ((ALL[((size_t)2 * M_FINAL + m) * 64 + lane] - musig[2 * 128 + lane]) * musig[2 * 128 + 64 + lane]) +
            c3 * ((ALL[((size_t)3 * M_FINAL + m) * 64 + lane] - musig[3 * 128 + lane]) * musig[3 * 128 + 64 + lane]);
        #pragma unroll
        for (int s = 0; s < 3; ++s) {
            float o0 = 0.f, o1 = 0.f, o2 = 0.f, o3 = 0.f;
            #pragma unroll
            for (int f = 0; f < 64; f += 4) {
                o0 += rdlane(r, f)     * Wl[s][f * 64 + lane];
                o1 += rdlane(r, f + 1) * Wl[s][(f + 1) * 64 + lane];
                o2 += rdlane(r, f + 2) * Wl[s][(f + 2) * 64 + lane];
                o3 += rdlane(r, f + 3) * Wl[s][(f + 3) * 64 + lane];
            }
            float o = (o0 + o1) + (o2 + o3);
            if (s < 2) o = (o > 0.f) ? scale * o : scale * alpha * expm1f(o);
            r = o;
        }
        outp[(size_t)m * 64 + lane] = r;
    }
}

extern "C" void kernel_launch(void* const* d_in, const int* in_sizes, int n_in,
                              void* d_out, int out_size, void* d_ws, size_t ws_size,
                              hipStream_t stream) {
    const float* x = (const float*)d_in[15];

    float* ws = (float*)d_ws;
    double* dstats_all = (double*)ws;                 // 1536 doubles -> [0, 3072)
    float*  cm         = ws + 3072;                   // 256
    float*  S          = ws + 3328;                   // 16
    float*  cvec       = ws + 3344;                   // 4
    float*  musig_all  = ws + 3584;                   // 3*512 -> [3584, 5120)
    float*  Wp_all     = ws + 5120;                   // 2*4*4096 -> [5120, 37888)
    float*  csh_all    = ws + 37888;                  // 2*4*64 -> [37888, 38400)
    int*    rowptr_all = (int*)(ws + 38400);          // 12*768 -> [38400, 47616)
    int*    colsrc_all = (int*)(ws + 47616);          // 12*8192 -> [47616, 145920)
    float*  sS1        = ws + 145920;                 // 180736
    float*  sD1        = sS1 + 180736;
    float*  sS2        = sD1 + 180736;                // 90624
    float*  sD2        = sS2 + 90624;
    __half* A16        = (__half*)(sD2 + 90624);      // 11,567,104 halves (5,783,552 slots)
    __half* B16        = (__half*)((float*)A16 + 5783552);  // 5,799,936 halves (2,899,968 slots)
    float*  ALLb       = (float*)B16 + 2899968;       // 2,916,352 floats
    const size_t as0h = (size_t)128 * 353 * 64;       // halves per view (layer0/1)
    const size_t as1h = (size_t)128 * 177 * 64;

    // edge sets (graph-0 structure shared by all 128 graphs)
    EdgeSets ES;
    int nemax[3] = {0, 0, 0};
    for (int s = 0; s < 12; ++s) {
        const int* e = (const int*)d_in[s];
        int E = in_sizes[s] / 2;
        ES.src[s] = e;
        ES.dst[s] = e + E;
        ES.ne[s] = E / 128;
        int lay = s % 3;
        if (ES.ne[s] > nemax[lay]) nemax[lay] = ES.ne[s];
    }

    // dynamic LDS sizes (mirror in-kernel layouts)
    int SM0 = 4096 + (706 * 6 + 356 * 4 + 8) * 4 + 708 * 2;
    SM0 = (SM0 + 15) & ~15;
    int SMa1 = 4096 + (2 * 353) * 4 + nemax[1] * 4 + 355 * 2;
    SMa1 = (SMa1 + 15) & ~15;
    int SMa2 = 4096 + (2 * 177) * 4 + nemax[2] * 4 + 179 * 2;
    SMa2 = (SMa2 + 15) & ~15;
    (void)hipFuncSetAttribute(reinterpret_cast<const void*>(&layer0_kernel),
                              hipFuncAttributeMaxDynamicSharedMemorySize, SM0);
    (void)hipFuncSetAttribute(reinterpret_cast<const void*>(&agg_kernel<353, __half>),
                              hipFuncAttributeMaxDynamicSharedMemorySize, SMa1);
    (void)hipFuncSetAttribute(reinterpret_cast<const void*>(&agg_kernel<177, float>),
                              hipFuncAttributeMaxDynamicSharedMemorySize, SMa2);

    zero_kernel<<<cdiv(3584, 256), 256, 0, stream>>>(ws, 3584);
    csr_build_kernel<<<12, 768, 0, stream>>>(ES, rowptr_all, colsrc_all);

    // ---- layer 0 -> fp16 raw0 in A16 ----
    {
        L0Args A;
        A.x = x;
        for (int j = 0; j < 4; ++j) {
            int s = j * 3;
            A.rowptr[j] = rowptr_all + s * 768;
            A.colsrc[j] = colsrc_all + s * 8192;
            A.ne[j] = ES.ne[s];
            A.out[j] = A16 + j * as0h;
        }
        A.nemax = nemax[0];
        A.dstats = dstats_all;
        A.W = (const float*)d_in[16];
        A.as = (const float*)d_in[17];
        A.ad = (const float*)d_in[18];
        A.bias = (const float*)d_in[19];
        layer0_kernel<<<1024, 512, SM0, stream>>>(A);
    }
    bn_finalize_kernel<<<4, 64, 0, stream>>>(dstats_all, musig_all, 128 * 353,
                                             (const float*)d_in[20], Wp_all, csh_all);

    // ---- layer 1: in-place fp16 proj on A16, then aggregate -> B16 ----
    proj_kernel<<<dim3(320, 4), 256, 0, stream>>>(A16, Wp_all, csh_all,
                                                  (const float*)d_in[21], (const float*)d_in[22],
                                                  sS1, sD1, 353);
    {
        AggArgs A;
        for (int j = 0; j < 4; ++j) {
            int s = j * 3 + 1;
            A.rowptr[j] = rowptr_all + s * 768;
            A.colsrc[j] = colsrc_all + s * 8192;
            A.ne[j] = ES.ne[s];
            A.hp[j] = A16 + j * as0h;
            A.out[j] = B16 + j * as1h;
        }
        A.nemax = nemax[1];
        A.sS = sS1; A.sD = sD1;
        A.bias = (const float*)d_in[23];
        A.dstats = dstats_all + 512;
        agg_kernel<353, __half><<<1024, 512, SMa1, stream>>>(A);
    }
    bn_finalize_kernel<<<4, 64, 0, stream>>>(dstats_all + 512, musig_all + 512, 128 * 177,
                                             (const float*)d_in[24], Wp_all + 16384, csh_all + 256);

    // ---- layer 2: in-place fp16 proj on B16, then aggregate -> ALLb fp32 --
    proj_kernel<<<dim3(320, 4), 256, 0, stream>>>(B16, Wp_all + 16384, csh_all + 256,
                                                  (const float*)d_in[25], (const float*)d_in[26],
                                                  sS2, sD2, 177);
    {
        AggArgs A;
        for (int j = 0; j < 4; ++j) {
            int s = j * 3 + 2;
            A.rowptr[j] = rowptr_all + s * 768;
            A.colsrc[j] = colsrc_all + s * 8192;
            A.ne[j] = ES.ne[s];
            A.hp[j] = B16 + j * as1h;
            A.out[j] = ALLb + (size_t)j * M_FINAL * 64;
        }
        A.nemax = nemax[2];
        A.sS = sS2; A.sD = sD2;
        A.bias = (const float*)d_in[27];
        A.dstats = dstats_all + 1024;
        agg_kernel<177, float><<<1024, 512, SMa2, stream>>>(A);
    }
    bn_finalize_kernel<<<4, 64, 0, stream>>>(dstats_all + 1024, musig_all + 1024, 128 * 89,
                                             nullptr, nullptr, nullptr);

    // ---- fusion head ----
    const float* musig2 = musig_all + 1024;
    head_reduce_kernel<<<256, 256, 0, stream>>>(ALLb, musig2, (const float*)d_in[28], S, cm);
    fuse_small_kernel<<<1, 64, 0, stream>>>(S, cm, (const float*)d_in[29], (const float*)d_in[30], cvec);
    head_out_kernel<<<256, 256, 0, stream>>>(ALLb, musig2, cvec,
                                             (const float*)d_in[31], (const float*)d_in[32],
                                             (const float*)d_in[33], (float*)d_out);
}

// Round 12
// 355.693 us; speedup vs baseline: 4.6375x; 1.1707x over previous
//
#include <hip/hip_runtime.h>
#include <hip/hip_fp16.h>
#include <math.h>

#define DIM 64
#define M_FINAL (128*89)   // 11392 final rows

static inline int cdiv(int a, int b) { return (a + b - 1) / b; }

typedef _Float16 v8h __attribute__((ext_vector_type(8)));
typedef float v4f __attribute__((ext_vector_type(4)));

__device__ inline float rdlane(float v, int l) {
    return __int_as_float(__builtin_amdgcn_readlane(__float_as_int(v), l));
}
__device__ inline unsigned packpw(float p, unsigned src) {
    return ((unsigned)__half_as_ushort(__float2half(p)) << 16) | src;
}
__device__ inline float unpackpw(unsigned ep) {
    return __half2float(__ushort_as_half((unsigned short)(ep >> 16)));
}
__device__ inline void storeval(float* p, float v) { *p = v; }
__device__ inline void storeval(__half* p, float v) { *p = __float2half(v); }

struct EdgeSets {
    const int* src[12];
    const int* dst[12];
    int ne[12];
};

struct L0Args {
    const float* x;
    __half* out[4];
    const int* rowptr[4];
    const int* colsrc[4];
    int ne[4];
    int nemax;
    double* dstats;
    const float* W;
    const float* as;
    const float* ad;
    const float* bias;
};

struct AggArgs {
    const __half* hp[4];      // projected rows (out-space, fp16)
    void* out[4];
    const int* rowptr[4];
    const int* colsrc[4];
    int ne[4];
    int nemax;
    const float* sS;          // [j][g][NPIN]
    const float* sD;
    const float* bias;
    double* dstats;
};

// ---------------- misc ----------------

__global__ void zero_kernel(float* __restrict__ p, int n) {
    int i = blockIdx.x * blockDim.x + threadIdx.x;
    if (i < n) p[i] = 0.f;
}

// ---------------- fused CSR build: one block per edge set ------------------
__global__ __launch_bounds__(768)
void csr_build_kernel(EdgeSets ES, int* __restrict__ rowptr_all,
                      int* __restrict__ colsrc_all) {
    __shared__ int cnt[768];
    __shared__ int cur[768];
    const int s = blockIdx.x;
    const int lay = s % 3;
    const int n = (lay == 0) ? 706 : (lay == 1) ? 353 : 177;
    const int ne = ES.ne[s];
    const int* __restrict__ src = ES.src[s];
    const int* __restrict__ dst = ES.dst[s];
    int* __restrict__ rowptr = rowptr_all + s * 768;
    int* __restrict__ colsrc = colsrc_all + s * 8192;
    const int t = threadIdx.x;

    cnt[t] = 0;
    __syncthreads();
    for (int k = t; k < ne; k += 768) atomicAdd(&cnt[dst[k]], 1);
    __syncthreads();
    int v = cnt[t];
    for (int off = 1; off < 768; off <<= 1) {
        int add = (t >= off) ? cnt[t - off] : 0;
        __syncthreads();
        cnt[t] += add;
        __syncthreads();
    }
    int excl = cnt[t] - v;
    if (t < n) { rowptr[t] = excl; cur[t] = excl; }
    if (t == n - 1) rowptr[n] = cnt[t];
    __syncthreads();
    for (int k = t; k < ne; k += 768) {
        int pos = atomicAdd(&cur[dst[k]], 1);
        colsrc[pos] = src[k];
    }
}

// ---------------- layer 0 mega kernel (in_dim=3, thread-par agg) -----------
// grid = split(2) x view(4) x graph(128) = 1024 blocks of 512 threads.
__global__ __launch_bounds__(512, 8)
void layer0_kernel(L0Args A) {
    constexpr int NPIN = 706, NPOUT = 353, HALF = 177;

    extern __shared__ char smem[];
    float* sredF = (float*)smem;                       // [2][8][64] = 4096 B
    float* fp = (float*)(smem + 4096);
    float* sSrc = fp; fp += NPIN;
    float* sDst = fp; fp += NPIN;
    float* hL4  = fp; fp += NPIN * 4;
    float* agg4 = fp; fp += 356 * 4;
    float* waL0 = fp; fp += 8;
    unsigned short* rp16 = (unsigned short*)fp;        // 708

    const int split = blockIdx.x >> 9;
    const int jg = blockIdx.x & 511;
    const int j = jg >> 7;
    const int g = jg & 127;
    const int tid = threadIdx.x;
    const int wave = tid >> 6;
    const int lane = tid & 63;

    const int n0c = split * HALF;
    const int n1c = min(NPOUT, n0c + HALF);
    const int ch0 = 2 * n0c;
    const int ch1 = 2 * n1c;          // NPIN even -> always valid children

    const int* __restrict__ rowptr = A.rowptr[j];
    const int* __restrict__ colsrc = A.colsrc[j];
    const float* __restrict__ W = A.W;

    for (int k = tid; k <= NPIN; k += 512) rp16[k] = (unsigned short)rowptr[k];
    if (tid < 6) {                    // wa_{src,dst}[f] = sum_d W[f][d]*a[d]
        int f = (tid < 3) ? tid : tid - 3;
        const float* av = (tid < 3) ? A.as : A.ad;
        float acc = 0.f;
        for (int d = 0; d < 64; ++d) acc += W[f * 64 + d] * av[d];
        waL0[tid] = acc;
    }
    __syncthreads();

    // h staging + s-dots
    {
        const float* hb = A.x + (size_t)g * (NPIN * 3);
        for (int r = tid; r < NPIN; r += 512) {
            float h0 = hb[r * 3], h1 = hb[r * 3 + 1], h2 = hb[r * 3 + 2];
            hL4[r * 4] = h0; hL4[r * 4 + 1] = h1; hL4[r * 4 + 2] = h2; hL4[r * 4 + 3] = 0.f;
            sSrc[r] = h0 * waL0[0] + h1 * waL0[1] + h2 * waL0[2];
            sDst[r] = h0 * waL0[3] + h1 * waL0[4] + h2 * waL0[5];
        }
    }
    __syncthreads();

    // thread-par softmax + aggregation: one child per thread
    const int child = ch0 + tid;
    if (child < ch1) {
        int s0 = rp16[child], e0 = rp16[child + 1];
        float sd = sDst[child];
        float m = -1e30f;
        for (int k = s0; k < e0; ++k) {
            float v = sSrc[colsrc[k]] + sd;
            v = (v >= 0.f) ? v : 0.2f * v;
            m = fmaxf(m, v);
        }
        float z = 0.f, a0 = 0.f, a1 = 0.f, a2 = 0.f;
        for (int k = s0; k < e0; ++k) {
            int sl = colsrc[k];
            float v = sSrc[sl] + sd;
            v = (v >= 0.f) ? v : 0.2f * v;
            float p = __expf(v - m);
            z += p;
            a0 += p * hL4[sl * 4];
            a1 += p * hL4[sl * 4 + 1];
            a2 += p * hL4[sl * 4 + 2];
        }
        float iz = 1.f / z;
        agg4[tid * 4]     = a0 * iz;
        agg4[tid * 4 + 1] = a1 * iz;
        agg4[tid * 4 + 2] = a2 * iz;
        agg4[tid * 4 + 3] = 0.f;
    }
    __syncthreads();

    // wave-par matvec + relu + pool + store + BN stats
    const float w0 = W[lane], w1 = W[64 + lane], w2 = W[128 + lane];
    const float b_l = A.bias[lane];
    __half* outj = A.out[j];
    const float4* agg4v = (const float4*)agg4;
    float bs = 0.f, bs2 = 0.f;

    for (int c = n0c + wave; c < n1c; c += 8) {
        int lc = 2 * (c - n0c);
        float4 va = agg4v[lc];
        float4 vb = agg4v[lc + 1];
        float oa = va.x * w0 + va.y * w1 + va.z * w2 + b_l;
        float ob = vb.x * w0 + vb.y * w1 + vb.z * w2 + b_l;
        float vmax = fmaxf(fmaxf(oa, ob), 0.f);
        outj[((size_t)g * NPOUT + c) * 64 + lane] = __float2half(vmax);
        bs += vmax;
        bs2 += vmax * vmax;
    }
    sredF[wave * 64 + lane] = bs;
    sredF[512 + wave * 64 + lane] = bs2;
    __syncthreads();
    if (wave == 0) {
        float t1 = 0.f, t2 = 0.f;
        #pragma unroll
        for (int w = 0; w < 8; ++w) {
            t1 += sredF[w * 64 + lane];
            t2 += sredF[512 + w * 64 + lane];
        }
        atomicAdd(A.dstats + j * 128 + lane, (double)t1);
        atomicAdd(A.dstats + j * 128 + 64 + lane, (double)t2);
    }
}

// BN finalize; optionally fold stats into next layer's weight:
// Wp[f][d] = rs[f]*Wn[f][d]; csh[d] = sum_f mu[f]*rs[f]*Wn[f][d]
__global__ void bn_finalize_kernel(const double* __restrict__ dstats,
                                   float* __restrict__ musig, int n_rows,
                                   const float* __restrict__ Wn,
                                   float* __restrict__ Wp, float* __restrict__ csh) {
    __shared__ float mur[128];
    int jv = blockIdx.x;           // view
    int d = threadIdx.x;           // 64
    double mu = dstats[jv * 128 + d] / n_rows;
    double var = dstats[jv * 128 + 64 + d] / n_rows - mu * mu;
    float rs = rsqrtf((float)var + 1e-5f);
    musig[jv * 128 + d] = (float)mu;
    musig[jv * 128 + 64 + d] = rs;
    if (Wn != nullptr) {
        mur[d] = (float)mu; mur[64 + d] = rs;
        __syncthreads();
        float c = 0.f;
        for (int f = 0; f < 64; ++f) {
            float wp = mur[64 + f] * Wn[f * 64 + d];
            Wp[jv * 4096 + f * 64 + d] = wp;
            c += mur[f] * wp;
        }
        csh[jv * 64 + d] = c;
    }
}

// ---------------- projection via MFMA: HP = h @ W' - c, fp16 in-place ------
// grid (256, view); block 256 = 4 waves; wave per 16-row tile.
// A-frag: A[m=lane&15][k=quad*8+j] -> one half8 global load per k-step.
// B-frags (8) held in registers from LDS-transposed W'.
// C/D: col=lane&15, row=quad*4+reg.
__global__ __launch_bounds__(256, 4)
void proj_kernel(__half* __restrict__ buf, const float* __restrict__ Wp_all,
                 const float* __restrict__ csh_all,
                 const float* __restrict__ a_s, const float* __restrict__ a_d,
                 float* __restrict__ sS, float* __restrict__ sD, int npin) {
    __shared__ _Float16 Wt[64 * 64];   // Wt[d][f] = W'[f][d], fp16 (8 KB)
    const int j = blockIdx.y;
    const int tid = threadIdx.x;
    const int lane = tid & 63, wave = tid >> 6;
    const int lc = lane & 15, quad = lane >> 4;
    const int R = 128 * npin;          // multiple of 16
    __half* h = buf + (size_t)j * R * 64;
    const float* Wp = Wp_all + j * 4096;

    for (int k = tid; k < 4096; k += 256) {
        int f = k >> 6, d = k & 63;
        Wt[d * 64 + f] = (_Float16)Wp[k];
    }
    __syncthreads();

    // B fragments: b[t][s] = B[k=s*32+quad*8+j][n=t*16+lc]
    v8h bfrag[4][2];
    #pragma unroll
    for (int t = 0; t < 4; ++t)
        #pragma unroll
        for (int s = 0; s < 2; ++s)
            bfrag[t][s] = *(const v8h*)&Wt[(t * 16 + lc) * 64 + s * 32 + quad * 8];

    float cshv[4], asv[4], adv[4];
    #pragma unroll
    for (int t = 0; t < 4; ++t) {
        cshv[t] = csh_all[j * 64 + t * 16 + lc];
        asv[t] = a_s[t * 16 + lc];
        adv[t] = a_d[t * 16 + lc];
    }

    const int ntiles = R >> 4;
    for (int tile = blockIdx.x * 4 + wave; tile < ntiles; tile += gridDim.x * 4) {
        const int rowbase = tile * 16;
        const __half* arow = h + ((size_t)(rowbase + lc)) * 64 + quad * 8;
        v8h a0 = *(const v8h*)arow;            // k-step 0 (k=0..31)
        v8h a1 = *(const v8h*)(arow + 32);     // k-step 1 (k=32..63)
        v4f acc[4];
        #pragma unroll
        for (int t = 0; t < 4; ++t) {
            acc[t] = (v4f){0.f, 0.f, 0.f, 0.f};
            acc[t] = __builtin_amdgcn_mfma_f32_16x16x32_f16(a0, bfrag[t][0], acc[t], 0, 0, 0);
            acc[t] = __builtin_amdgcn_mfma_f32_16x16x32_f16(a1, bfrag[t][1], acc[t], 0, 0, 0);
        }
        float pS[4] = {0.f, 0.f, 0.f, 0.f};
        float pD[4] = {0.f, 0.f, 0.f, 0.f};
        #pragma unroll
        for (int t = 0; t < 4; ++t) {
            #pragma unroll
            for (int r = 0; r < 4; ++r) {
                float o = acc[t][r] - cshv[t];
                h[((size_t)(rowbase + quad * 4 + r)) * 64 + t * 16 + lc] = __float2half(o);
                pS[r] += o * asv[t];
                pD[r] += o * adv[t];
            }
        }
        #pragma unroll
        for (int m = 1; m < 16; m <<= 1) {
            #pragma unroll
            for (int r = 0; r < 4; ++r) {
                pS[r] += __shfl_xor(pS[r], m, 64);
                pD[r] += __shfl_xor(pD[r], m, 64);
            }
        }
        if (lc == 0) {
            #pragma unroll
            for (int r = 0; r < 4; ++r) {
                sS[j * R + rowbase + quad * 4 + r] = pS[r];
                sD[j * R + rowbase + quad * 4 + r] = pD[r];
            }
        }
    }
}

// ---------------- aggregation (L>0): softmax + fp16 gather + pool + BN -----
// grid = split(2) x view(4) x graph(128) = 1024 blocks of 512 threads.
template<int NPIN, typename OutT>
__global__ __launch_bounds__(512, 8)
void agg_kernel(AggArgs A) {
    constexpr int NPOUT = (NPIN + 1) / 2;
    constexpr int HALF = (NPOUT + 1) / 2;

    extern __shared__ char smem[];
    float* sredF = (float*)smem;                       // 4096 B
    float* fp = (float*)(smem + 4096);
    float* sSrc = fp; fp += NPIN;
    float* sDst = fp; fp += NPIN;
    unsigned* ep32 = (unsigned*)fp;
    unsigned short* rp16 = (unsigned short*)(ep32 + A.nemax);

    const int split = blockIdx.x >> 9;
    const int jg = blockIdx.x & 511;
    const int j = jg >> 7;
    const int g = jg & 127;
    const int tid = threadIdx.x;
    const int wave = tid >> 6;
    const int lane = tid & 63;

    const int n0c = split * HALF;
    const int n1c = min(NPOUT, n0c + HALF);
    const int ch0 = 2 * n0c;
    const int ch1 = min(NPIN, 2 * n1c);

    const int* __restrict__ rowptr = A.rowptr[j];
    const int* __restrict__ colsrc = A.colsrc[j];
    const int ne = A.ne[j];
    const int sbase = (j * 128 + g) * NPIN;
    // per-lane gather base: hp row sl is at hpg + sl*64 (halves)
    const __half* __restrict__ hpg = A.hp[j] + (size_t)g * NPIN * 64 + lane;

    for (int k = tid; k <= NPIN; k += 512) rp16[k] = (unsigned short)rowptr[k];
    for (int k = tid; k < ne; k += 512) ep32[k] = (unsigned)colsrc[k];
    for (int r = tid; r < NPIN; r += 512) {
        sSrc[r] = A.sS[sbase + r];
        sDst[r] = A.sD[sbase + r];
    }
    __syncthreads();

    for (int r = ch0 + tid; r < ch1; r += 512) {
        int s0 = rp16[r], e0 = rp16[r + 1];
        float sd = sDst[r];
        float m = -1e30f, z = 0.f;
        for (int k = s0; k < e0; ++k) {
            float v = sSrc[ep32[k] & 0xFFFFu] + sd;
            v = (v >= 0.f) ? v : 0.2f * v;
            if (v > m) { z = z * __expf(m - v) + 1.f; m = v; }
            else z += __expf(v - m);
        }
        float invz = 1.f / z;
        for (int k = s0; k < e0; ++k) {
            unsigned sl = ep32[k] & 0xFFFFu;
            float v = sSrc[sl] + sd;
            v = (v >= 0.f) ? v : 0.2f * v;
            ep32[k] = packpw(__expf(v - m) * invz, sl);
        }
    }
    __syncthreads();

    const float b_l = A.bias[lane];
    OutT* outj = (OutT*)A.out[j];
    float bs = 0.f, bs2 = 0.f;

    for (int c = n0c + wave; c < n1c; c += 8) {
        float vmax = 0.f;
        #pragma unroll
        for (int ch = 0; ch < 2; ++ch) {
            int child = 2 * c + ch;
            if (child >= NPIN) break;
            int s0 = rp16[child], e0 = rp16[child + 1];
            float acc0 = 0.f, acc1 = 0.f;
            int k = s0;
            for (; k + 4 <= e0; k += 4) {
                unsigned ea = ep32[k], eb = ep32[k + 1], ec = ep32[k + 2], ed = ep32[k + 3];
                float ha = __half2float(hpg[(size_t)(ea & 0xFFFFu) << 6]);
                float hb = __half2float(hpg[(size_t)(eb & 0xFFFFu) << 6]);
                float hc = __half2float(hpg[(size_t)(ec & 0xFFFFu) << 6]);
                float hd = __half2float(hpg[(size_t)(ed & 0xFFFFu) << 6]);
                acc0 += unpackpw(ea) * ha + unpackpw(eb) * hb;
                acc1 += unpackpw(ec) * hc + unpackpw(ed) * hd;
            }
            for (; k < e0; ++k) {
                unsigned ea = ep32[k];
                acc0 += unpackpw(ea) * __half2float(hpg[(size_t)(ea & 0xFFFFu) << 6]);
            }
            float o = acc0 + acc1 + b_l;
            vmax = fmaxf(vmax, fmaxf(o, 0.f));
        }
        storeval(&outj[((size_t)g * NPOUT + c) * 64 + lane], vmax);
        bs += vmax;
        bs2 += vmax * vmax;
    }
    sredF[wave * 64 + lane] = bs;
    sredF[512 + wave * 64 + lane] = bs2;
    __syncthreads();
    if (wave == 0) {
        float t1 = 0.f, t2 = 0.f;
        #pragma unroll
        for (int w = 0; w < 8; ++w) {
            t1 += sredF[w * 64 + lane];
            t2 += sredF[512 + w * 64 + lane];
        }
        atomicAdd(A.dstats + j * 128 + lane, (double)t1);
        atomicAdd(A.dstats + j * 128 + 64 + lane, (double)t2);
    }
}

// ---------------- fused head reduce: Bm dots -> S (BmT Bm) + column means --
__global__ __launch_bounds__(256)
void head_reduce_kernel(const float* __restrict__ ALL, const float* __restrict__ musig,
                        const float* __restrict__ w_attn,
                        float* __restrict__ S, float* __restrict__ cm) {
    __shared__ float S_loc[16];
    __shared__ float cm_loc[256];
    const int t = threadIdx.x, wave = t >> 6, lane = t & 63;
    if (t < 16) S_loc[t] = 0.f;
    cm_loc[t] = 0.f;
    __syncthreads();
    const float wa = w_attn[lane];
    float cacc[4] = {0.f, 0.f, 0.f, 0.f};
    for (int m = blockIdx.x * 4 + wave; m < M_FINAL; m += gridDim.x * 4) {
        float b4[4];
        float csum = 0.f;
        #pragma unroll
        for (int v = 0; v < 4; ++v) {
            float val = (ALL[((size_t)v * M_FINAL + m) * 64 + lane] - musig[v * 128 + lane])
                        * musig[v * 128 + 64 + lane];
            csum += val;
            float p = val * wa;
            for (int off = 32; off > 0; off >>= 1) p += __shfl_down(p, off, 64);
            b4[v] = __shfl(p, 0, 64);
        }
        cacc[m & 3] += csum;
        if (lane < 16) atomicAdd(&S_loc[lane], b4[lane >> 2] * b4[lane & 3]);
    }
    #pragma unroll
    for (int q = 0; q < 4; ++q) atomicAdd(&cm_loc[q * 64 + lane], cacc[q]);
    __syncthreads();
    if (t < 16) atomicAdd(&S[t], S_loc[t]);
    atomicAdd(&cm[t], cm_loc[t]);
}

// wave-parallel: 64 lanes split the 256-column mean-dot; lane 0 does the
// tiny 4x4 softmax tail.
__global__ void fuse_small_kernel(const float* __restrict__ S, const float* __restrict__ cm,
                                  const float* __restrict__ w_lin0, const float* __restrict__ b_lin0,
                                  float* __restrict__ cvec) {
    const int lane = threadIdx.x;      // 64
    float pa0 = 0.f, pa1 = 0.f, pa2 = 0.f, pa3 = 0.f;
    #pragma unroll
    for (int q = 0; q < 4; ++q) {
        int c = q * 64 + lane;
        float cmv = cm[c] / (float)M_FINAL;
        pa0 += cmv * w_lin0[c * 4 + 0];
        pa1 += cmv * w_lin0[c * 4 + 1];
        pa2 += cmv * w_lin0[c * 4 + 2];
        pa3 += cmv * w_lin0[c * 4 + 3];
    }
    for (int off = 32; off > 0; off >>= 1) {
        pa0 += __shfl_down(pa0, off, 64);
        pa1 += __shfl_down(pa1, off, 64);
        pa2 += __shfl_down(pa2, off, 64);
        pa3 += __shfl_down(pa3, off, 64);
    }
    if (lane != 0) return;
    float e4[4] = {pa0 + b_lin0[0], pa1 + b_lin0[1], pa2 + b_lin0[2], pa3 + b_lin0[3]};
    float cn[4];
    for (int v = 0; v < 4; ++v) cn[v] = sqrtf(S[v * 4 + v]);
    float A[16];
    for (int u = 0; u < 4; ++u) {
        float row[4]; float mx = -1e30f;
        for (int v = 0; v < 4; ++v) {
            float g = S[u * 4 + v] / (cn[u] * cn[v]);
            g = (g >= 0.f) ? g : 0.1f * g;       // leaky_relu 0.1
            row[v] = g; mx = fmaxf(mx, g);
        }
        float sum = 0.f;
        for (int v = 0; v < 4; ++v) { row[v] = expf(row[v] - mx); sum += row[v]; }
        for (int v = 0; v < 4; ++v) A[u * 4 + v] = row[v] / sum;
    }
    float mx = fmaxf(fmaxf(e4[0], e4[1]), fmaxf(e4[2], e4[3]));
    float sum = 0.f, w[4];
    for (int v = 0; v < 4; ++v) { w[v] = expf(e4[v] - mx); sum += w[v]; }
    for (int v = 0; v < 4; ++v) w[v] /= sum;
    for (int k = 0; k < 4; ++k) {
        float c = 0.f;
        for (int v = 0; v < 4; ++v) c += A[k * 4 + v] * w[v];
        cvec[k] = c;
    }
}

// ---------------- fused head output: combine + 3 matvecs (selu,selu,none) --
__global__ __launch_bounds__(256)
void head_out_kernel(const float* __restrict__ ALL, const float* __restrict__ musig,
                     const float* __restrict__ cvec,
                     const float* __restrict__ W0, const float* __restrict__ W1,
                     const float* __restrict__ W2, float* __restrict__ outp) {
    __shared__ float Wl[3][64 * 64];   // 48 KB
    const int t = threadIdx.x, wave = t >> 6, lane = t & 63;
    for (int k = t; k < 4096; k += 256) {
        Wl[0][k] = W0[k]; Wl[1][k] = W1[k]; Wl[2][k] = W2[k];
    }
    __syncthreads();
    const float c0 = cvec[0], c1 = cvec[1], c2 = cvec[2], c3 = cvec[3];
    const float scale = 1.0507009873554805f;
    const float alpha = 1.6732632423543772f;
    for (int m = blockIdx.x * 4 + wave; m < M_FINAL; m += gridDim.x * 4) {
        float r =
            c0 * ((ALL[((size_t)0 * M_FINAL + m) * 64 + lane] - musig[0 * 128 + lane]) * musig[0 * 128 + 64 + lane]) +
            c1 * ((ALL[((size_t)1 * M_FINAL + m) * 64 + lane] - musig[1 * 128 + lane]) * musig[1 * 128 + 64 + lane]) +
            c2 * ((ALL[((size_t)2 * M_FINAL + m) * 64 + lane] - musig[2 * 128 + lane]) * musig[2 * 128 + 64 + lane]) +
            c3 * ((ALL[((size_t)3 * M_FINAL + m) * 64 + lane] - musig[3 * 128 + lane]) * musig[3 * 128 + 64 + lane]);
        #pragma unroll
        for (int s = 0; s < 3; ++s) {
            float o0 = 0.f, o1 = 0.f, o2 = 0.f, o3 = 0.f;
            #pragma unroll
            for (int f = 0; f < 64; f += 4) {
                o0 += rdlane(r, f)     * Wl[s][f * 64 + lane];
                o1 += rdlane(r, f + 1) * Wl[s][(f + 1) * 64 + lane];
                o2 += rdlane(r, f + 2) * Wl[s][(f + 2) * 64 + lane];
                o3 += rdlane(r, f + 3) * Wl[s][(f + 3) * 64 + lane];
            }
            float o = (o0 + o1) + (o2 + o3);
            if (s < 2) o = (o > 0.f) ? scale * o : scale * alpha * expm1f(o);
            r = o;
        }
        outp[(size_t)m * 64 + lane] = r;
    }
}

extern "C" void kernel_launch(void* const* d_in, const int* in_sizes, int n_in,
                              void* d_out, int out_size, void* d_ws, size_t ws_size,
                              hipStream_t stream) {
    const float* x = (const float*)d_in[15];

    float* ws = (float*)d_ws;
    double* dstats_all = (double*)ws;                 // 1536 doubles -> [0, 3072)
    float*  cm         = ws + 3072;                   // 256
    float*  S          = ws + 3328;                   // 16
    float*  cvec       = ws + 3344;                   // 4
    float*  musig_all  = ws + 3584;                   // 3*512 -> [3584, 5120)
    float*  Wp_all     = ws + 5120;                   // 2*4*4096 -> [5120, 37888)
    float*  csh_all    = ws + 37888;                  // 2*4*64 -> [37888, 38400)
    int*    rowptr_all = (int*)(ws + 38400);          // 12*768 -> [38400, 47616)
    int*    colsrc_all = (int*)(ws + 47616);          // 12*8192 -> [47616, 145920)
    float*  sS1        = ws + 145920;                 // 180736
    float*  sD1        = sS1 + 180736;
    float*  sS2        = sD1 + 180736;                // 90624
    float*  sD2        = sS2 + 90624;
    __half* A16        = (__half*)(sD2 + 90624);      // 11,567,104 halves (5,783,552 slots)
    __half* B16        = (__half*)((float*)A16 + 5783552);  // 5,799,936 halves (2,899,968 slots)
    float*  ALLb       = (float*)B16 + 2899968;       // 2,916,352 floats
    const size_t as0h = (size_t)128 * 353 * 64;       // halves per view (layer0/1)
    const size_t as1h = (size_t)128 * 177 * 64;

    // edge sets (graph-0 structure shared by all 128 graphs)
    EdgeSets ES;
    int nemax[3] = {0, 0, 0};
    for (int s = 0; s < 12; ++s) {
        const int* e = (const int*)d_in[s];
        int E = in_sizes[s] / 2;
        ES.src[s] = e;
        ES.dst[s] = e + E;
        ES.ne[s] = E / 128;
        int lay = s % 3;
        if (ES.ne[s] > nemax[lay]) nemax[lay] = ES.ne[s];
    }

    // dynamic LDS sizes (mirror in-kernel layouts)
    int SM0 = 4096 + (706 * 6 + 356 * 4 + 8) * 4 + 708 * 2;
    SM0 = (SM0 + 15) & ~15;
    int SMa1 = 4096 + (2 * 353) * 4 + nemax[1] * 4 + 355 * 2;
    SMa1 = (SMa1 + 15) & ~15;
    int SMa2 = 4096 + (2 * 177) * 4 + nemax[2] * 4 + 179 * 2;
    SMa2 = (SMa2 + 15) & ~15;
    (void)hipFuncSetAttribute(reinterpret_cast<const void*>(&layer0_kernel),
                              hipFuncAttributeMaxDynamicSharedMemorySize, SM0);
    (void)hipFuncSetAttribute(reinterpret_cast<const void*>(&agg_kernel<353, __half>),
                              hipFuncAttributeMaxDynamicSharedMemorySize, SMa1);
    (void)hipFuncSetAttribute(reinterpret_cast<const void*>(&agg_kernel<177, float>),
                              hipFuncAttributeMaxDynamicSharedMemorySize, SMa2);

    zero_kernel<<<cdiv(3584, 256), 256, 0, stream>>>(ws, 3584);
    csr_build_kernel<<<12, 768, 0, stream>>>(ES, rowptr_all, colsrc_all);

    // ---- layer 0 -> fp16 raw0 in A16 ----
    {
        L0Args A;
        A.x = x;
        for (int j = 0; j < 4; ++j) {
            int s = j * 3;
            A.rowptr[j] = rowptr_all + s * 768;
            A.colsrc[j] = colsrc_all + s * 8192;
            A.ne[j] = ES.ne[s];
            A.out[j] = A16 + j * as0h;
        }
        A.nemax = nemax[0];
        A.dstats = dstats_all;
        A.W = (const float*)d_in[16];
        A.as = (const float*)d_in[17];
        A.ad = (const float*)d_in[18];
        A.bias = (const float*)d_in[19];
        layer0_kernel<<<1024, 512, SM0, stream>>>(A);
    }
    bn_finalize_kernel<<<4, 64, 0, stream>>>(dstats_all, musig_all, 128 * 353,
                                             (const float*)d_in[20], Wp_all, csh_all);

    // ---- layer 1: in-place fp16 MFMA proj on A16, then aggregate -> B16 ---
    proj_kernel<<<dim3(256, 4), 256, 0, stream>>>(A16, Wp_all, csh_all,
                                                  (const float*)d_in[21], (const float*)d_in[22],
                                                  sS1, sD1, 353);
    {
        AggArgs A;
        for (int j = 0; j < 4; ++j) {
            int s = j * 3 + 1;
            A.rowptr[j] = rowptr_all + s * 768;
            A.colsrc[j] = colsrc_all + s * 8192;
            A.ne[j] = ES.ne[s];
            A.hp[j] = A16 + j * as0h;
            A.out[j] = B16 + j * as1h;
        }
        A.nemax = nemax[1];
        A.sS = sS1; A.sD = sD1;
        A.bias = (const float*)d_in[23];
        A.dstats = dstats_all + 512;
        agg_kernel<353, __half><<<1024, 512, SMa1, stream>>>(A);
    }
    bn_finalize_kernel<<<4, 64, 0, stream>>>(dstats_all + 512, musig_all + 512, 128 * 177,
                                             (const float*)d_in[24], Wp_all + 16384, csh_all + 256);

    // ---- layer 2: in-place fp16 MFMA proj on B16, then aggregate -> ALLb --
    proj_kernel<<<dim3(256, 4), 256, 0, stream>>>(B16, Wp_all + 16384, csh_all + 256,
                                                  (const float*)d_in[25], (const float*)d_in[26],
                                                  sS2, sD2, 177);
    {
        AggArgs A;
        for (int j = 0; j < 4; ++j) {
            int s = j * 3 + 2;
            A.rowptr[j] = rowptr_all + s * 768;
            A.colsrc[j] = colsrc_all + s * 8192;
            A.ne[j] = ES.ne[s];
            A.hp[j] = B16 + j * as1h;
            A.out[j] = ALLb + (size_t)j * M_FINAL * 64;
        }
        A.nemax = nemax[2];
        A.sS = sS2; A.sD = sD2;
        A.bias = (const float*)d_in[27];
        A.dstats = dstats_all + 1024;
        agg_kernel<177, float><<<1024, 512, SMa2, stream>>>(A);
    }
    bn_finalize_kernel<<<4, 64, 0, stream>>>(dstats_all + 1024, musig_all + 1024, 128 * 89,
                                             nullptr, nullptr, nullptr);

    // ---- fusion head ----
    const float* musig2 = musig_all + 1024;
    head_reduce_kernel<<<256, 256, 0, stream>>>(ALLb, musig2, (const float*)d_in[28], S, cm);
    fuse_small_kernel<<<1, 64, 0, stream>>>(S, cm, (const float*)d_in[29], (const float*)d_in[30], cvec);
    head_out_kernel<<<256, 256, 0, stream>>>(ALLb, musig2, cvec,
                                             (const float*)d_in[31], (const float*)d_in[32],
                                             (const float*)d_in[33], (float*)d_out);
}

// Round 13
// 334.398 us; speedup vs baseline: 4.9328x; 1.0637x over previous
//
#include <hip/hip_runtime.h>
#include <hip/hip_fp16.h>
#include <math.h>

#define DIM 64
#define M_FINAL (128*89)   // 11392 final rows

static inline int cdiv(int a, int b) { return (a + b - 1) / b; }

typedef _Float16 v8h __attribute__((ext_vector_type(8)));
typedef _Float16 v4h __attribute__((ext_vector_type(4)));
typedef float v4f __attribute__((ext_vector_type(4)));

__device__ inline float rdlane(float v, int l) {
    return __int_as_float(__builtin_amdgcn_readlane(__float_as_int(v), l));
}
__device__ inline unsigned packpw(float p, unsigned src) {
    return ((unsigned)__half_as_ushort(__float2half(p)) << 16) | src;
}
__device__ inline float unpackpw(unsigned ep) {
    return __half2float(__ushort_as_half((unsigned short)(ep >> 16)));
}

struct EdgeSets {
    const int* src[12];
    const int* dst[12];
    int ne[12];
};

struct L0Args {
    const float* x;
    __half* out[4];
    const int* rowptr[4];
    const int* colsrc[4];
    int ne[4];
    int nemax;
    double* dstats;
    const float* W;
    const float* as;
    const float* ad;
    const float* bias;
};

struct AggArgs {
    const __half* hp[4];      // projected rows (out-space, fp16)
    void* out[4];
    const int* rowptr[4];
    const int* colsrc[4];
    int ne[4];
    int nemax;
    const float* sS;          // [j][g][NPIN]
    const float* sD;
    const float* bias;
    double* dstats;
};

// ---------------- misc ----------------

__global__ void zero_kernel(float* __restrict__ p, int n) {
    int i = blockIdx.x * blockDim.x + threadIdx.x;
    if (i < n) p[i] = 0.f;
}

// ---------------- fused CSR build: one block per edge set ------------------
__global__ __launch_bounds__(768)
void csr_build_kernel(EdgeSets ES, int* __restrict__ rowptr_all,
                      int* __restrict__ colsrc_all) {
    __shared__ int cnt[768];
    __shared__ int cur[768];
    const int s = blockIdx.x;
    const int lay = s % 3;
    const int n = (lay == 0) ? 706 : (lay == 1) ? 353 : 177;
    const int ne = ES.ne[s];
    const int* __restrict__ src = ES.src[s];
    const int* __restrict__ dst = ES.dst[s];
    int* __restrict__ rowptr = rowptr_all + s * 768;
    int* __restrict__ colsrc = colsrc_all + s * 8192;
    const int t = threadIdx.x;

    cnt[t] = 0;
    __syncthreads();
    for (int k = t; k < ne; k += 768) atomicAdd(&cnt[dst[k]], 1);
    __syncthreads();
    int v = cnt[t];
    for (int off = 1; off < 768; off <<= 1) {
        int add = (t >= off) ? cnt[t - off] : 0;
        __syncthreads();
        cnt[t] += add;
        __syncthreads();
    }
    int excl = cnt[t] - v;
    if (t < n) { rowptr[t] = excl; cur[t] = excl; }
    if (t == n - 1) rowptr[n] = cnt[t];
    __syncthreads();
    for (int k = t; k < ne; k += 768) {
        int pos = atomicAdd(&cur[dst[k]], 1);
        colsrc[pos] = src[k];
    }
}

// ---------------- layer 0 mega kernel (in_dim=3, thread-par agg) -----------
// grid = split(2) x view(4) x graph(128) = 1024 blocks of 512 threads.
__global__ __launch_bounds__(512, 8)
void layer0_kernel(L0Args A) {
    constexpr int NPIN = 706, NPOUT = 353, HALF = 177;

    extern __shared__ char smem[];
    float* sredF = (float*)smem;                       // [2][8][64] = 4096 B
    float* fp = (float*)(smem + 4096);
    float* sSrc = fp; fp += NPIN;
    float* sDst = fp; fp += NPIN;
    float* hL4  = fp; fp += NPIN * 4;
    float* agg4 = fp; fp += 356 * 4;
    float* waL0 = fp; fp += 8;
    unsigned short* rp16 = (unsigned short*)fp;        // 708

    const int split = blockIdx.x >> 9;
    const int jg = blockIdx.x & 511;
    const int j = jg >> 7;
    const int g = jg & 127;
    const int tid = threadIdx.x;
    const int wave = tid >> 6;
    const int lane = tid & 63;

    const int n0c = split * HALF;
    const int n1c = min(NPOUT, n0c + HALF);
    const int ch0 = 2 * n0c;
    const int ch1 = 2 * n1c;          // NPIN even -> always valid children

    const int* __restrict__ rowptr = A.rowptr[j];
    const int* __restrict__ colsrc = A.colsrc[j];
    const float* __restrict__ W = A.W;

    for (int k = tid; k <= NPIN; k += 512) rp16[k] = (unsigned short)rowptr[k];
    if (tid < 6) {                    // wa_{src,dst}[f] = sum_d W[f][d]*a[d]
        int f = (tid < 3) ? tid : tid - 3;
        const float* av = (tid < 3) ? A.as : A.ad;
        float acc = 0.f;
        for (int d = 0; d < 64; ++d) acc += W[f * 64 + d] * av[d];
        waL0[tid] = acc;
    }
    __syncthreads();

    // h staging + s-dots
    {
        const float* hb = A.x + (size_t)g * (NPIN * 3);
        for (int r = tid; r < NPIN; r += 512) {
            float h0 = hb[r * 3], h1 = hb[r * 3 + 1], h2 = hb[r * 3 + 2];
            hL4[r * 4] = h0; hL4[r * 4 + 1] = h1; hL4[r * 4 + 2] = h2; hL4[r * 4 + 3] = 0.f;
            sSrc[r] = h0 * waL0[0] + h1 * waL0[1] + h2 * waL0[2];
            sDst[r] = h0 * waL0[3] + h1 * waL0[4] + h2 * waL0[5];
        }
    }
    __syncthreads();

    // thread-par softmax + aggregation: one child per thread
    const int child = ch0 + tid;
    if (child < ch1) {
        int s0 = rp16[child], e0 = rp16[child + 1];
        float sd = sDst[child];
        float m = -1e30f;
        for (int k = s0; k < e0; ++k) {
            float v = sSrc[colsrc[k]] + sd;
            v = (v >= 0.f) ? v : 0.2f * v;
            m = fmaxf(m, v);
        }
        float z = 0.f, a0 = 0.f, a1 = 0.f, a2 = 0.f;
        for (int k = s0; k < e0; ++k) {
            int sl = colsrc[k];
            float v = sSrc[sl] + sd;
            v = (v >= 0.f) ? v : 0.2f * v;
            float p = __expf(v - m);
            z += p;
            a0 += p * hL4[sl * 4];
            a1 += p * hL4[sl * 4 + 1];
            a2 += p * hL4[sl * 4 + 2];
        }
        float iz = 1.f / z;
        agg4[tid * 4]     = a0 * iz;
        agg4[tid * 4 + 1] = a1 * iz;
        agg4[tid * 4 + 2] = a2 * iz;
        agg4[tid * 4 + 3] = 0.f;
    }
    __syncthreads();

    // wave-par matvec + relu + pool + store + BN stats
    const float w0 = W[lane], w1 = W[64 + lane], w2 = W[128 + lane];
    const float b_l = A.bias[lane];
    __half* outj = A.out[j];
    const float4* agg4v = (const float4*)agg4;
    float bs = 0.f, bs2 = 0.f;

    for (int c = n0c + wave; c < n1c; c += 8) {
        int lc = 2 * (c - n0c);
        float4 va = agg4v[lc];
        float4 vb = agg4v[lc + 1];
        float oa = va.x * w0 + va.y * w1 + va.z * w2 + b_l;
        float ob = vb.x * w0 + vb.y * w1 + vb.z * w2 + b_l;
        float vmax = fmaxf(fmaxf(oa, ob), 0.f);
        outj[((size_t)g * NPOUT + c) * 64 + lane] = __float2half(vmax);
        bs += vmax;
        bs2 += vmax * vmax;
    }
    sredF[wave * 64 + lane] = bs;
    sredF[512 + wave * 64 + lane] = bs2;
    __syncthreads();
    if (wave == 0) {
        float t1 = 0.f, t2 = 0.f;
        #pragma unroll
        for (int w = 0; w < 8; ++w) {
            t1 += sredF[w * 64 + lane];
            t2 += sredF[512 + w * 64 + lane];
        }
        atomicAdd(A.dstats + j * 128 + lane, (double)t1);
        atomicAdd(A.dstats + j * 128 + 64 + lane, (double)t2);
    }
}

// BN finalize; optionally fold stats into next layer's weight:
// Wp[f][d] = rs[f]*Wn[f][d]; csh[d] = sum_f mu[f]*rs[f]*Wn[f][d]
__global__ void bn_finalize_kernel(const double* __restrict__ dstats,
                                   float* __restrict__ musig, int n_rows,
                                   const float* __restrict__ Wn,
                                   float* __restrict__ Wp, float* __restrict__ csh) {
    __shared__ float mur[128];
    int jv = blockIdx.x;           // view
    int d = threadIdx.x;           // 64
    double mu = dstats[jv * 128 + d] / n_rows;
    double var = dstats[jv * 128 + 64 + d] / n_rows - mu * mu;
    float rs = rsqrtf((float)var + 1e-5f);
    musig[jv * 128 + d] = (float)mu;
    musig[jv * 128 + 64 + d] = rs;
    if (Wn != nullptr) {
        mur[d] = (float)mu; mur[64 + d] = rs;
        __syncthreads();
        float c = 0.f;
        for (int f = 0; f < 64; ++f) {
            float wp = mur[64 + f] * Wn[f * 64 + d];
            Wp[jv * 4096 + f * 64 + d] = wp;
            c += mur[f] * wp;
        }
        csh[jv * 64 + d] = c;
    }
}

// ---------------- projection via MFMA: HP = h @ W' - c, fp16 in-place ------
__global__ __launch_bounds__(256, 4)
void proj_kernel(__half* __restrict__ buf, const float* __restrict__ Wp_all,
                 const float* __restrict__ csh_all,
                 const float* __restrict__ a_s, const float* __restrict__ a_d,
                 float* __restrict__ sS, float* __restrict__ sD, int npin) {
    __shared__ _Float16 Wt[64 * 64];   // Wt[d][f] = W'[f][d], fp16 (8 KB)
    const int j = blockIdx.y;
    const int tid = threadIdx.x;
    const int lane = tid & 63, wave = tid >> 6;
    const int lc = lane & 15, quad = lane >> 4;
    const int R = 128 * npin;          // multiple of 16
    __half* h = buf + (size_t)j * R * 64;
    const float* Wp = Wp_all + j * 4096;

    for (int k = tid; k < 4096; k += 256) {
        int f = k >> 6, d = k & 63;
        Wt[d * 64 + f] = (_Float16)Wp[k];
    }
    __syncthreads();

    v8h bfrag[4][2];
    #pragma unroll
    for (int t = 0; t < 4; ++t)
        #pragma unroll
        for (int s = 0; s < 2; ++s)
            bfrag[t][s] = *(const v8h*)&Wt[(t * 16 + lc) * 64 + s * 32 + quad * 8];

    float cshv[4], asv[4], adv[4];
    #pragma unroll
    for (int t = 0; t < 4; ++t) {
        cshv[t] = csh_all[j * 64 + t * 16 + lc];
        asv[t] = a_s[t * 16 + lc];
        adv[t] = a_d[t * 16 + lc];
    }

    const int ntiles = R >> 4;
    for (int tile = blockIdx.x * 4 + wave; tile < ntiles; tile += gridDim.x * 4) {
        const int rowbase = tile * 16;
        const __half* arow = h + ((size_t)(rowbase + lc)) * 64 + quad * 8;
        v8h a0 = *(const v8h*)arow;            // k-step 0 (k=0..31)
        v8h a1 = *(const v8h*)(arow + 32);     // k-step 1 (k=32..63)
        v4f acc[4];
        #pragma unroll
        for (int t = 0; t < 4; ++t) {
            acc[t] = (v4f){0.f, 0.f, 0.f, 0.f};
            acc[t] = __builtin_amdgcn_mfma_f32_16x16x32_f16(a0, bfrag[t][0], acc[t], 0, 0, 0);
            acc[t] = __builtin_amdgcn_mfma_f32_16x16x32_f16(a1, bfrag[t][1], acc[t], 0, 0, 0);
        }
        float pS[4] = {0.f, 0.f, 0.f, 0.f};
        float pD[4] = {0.f, 0.f, 0.f, 0.f};
        #pragma unroll
        for (int t = 0; t < 4; ++t) {
            #pragma unroll
            for (int r = 0; r < 4; ++r) {
                float o = acc[t][r] - cshv[t];
                h[((size_t)(rowbase + quad * 4 + r)) * 64 + t * 16 + lc] = __float2half(o);
                pS[r] += o * asv[t];
                pD[r] += o * adv[t];
            }
        }
        #pragma unroll
        for (int m = 1; m < 16; m <<= 1) {
            #pragma unroll
            for (int r = 0; r < 4; ++r) {
                pS[r] += __shfl_xor(pS[r], m, 64);
                pD[r] += __shfl_xor(pD[r], m, 64);
            }
        }
        if (lc == 0) {
            #pragma unroll
            for (int r = 0; r < 4; ++r) {
                sS[j * R + rowbase + quad * 4 + r] = pS[r];
                sD[j * R + rowbase + quad * 4 + r] = pD[r];
            }
        }
    }
}

// ---------------- aggregation (L>0): quad-row gather -----------------------
// wave = (edge-group qg = lane>>4) x (dim-group lc = lane&15, 4 dims/lane).
// One half4 load per lane covers 4 edges' rows (4 x 128B segments = 512 B).
template<int NPIN, typename OutT>
__global__ __launch_bounds__(512, 8)
void agg_kernel(AggArgs A) {
    constexpr int NPOUT = (NPIN + 1) / 2;
    constexpr int HALF = (NPOUT + 1) / 2;

    extern __shared__ char smem[];
    float* sredF = (float*)smem;                       // 4096 B
    float* fp = (float*)(smem + 4096);
    float* sSrc = fp; fp += NPIN;
    float* sDst = fp; fp += NPIN;
    unsigned* ep32 = (unsigned*)fp;
    unsigned short* rp16 = (unsigned short*)(ep32 + A.nemax);

    const int split = blockIdx.x >> 9;
    const int jg = blockIdx.x & 511;
    const int j = jg >> 7;
    const int g = jg & 127;
    const int tid = threadIdx.x;
    const int wave = tid >> 6;
    const int lane = tid & 63;
    const int qg = lane >> 4;          // edge-group 0..3
    const int lc = lane & 15;          // dim-group: dims 4*lc .. 4*lc+3

    const int n0c = split * HALF;
    const int n1c = min(NPOUT, n0c + HALF);
    const int ch0 = 2 * n0c;
    const int ch1 = min(NPIN, 2 * n1c);

    const int* __restrict__ rowptr = A.rowptr[j];
    const int* __restrict__ colsrc = A.colsrc[j];
    const int ne = A.ne[j];
    const int sbase = (j * 128 + g) * NPIN;
    const __half* __restrict__ hpb = A.hp[j] + (size_t)g * NPIN * 64 + 4 * lc;

    for (int k = tid; k <= NPIN; k += 512) rp16[k] = (unsigned short)rowptr[k];
    for (int k = tid; k < ne; k += 512) ep32[k] = (unsigned)colsrc[k];
    for (int r = tid; r < NPIN; r += 512) {
        sSrc[r] = A.sS[sbase + r];
        sDst[r] = A.sD[sbase + r];
    }
    __syncthreads();

    // per-node online softmax -> packed fp16 weights (own child range)
    for (int r = ch0 + tid; r < ch1; r += 512) {
        int s0 = rp16[r], e0 = rp16[r + 1];
        float sd = sDst[r];
        float m = -1e30f, z = 0.f;
        for (int k = s0; k < e0; ++k) {
            float v = sSrc[ep32[k] & 0xFFFFu] + sd;
            v = (v >= 0.f) ? v : 0.2f * v;
            if (v > m) { z = z * __expf(m - v) + 1.f; m = v; }
            else z += __expf(v - m);
        }
        float invz = 1.f / z;
        for (int k = s0; k < e0; ++k) {
            unsigned sl = ep32[k] & 0xFFFFu;
            float v = sSrc[sl] + sd;
            v = (v >= 0.f) ? v : 0.2f * v;
            ep32[k] = packpw(__expf(v - m) * invz, sl);
        }
    }
    __syncthreads();

    const float4 b4 = *(const float4*)(A.bias + 4 * lc);
    OutT* outj = (OutT*)A.out[j];
    float bs[4] = {0.f, 0.f, 0.f, 0.f};
    float bs2[4] = {0.f, 0.f, 0.f, 0.f};

    for (int c = n0c + wave; c < n1c; c += 8) {
        float vch[2][4];
        #pragma unroll
        for (int ch = 0; ch < 2; ++ch) {
            float a0[4] = {0.f, 0.f, 0.f, 0.f};
            float a1[4] = {0.f, 0.f, 0.f, 0.f};
            int child = 2 * c + ch;
            if (child < NPIN) {
                int s0 = rp16[child], e0 = rp16[child + 1];
                int k = s0;
                for (; k + 8 <= e0; k += 8) {
                    unsigned e0p = ep32[k + qg];
                    unsigned e1p = ep32[k + 4 + qg];
                    v4h h0 = *(const v4h*)(hpb + (size_t)(e0p & 0xFFFFu) * 64);
                    v4h h1 = *(const v4h*)(hpb + (size_t)(e1p & 0xFFFFu) * 64);
                    float p0 = unpackpw(e0p), p1 = unpackpw(e1p);
                    #pragma unroll
                    for (int r = 0; r < 4; ++r) {
                        a0[r] += p0 * (float)h0[r];
                        a1[r] += p1 * (float)h1[r];
                    }
                }
                for (; k < e0; k += 4) {
                    int idx = k + qg;
                    unsigned ep = ep32[(idx < e0) ? idx : (e0 - 1)];
                    float p = (idx < e0) ? unpackpw(ep) : 0.f;
                    v4h hv = *(const v4h*)(hpb + (size_t)(ep & 0xFFFFu) * 64);
                    #pragma unroll
                    for (int r = 0; r < 4; ++r) a0[r] += p * (float)hv[r];
                }
            }
            #pragma unroll
            for (int r = 0; r < 4; ++r) vch[ch][r] = a0[r] + a1[r];
        }
        // reduce over the 4 edge-groups
        #pragma unroll
        for (int m = 16; m < 64; m <<= 1) {
            #pragma unroll
            for (int r = 0; r < 4; ++r) {
                vch[0][r] += __shfl_xor(vch[0][r], m, 64);
                vch[1][r] += __shfl_xor(vch[1][r], m, 64);
            }
        }
        float vm[4];
        #pragma unroll
        for (int r = 0; r < 4; ++r) {
            float oa = vch[0][r] + ((const float*)&b4)[r];
            float ob = vch[1][r] + ((const float*)&b4)[r];
            vm[r] = fmaxf(fmaxf(oa, ob), 0.f);
            bs[r] += vm[r];
            bs2[r] += vm[r] * vm[r];
        }
        if (qg == 0) {
            if constexpr (sizeof(OutT) == 2) {
                v4h hv;
                #pragma unroll
                for (int r = 0; r < 4; ++r) hv[r] = (_Float16)vm[r];
                *(v4h*)((__half*)outj + ((size_t)g * NPOUT + c) * 64 + 4 * lc) = hv;
            } else {
                float4 fv = {vm[0], vm[1], vm[2], vm[3]};
                *(float4*)((float*)outj + ((size_t)g * NPOUT + c) * 64 + 4 * lc) = fv;
            }
        }
    }
    // stats: post-reduce values identical across qg; qg==0 lanes cover all 64 dims
    if (qg == 0) {
        #pragma unroll
        for (int r = 0; r < 4; ++r) {
            sredF[wave * 64 + 4 * lc + r] = bs[r];
            sredF[512 + wave * 64 + 4 * lc + r] = bs2[r];
        }
    }
    __syncthreads();
    if (wave == 0) {
        float t1 = 0.f, t2 = 0.f;
        #pragma unroll
        for (int w = 0; w < 8; ++w) {
            t1 += sredF[w * 64 + lane];
            t2 += sredF[512 + w * 64 + lane];
        }
        atomicAdd(A.dstats + j * 128 + lane, (double)t1);
        atomicAdd(A.dstats + j * 128 + 64 + lane, (double)t2);
    }
}

// ---------------- fused head reduce: Bm dots -> S (BmT Bm) + column means --
__global__ __launch_bounds__(256)
void head_reduce_kernel(const float* __restrict__ ALL, const float* __restrict__ musig,
                        const float* __restrict__ w_attn,
                        float* __restrict__ S, float* __restrict__ cm) {
    __shared__ float S_loc[16];
    __shared__ float cm_loc[256];
    const int t = threadIdx.x, wave = t >> 6, lane = t & 63;
    if (t < 16) S_loc[t] = 0.f;
    cm_loc[t] = 0.f;
    __syncthreads();
    const float wa = w_attn[lane];
    float cacc[4] = {0.f, 0.f, 0.f, 0.f};
    for (int m = blockIdx.x * 4 + wave; m < M_FINAL; m += gridDim.x * 4) {
        float b4[4];
        float csum = 0.f;
        #pragma unroll
        for (int v = 0; v < 4; ++v) {
            float val = (ALL[((size_t)v * M_FINAL + m) * 64 + lane] - musig[v * 128 + lane])
                        * musig[v * 128 + 64 + lane];
            csum += val;
            float p = val * wa;
            for (int off = 32; off > 0; off >>= 1) p += __shfl_down(p, off, 64);
            b4[v] = __shfl(p, 0, 64);
        }
        cacc[m & 3] += csum;
        if (lane < 16) atomicAdd(&S_loc[lane], b4[lane >> 2] * b4[lane & 3]);
    }
    #pragma unroll
    for (int q = 0; q < 4; ++q) atomicAdd(&cm_loc[q * 64 + lane], cacc[q]);
    __syncthreads();
    if (t < 16) atomicAdd(&S[t], S_loc[t]);
    atomicAdd(&cm[t], cm_loc[t]);
}

// wave-parallel: 64 lanes split the 256-column mean-dot; lane 0 does the
// tiny 4x4 softmax tail.
__global__ void fuse_small_kernel(const float* __restrict__ S, const float* __restrict__ cm,
                                  const float* __restrict__ w_lin0, const float* __restrict__ b_lin0,
                                  float* __restrict__ cvec) {
    const int lane = threadIdx.x;      // 64
    float pa0 = 0.f, pa1 = 0.f, pa2 = 0.f, pa3 = 0.f;
    #pragma unroll
    for (int q = 0; q < 4; ++q) {
        int c = q * 64 + lane;
        float cmv = cm[c] / (float)M_FINAL;
        pa0 += cmv * w_lin0[c * 4 + 0];
        pa1 += cmv * w_lin0[c * 4 + 1];
        pa2 += cmv * w_lin0[c * 4 + 2];
        pa3 += cmv * w_lin0[c * 4 + 3];
    }
    for (int off = 32; off > 0; off >>= 1) {
        pa0 += __shfl_down(pa0, off, 64);
        pa1 += __shfl_down(pa1, off, 64);
        pa2 += __shfl_down(pa2, off, 64);
        pa3 += __shfl_down(pa3, off, 64);
    }
    if (lane != 0) return;
    float e4[4] = {pa0 + b_lin0[0], pa1 + b_lin0[1], pa2 + b_lin0[2], pa3 + b_lin0[3]};
    float cn[4];
    for (int v = 0; v < 4; ++v) cn[v] = sqrtf(S[v * 4 + v]);
    float A[16];
    for (int u = 0; u < 4; ++u) {
        float row[4]; float mx = -1e30f;
        for (int v = 0; v < 4; ++v) {
            float g = S[u * 4 + v] / (cn[u] * cn[v]);
            g = (g >= 0.f) ? g : 0.1f * g;       // leaky_relu 0.1
            row[v] = g; mx = fmaxf(mx, g);
        }
        float sum = 0.f;
        for (int v = 0; v < 4; ++v) { row[v] = expf(row[v] - mx); sum += row[v]; }
        for (int v = 0; v < 4; ++v) A[u * 4 + v] = row[v] / sum;
    }
    float mx = fmaxf(fmaxf(e4[0], e4[1]), fmaxf(e4[2], e4[3]));
    float sum = 0.f, w[4];
    for (int v = 0; v < 4; ++v) { w[v] = expf(e4[v] - mx); sum += w[v]; }
    for (int v = 0; v < 4; ++v) w[v] /= sum;
    for (int k = 0; k < 4; ++k) {
        float c = 0.f;
        for (int v = 0; v < 4; ++v) c += A[k * 4 + v] * w[v];
        cvec[k] = c;
    }
}

// ---------------- fused head output: combine + 3 matvecs (selu,selu,none) --
__global__ __launch_bounds__(256)
void head_out_kernel(const float* __restrict__ ALL, const float* __restrict__ musig,
                     const float* __restrict__ cvec,
                     const float* __restrict__ W0, const float* __restrict__ W1,
                     const float* __restrict__ W2, float* __restrict__ outp) {
    __shared__ float Wl[3][64 * 64];   // 48 KB
    const int t = threadIdx.x, wave = t >> 6, lane = t & 63;
    for (int k = t; k < 4096; k += 256) {
        Wl[0][k] = W0[k]; Wl[1][k] = W1[k]; Wl[2][k] = W2[k];
    }
    __syncthreads();
    const float c0 = cvec[0], c1 = cvec[1], c2 = cvec[2], c3 = cvec[3];
    const float scale = 1.0507009873554805f;
    const float alpha = 1.6732632423543772f;
    for (int m = blockIdx.x * 4 + wave; m < M_FINAL; m += gridDim.x * 4) {
        float r =
            c0 * ((ALL[((size_t)0 * M_FINAL + m) * 64 + lane] - musig[0 * 128 + lane]) * musig[0 * 128 + 64 + lane]) +
            c1 * ((ALL[((size_t)1 * M_FINAL + m) * 64 + lane] - musig[1 * 128 + lane]) * musig[1 * 128 + 64 + lane]) +
            c2 * ((ALL[((size_t)2 * M_FINAL + m) * 64 + lane] - musig[2 * 128 + lane]) * musig[2 * 128 + 64 + lane]) +
            c3 * ((ALL[((size_t)3 * M_FINAL + m) * 64 + lane] - musig[3 * 128 + lane]) * musig[3 * 128 + 64 + lane]);
        #pragma unroll
        for (int s = 0; s < 3; ++s) {
            float o0 = 0.f, o1 = 0.f, o2 = 0.f, o3 = 0.f;
            #pragma unroll
            for (int f = 0; f < 64; f += 4) {
                o0 += rdlane(r, f)     * Wl[s][f * 64 + lane];
                o1 += rdlane(r, f + 1) * Wl[s][(f + 1) * 64 + lane];
                o2 += rdlane(r, f + 2) * Wl[s][(f + 2) * 64 + lane];
                o3 += rdlane(r, f + 3) * Wl[s][(f + 3) * 64 + lane];
            }
            float o = (o0 + o1) + (o2 + o3);
            if (s < 2) o = (o > 0.f) ? scale * o : scale * alpha * expm1f(o);
            r = o;
        }
        outp[(size_t)m * 64 + lane] = r;
    }
}

extern "C" void kernel_launch(void* const* d_in, const int* in_sizes, int n_in,
                              void* d_out, int out_size, void* d_ws, size_t ws_size,
                              hipStream_t stream) {
    const float* x = (const float*)d_in[15];

    float* ws = (float*)d_ws;
    double* dstats_all = (double*)ws;                 // 1536 doubles -> [0, 3072)
    float*  cm         = ws + 3072;                   // 256
    float*  S          = ws + 3328;                   // 16
    float*  cvec       = ws + 3344;                   // 4
    float*  musig_all  = ws + 3584;                   // 3*512 -> [3584, 5120)
    float*  Wp_all     = ws + 5120;                   // 2*4*4096 -> [5120, 37888)
    float*  csh_all    = ws + 37888;                  // 2*4*64 -> [37888, 38400)
    int*    rowptr_all = (int*)(ws + 38400);          // 12*768 -> [38400, 47616)
    int*    colsrc_all = (int*)(ws + 47616);          // 12*8192 -> [47616, 145920)
    float*  sS1        = ws + 145920;                 // 180736
    float*  sD1        = sS1 + 180736;
    float*  sS2        = sD1 + 180736;                // 90624
    float*  sD2        = sS2 + 90624;
    __half* A16        = (__half*)(sD2 + 90624);      // 11,567,104 halves (5,783,552 slots)
    __half* B16        = (__half*)((float*)A16 + 5783552);  // 5,799,936 halves (2,899,968 slots)
    float*  ALLb       = (float*)B16 + 2899968;       // 2,916,352 floats
    const size_t as0h = (size_t)128 * 353 * 64;       // halves per view (layer0/1)
    const size_t as1h = (size_t)128 * 177 * 64;

    // edge sets (graph-0 structure shared by all 128 graphs)
    EdgeSets ES;
    int nemax[3] = {0, 0, 0};
    for (int s = 0; s < 12; ++s) {
        const int* e = (const int*)d_in[s];
        int E = in_sizes[s] / 2;
        ES.src[s] = e;
        ES.dst[s] = e + E;
        ES.ne[s] = E / 128;
        int lay = s % 3;
        if (ES.ne[s] > nemax[lay]) nemax[lay] = ES.ne[s];
    }

    // dynamic LDS sizes (mirror in-kernel layouts)
    int SM0 = 4096 + (706 * 6 + 356 * 4 + 8) * 4 + 708 * 2;
    SM0 = (SM0 + 15) & ~15;
    int SMa1 = 4096 + (2 * 353) * 4 + nemax[1] * 4 + 355 * 2;
    SMa1 = (SMa1 + 15) & ~15;
    int SMa2 = 4096 + (2 * 177) * 4 + nemax[2] * 4 + 179 * 2;
    SMa2 = (SMa2 + 15) & ~15;
    (void)hipFuncSetAttribute(reinterpret_cast<const void*>(&layer0_kernel),
                              hipFuncAttributeMaxDynamicSharedMemorySize, SM0);
    (void)hipFuncSetAttribute(reinterpret_cast<const void*>(&agg_kernel<353, __half>),
                              hipFuncAttributeMaxDynamicSharedMemorySize, SMa1);
    (void)hipFuncSetAttribute(reinterpret_cast<const void*>(&agg_kernel<177, float>),
                              hipFuncAttributeMaxDynamicSharedMemorySize, SMa2);

    zero_kernel<<<cdiv(3584, 256), 256, 0, stream>>>(ws, 3584);
    csr_build_kernel<<<12, 768, 0, stream>>>(ES, rowptr_all, colsrc_all);

    // ---- layer 0 -> fp16 raw0 in A16 ----
    {
        L0Args A;
        A.x = x;
        for (int j = 0; j < 4; ++j) {
            int s = j * 3;
            A.rowptr[j] = rowptr_all + s * 768;
            A.colsrc[j] = colsrc_all + s * 8192;
            A.ne[j] = ES.ne[s];
            A.out[j] = A16 + j * as0h;
        }
        A.nemax = nemax[0];
        A.dstats = dstats_all;
        A.W = (const float*)d_in[16];
        A.as = (const float*)d_in[17];
        A.ad = (const float*)d_in[18];
        A.bias = (const float*)d_in[19];
        layer0_kernel<<<1024, 512, SM0, stream>>>(A);
    }
    bn_finalize_kernel<<<4, 64, 0, stream>>>(dstats_all, musig_all, 128 * 353,
                                             (const float*)d_in[20], Wp_all, csh_all);

    // ---- layer 1: in-place fp16 MFMA proj on A16, then aggregate -> B16 ---
    proj_kernel<<<dim3(256, 4), 256, 0, stream>>>(A16, Wp_all, csh_all,
                                                  (const float*)d_in[21], (const float*)d_in[22],
                                                  sS1, sD1, 353);
    {
        AggArgs A;
        for (int j = 0; j < 4; ++j) {
            int s = j * 3 + 1;
            A.rowptr[j] = rowptr_all + s * 768;
            A.colsrc[j] = colsrc_all + s * 8192;
            A.ne[j] = ES.ne[s];
            A.hp[j] = A16 + j * as0h;
            A.out[j] = B16 + j * as1h;
        }
        A.nemax = nemax[1];
        A.sS = sS1; A.sD = sD1;
        A.bias = (const float*)d_in[23];
        A.dstats = dstats_all + 512;
        agg_kernel<353, __half><<<1024, 512, SMa1, stream>>>(A);
    }
    bn_finalize_kernel<<<4, 64, 0, stream>>>(dstats_all + 512, musig_all + 512, 128 * 177,
                                             (const float*)d_in[24], Wp_all + 16384, csh_all + 256);

    // ---- layer 2: in-place fp16 MFMA proj on B16, then aggregate -> ALLb --
    proj_kernel<<<dim3(256, 4), 256, 0, stream>>>(B16, Wp_all + 16384, csh_all + 256,
                                                  (const float*)d_in[25], (const float*)d_in[26],
                                                  sS2, sD2, 177);
    {
        AggArgs A;
        for (int j = 0; j < 4; ++j) {
            int s = j * 3 + 2;
            A.rowptr[j] = rowptr_all + s * 768;
            A.colsrc[j] = colsrc_all + s * 8192;
            A.ne[j] = ES.ne[s];
            A.hp[j] = B16 + j * as1h;
            A.out[j] = ALLb + (size_t)j * M_FINAL * 64;
        }
        A.nemax = nemax[2];
        A.sS = sS2; A.sD = sD2;
        A.bias = (const float*)d_in[27];
        A.dstats = dstats_all + 1024;
        agg_kernel<177, float><<<1024, 512, SMa2, stream>>>(A);
    }
    bn_finalize_kernel<<<4, 64, 0, stream>>>(dstats_all + 1024, musig_all + 1024, 128 * 89,
                                             nullptr, nullptr, nullptr);

    // ---- fusion head ----
    const float* musig2 = musig_all + 1024;
    head_reduce_kernel<<<256, 256, 0, stream>>>(ALLb, musig2, (const float*)d_in[28], S, cm);
    fuse_small_kernel<<<1, 64, 0, stream>>>(S, cm, (const float*)d_in[29], (const float*)d_in[30], cvec);
    head_out_kernel<<<256, 256, 0, stream>>>(ALLb, musig2, cvec,
                                             (const float*)d_in[31], (const float*)d_in[32],
                                             (const float*)d_in[33], (float*)d_out);
}